// Round 1
// baseline (503.976 us; speedup 1.0000x reference)
//
#include <hip/hip_runtime.h>
#include <math.h>

#define N_NODES 30000
#define N_EDGESN 480000
#define NFEAT 256
#define HEADS 4
#define C0V 64
#define C1V 40
#define HC0 (HEADS*C0V)   // 256
#define HC1 (HEADS*C1V)   // 160
#define NEG_SLOPE 0.2f
#define EPSV 1e-16f

__device__ __forceinline__ float lrelu(float x) { return x >= 0.f ? x : x * NEG_SLOPE; }

// ---------------- GEMM: C[n,M] = A[n,K] @ W[K,M], f32, 64x64 tile, 4x4/thread ----
__global__ __launch_bounds__(256) void gemm_f32(const float* __restrict__ A,
    const float* __restrict__ W, float* __restrict__ C, int n, int K, int M) {
  __shared__ float As[16][64];
  __shared__ float Bs[16][64];
  const int tid = threadIdx.x;
  const int tx = tid & 15, ty = tid >> 4;
  const int row0 = blockIdx.x * 64;
  const int col0 = blockIdx.y * 64;
  const int ar_ = tid >> 2;          // A-load: row in tile (0..63)
  const int ak = (tid & 3) << 2;     // A-load: k offset (0,4,8,12)
  const int bk = tid >> 4;           // B-load: k row (0..15)
  const int bn = (tid & 15) << 2;    // B-load: col offset
  float acc[4][4] = {};
  for (int k0 = 0; k0 < K; k0 += 16) {
    float4 va = make_float4(0.f, 0.f, 0.f, 0.f);
    const int grow = row0 + ar_;
    if (grow < n) va = *reinterpret_cast<const float4*>(A + (size_t)grow * K + k0 + ak);
    float4 vb = make_float4(0.f, 0.f, 0.f, 0.f);
    const int gcol = col0 + bn;
    if (gcol < M) vb = *reinterpret_cast<const float4*>(W + (size_t)(k0 + bk) * M + gcol);
    __syncthreads();
    As[ak + 0][ar_] = va.x; As[ak + 1][ar_] = va.y;
    As[ak + 2][ar_] = va.z; As[ak + 3][ar_] = va.w;
    *reinterpret_cast<float4*>(&Bs[bk][bn]) = vb;
    __syncthreads();
#pragma unroll
    for (int k = 0; k < 16; ++k) {
      float4 a = *reinterpret_cast<const float4*>(&As[k][ty << 2]);
      float4 b = *reinterpret_cast<const float4*>(&Bs[k][tx << 2]);
      acc[0][0] = fmaf(a.x, b.x, acc[0][0]); acc[0][1] = fmaf(a.x, b.y, acc[0][1]);
      acc[0][2] = fmaf(a.x, b.z, acc[0][2]); acc[0][3] = fmaf(a.x, b.w, acc[0][3]);
      acc[1][0] = fmaf(a.y, b.x, acc[1][0]); acc[1][1] = fmaf(a.y, b.y, acc[1][1]);
      acc[1][2] = fmaf(a.y, b.z, acc[1][2]); acc[1][3] = fmaf(a.y, b.w, acc[1][3]);
      acc[2][0] = fmaf(a.z, b.x, acc[2][0]); acc[2][1] = fmaf(a.z, b.y, acc[2][1]);
      acc[2][2] = fmaf(a.z, b.z, acc[2][2]); acc[2][3] = fmaf(a.z, b.w, acc[2][3]);
      acc[3][0] = fmaf(a.w, b.x, acc[3][0]); acc[3][1] = fmaf(a.w, b.y, acc[3][1]);
      acc[3][2] = fmaf(a.w, b.z, acc[3][2]); acc[3][3] = fmaf(a.w, b.w, acc[3][3]);
    }
  }
#pragma unroll
  for (int i2 = 0; i2 < 4; ++i2) {
    const int r = row0 + (ty << 2) + i2;
    if (r < n) {
#pragma unroll
      for (int j = 0; j < 4; ++j) {
        const int c = col0 + (tx << 2) + j;
        if (c < M) C[(size_t)r * M + c] = acc[i2][j];
      }
    }
  }
}

// ---------------- per-node attention dot products ------------------------------
template <int C>
__global__ __launch_bounds__(256) void att_dots(const float* __restrict__ h,
    const float* __restrict__ att, float* __restrict__ al, float* __restrict__ ar,
    int n) {
  const int i = blockIdx.x;
  const int hd = threadIdx.x >> 6, lane = threadIdx.x & 63;
  float hv = 0.f, wl = 0.f, wr = 0.f;
  if (lane < C) {
    hv = h[((size_t)i * HEADS + hd) * C + lane];
    wl = att[hd * 2 * C + lane];
    wr = att[hd * 2 * C + C + lane];
  }
  float pl = hv * wl, pr = hv * wr;
#pragma unroll
  for (int o = 32; o; o >>= 1) { pl += __shfl_xor(pl, o); pr += __shfl_xor(pr, o); }
  if (lane == 0) { al[(size_t)i * HEADS + hd] = pl; ar[(size_t)i * HEADS + hd] = pr; }
}

// ---------------- CSR build ----------------------------------------------------
__global__ void hist_kernel(const int* __restrict__ src, int* __restrict__ deg, int E) {
  const int e = blockIdx.x * blockDim.x + threadIdx.x;
  if (e < E) atomicAdd(&deg[src[e]], 1);
}

__global__ __launch_bounds__(1024) void scan_kernel(const int* __restrict__ deg,
    int* __restrict__ rowstart, int n) {
  __shared__ int carry;
  __shared__ int wsum[16];
  const int tid = threadIdx.x;
  const int lane = tid & 63, w = tid >> 6;
  if (tid == 0) { carry = 0; rowstart[0] = 0; }
  __syncthreads();
  for (int base = 0; base < n; base += 1024) {
    const int idx = base + tid;
    int x = (idx < n) ? deg[idx] : 0;
#pragma unroll
    for (int o = 1; o < 64; o <<= 1) { int y = __shfl_up(x, o); if (lane >= o) x += y; }
    if (lane == 63) wsum[w] = x;
    __syncthreads();
    if (w == 0) {
      int s = (lane < 16) ? wsum[lane] : 0;
#pragma unroll
      for (int o = 1; o < 16; o <<= 1) { int y = __shfl_up(s, o); if (lane >= o) s += y; }
      if (lane < 16) wsum[lane] = s;
    }
    __syncthreads();
    const int add = (w > 0 ? wsum[w - 1] : 0) + carry;
    if (idx < n) rowstart[idx + 1] = x + add;
    __syncthreads();
    if (tid == 0) carry += wsum[15];
    __syncthreads();
  }
}

__global__ void scatter_kernel(const int* __restrict__ src, const int* __restrict__ dst,
    const int* __restrict__ rowstart, int* __restrict__ fill, int* __restrict__ scol,
    int E) {
  const int e = blockIdx.x * blockDim.x + threadIdx.x;
  if (e < E) {
    const int r = src[e];
    const int pos = rowstart[r] + atomicAdd(&fill[r], 1);
    scol[pos] = dst[e];
  }
}

// ---------------- fused softmax + aggregation, one block per node --------------
// wave = head, lane = channel. CONCAT_RELU: layer0 (concat heads + relu).
// else: mean over heads (layer1), no relu.
template <int C, bool CONCAT_RELU>
__global__ __launch_bounds__(256) void gat_agg(const float* __restrict__ h,
    const float* __restrict__ al, const float* __restrict__ ar,
    const int* __restrict__ rowstart, const int* __restrict__ scol,
    const float* __restrict__ bias, float* __restrict__ out, int n) {
  __shared__ float sm[HEADS][64];
  const int i = blockIdx.x;
  const int hd = threadIdx.x >> 6, lane = threadIdx.x & 63;
  const int s0 = rowstart[i], s1 = rowstart[i + 1];
  const float ali = al[(size_t)i * HEADS + hd];
  const float aself = lrelu(ali + ar[(size_t)i * HEADS + hd]);
  // pass 1: max
  float m = aself;
  for (int e = s0 + lane; e < s1; e += 64) {
    const int j = scol[e];
    m = fmaxf(m, lrelu(ali + ar[(size_t)j * HEADS + hd]));
  }
#pragma unroll
  for (int o = 32; o; o >>= 1) m = fmaxf(m, __shfl_xor(m, o));
  // pass 2: sum of exp
  float ssum = (lane == 0) ? expf(aself - m) : 0.f;
  for (int e = s0 + lane; e < s1; e += 64) {
    const int j = scol[e];
    ssum += expf(lrelu(ali + ar[(size_t)j * HEADS + hd]) - m);
  }
#pragma unroll
  for (int o = 32; o; o >>= 1) ssum += __shfl_xor(ssum, o);
  const float inv = 1.f / (ssum + EPSV);
  // pass 3: weighted aggregation
  const float hself = (lane < C) ? h[((size_t)i * HEADS + hd) * C + lane] : 0.f;
  float acc = expf(aself - m) * inv * hself;
  for (int e0 = s0; e0 < s1; e0 += 64) {
    const int cnt = min(64, s1 - e0);
    int j = 0; float wgt = 0.f;
    if (lane < cnt) {
      j = scol[e0 + lane];
      wgt = expf(lrelu(ali + ar[(size_t)j * HEADS + hd]) - m) * inv;
    }
    for (int t = 0; t < cnt; ++t) {
      const float wv = __shfl(wgt, t);
      const int jj = __shfl(j, t);
      const float hv = (lane < C) ? h[((size_t)jj * HEADS + hd) * C + lane] : 0.f;
      acc = fmaf(wv, hv, acc);
    }
  }
  if (CONCAT_RELU) {
    if (lane < C) {
      const float v = acc + bias[hd * C + lane];
      out[(size_t)i * (HEADS * C) + hd * C + lane] = fmaxf(v, 0.f);
    }
  } else {
    sm[hd][lane] = acc;
    __syncthreads();
    if (threadIdx.x < C) {
      const float v = (sm[0][threadIdx.x] + sm[1][threadIdx.x] +
                       sm[2][threadIdx.x] + sm[3][threadIdx.x]) * 0.25f +
                      bias[threadIdx.x];
      out[(size_t)i * C + threadIdx.x] = v;
    }
  }
}

// ---------------- launch -------------------------------------------------------
extern "C" void kernel_launch(void* const* d_in, const int* in_sizes, int n_in,
                              void* d_out, int out_size, void* d_ws, size_t ws_size,
                              hipStream_t stream) {
  const float* x    = (const float*)d_in[0];
  const int*   ei   = (const int*)d_in[1];
  const float* w0   = (const float*)d_in[2];
  const float* att0 = (const float*)d_in[3];
  const float* b0   = (const float*)d_in[4];
  const float* w1   = (const float*)d_in[5];
  const float* att1 = (const float*)d_in[6];
  const float* b1   = (const float*)d_in[7];
  float* out = (float*)d_out;

  char* ws = (char*)d_ws;
  size_t off = 0;
  auto alloc = [&](size_t bytes) -> void* {
    void* p = ws + off;
    off += (bytes + 255) & ~(size_t)255;
    return p;
  };
  float* h0  = (float*)alloc((size_t)N_NODES * HC0 * 4);   // 30.72 MB
  float* o0  = (float*)alloc((size_t)N_NODES * HC0 * 4);   // 30.72 MB
  float* al0 = (float*)alloc((size_t)N_NODES * HEADS * 4);
  float* ar0 = (float*)alloc((size_t)N_NODES * HEADS * 4);
  int* deg      = (int*)alloc((size_t)N_NODES * 4);
  int* rowstart = (int*)alloc((size_t)(N_NODES + 1) * 4);
  int* fill     = (int*)alloc((size_t)N_NODES * 4);
  int* scol     = (int*)alloc((size_t)N_EDGESN * 4);
  // aliases: layer-0 buffers are dead once layer-0 aggregation finished
  float* h1  = h0;    // N x 160 fits in N x 256 region
  float* al1 = al0;
  float* ar1 = ar0;

  const int* srcp = ei;
  const int* dstp = ei + N_EDGESN;

  hipMemsetAsync(deg, 0, N_NODES * 4, stream);
  hipMemsetAsync(fill, 0, N_NODES * 4, stream);
  hist_kernel<<<(N_EDGESN + 255) / 256, 256, 0, stream>>>(srcp, deg, N_EDGESN);
  scan_kernel<<<1, 1024, 0, stream>>>(deg, rowstart, N_NODES);
  scatter_kernel<<<(N_EDGESN + 255) / 256, 256, 0, stream>>>(srcp, dstp, rowstart,
                                                             fill, scol, N_EDGESN);
  // layer 0
  dim3 g0((N_NODES + 63) / 64, HC0 / 64);
  gemm_f32<<<g0, 256, 0, stream>>>(x, w0, h0, N_NODES, NFEAT, HC0);
  att_dots<C0V><<<N_NODES, 256, 0, stream>>>(h0, att0, al0, ar0, N_NODES);
  gat_agg<C0V, true><<<N_NODES, 256, 0, stream>>>(h0, al0, ar0, rowstart, scol, b0,
                                                  o0, N_NODES);
  // layer 1
  dim3 g1((N_NODES + 63) / 64, (HC1 + 63) / 64);
  gemm_f32<<<g1, 256, 0, stream>>>(o0, w1, h1, N_NODES, HC0, HC1);
  att_dots<C1V><<<N_NODES, 256, 0, stream>>>(h1, att1, al1, ar1, N_NODES);
  gat_agg<C1V, false><<<N_NODES, 256, 0, stream>>>(h1, al1, ar1, rowstart, scol, b1,
                                                   out, N_NODES);
}

// Round 2
// 363.721 us; speedup vs baseline: 1.3856x; 1.3856x over previous
//
#include <hip/hip_runtime.h>
#include <math.h>

#define N_NODES 30000
#define N_EDGESN 480000
#define NFEAT 256
#define HEADS 4
#define C0V 64
#define C1V 40
#define HC0 (HEADS*C0V)   // 256
#define HC1 (HEADS*C1V)   // 160
#define NEG_SLOPE 0.2f
#define EPSV 1e-16f

__device__ __forceinline__ float lrelu(float x) { return x >= 0.f ? x : x * NEG_SLOPE; }

// ---------------- GEMM: C[n,M] = A[n,K] @ W[K,M], f32, 64x64 tile, 4x4/thread ----
__global__ __launch_bounds__(256) void gemm_f32(const float* __restrict__ A,
    const float* __restrict__ W, float* __restrict__ C, int n, int K, int M) {
  __shared__ float As[16][64];
  __shared__ float Bs[16][64];
  const int tid = threadIdx.x;
  const int tx = tid & 15, ty = tid >> 4;
  const int row0 = blockIdx.x * 64;
  const int col0 = blockIdx.y * 64;
  const int ar_ = tid >> 2;          // A-load: row in tile (0..63)
  const int ak = (tid & 3) << 2;     // A-load: k offset (0,4,8,12)
  const int bk = tid >> 4;           // B-load: k row (0..15)
  const int bn = (tid & 15) << 2;    // B-load: col offset
  float acc[4][4] = {};
  for (int k0 = 0; k0 < K; k0 += 16) {
    float4 va = make_float4(0.f, 0.f, 0.f, 0.f);
    const int grow = row0 + ar_;
    if (grow < n) va = *reinterpret_cast<const float4*>(A + (size_t)grow * K + k0 + ak);
    float4 vb = make_float4(0.f, 0.f, 0.f, 0.f);
    const int gcol = col0 + bn;
    if (gcol < M) vb = *reinterpret_cast<const float4*>(W + (size_t)(k0 + bk) * M + gcol);
    __syncthreads();
    As[ak + 0][ar_] = va.x; As[ak + 1][ar_] = va.y;
    As[ak + 2][ar_] = va.z; As[ak + 3][ar_] = va.w;
    *reinterpret_cast<float4*>(&Bs[bk][bn]) = vb;
    __syncthreads();
#pragma unroll
    for (int k = 0; k < 16; ++k) {
      float4 a = *reinterpret_cast<const float4*>(&As[k][ty << 2]);
      float4 b = *reinterpret_cast<const float4*>(&Bs[k][tx << 2]);
      acc[0][0] = fmaf(a.x, b.x, acc[0][0]); acc[0][1] = fmaf(a.x, b.y, acc[0][1]);
      acc[0][2] = fmaf(a.x, b.z, acc[0][2]); acc[0][3] = fmaf(a.x, b.w, acc[0][3]);
      acc[1][0] = fmaf(a.y, b.x, acc[1][0]); acc[1][1] = fmaf(a.y, b.y, acc[1][1]);
      acc[1][2] = fmaf(a.y, b.z, acc[1][2]); acc[1][3] = fmaf(a.y, b.w, acc[1][3]);
      acc[2][0] = fmaf(a.z, b.x, acc[2][0]); acc[2][1] = fmaf(a.z, b.y, acc[2][1]);
      acc[2][2] = fmaf(a.z, b.z, acc[2][2]); acc[2][3] = fmaf(a.z, b.w, acc[2][3]);
      acc[3][0] = fmaf(a.w, b.x, acc[3][0]); acc[3][1] = fmaf(a.w, b.y, acc[3][1]);
      acc[3][2] = fmaf(a.w, b.z, acc[3][2]); acc[3][3] = fmaf(a.w, b.w, acc[3][3]);
    }
  }
#pragma unroll
  for (int i2 = 0; i2 < 4; ++i2) {
    const int r = row0 + (ty << 2) + i2;
    if (r < n) {
#pragma unroll
      for (int j = 0; j < 4; ++j) {
        const int c = col0 + (tx << 2) + j;
        if (c < M) C[(size_t)r * M + c] = acc[i2][j];
      }
    }
  }
}

// ---------------- per-node attention dot products ------------------------------
template <int C>
__global__ __launch_bounds__(256) void att_dots(const float* __restrict__ h,
    const float* __restrict__ att, float* __restrict__ al, float* __restrict__ ar,
    int n) {
  const int i = blockIdx.x;
  const int hd = threadIdx.x >> 6, lane = threadIdx.x & 63;
  float hv = 0.f, wl = 0.f, wr = 0.f;
  if (lane < C) {
    hv = h[((size_t)i * HEADS + hd) * C + lane];
    wl = att[hd * 2 * C + lane];
    wr = att[hd * 2 * C + C + lane];
  }
  float pl = hv * wl, pr = hv * wr;
#pragma unroll
  for (int o = 32; o; o >>= 1) { pl += __shfl_xor(pl, o); pr += __shfl_xor(pr, o); }
  if (lane == 0) { al[(size_t)i * HEADS + hd] = pl; ar[(size_t)i * HEADS + hd] = pr; }
}

// ---------------- CSR build ----------------------------------------------------
__global__ void hist_kernel(const int* __restrict__ src, int* __restrict__ deg, int E) {
  const int e = blockIdx.x * blockDim.x + threadIdx.x;
  if (e < E) atomicAdd(&deg[src[e]], 1);
}

__global__ __launch_bounds__(1024) void scan_kernel(const int* __restrict__ deg,
    int* __restrict__ rowstart, int n) {
  __shared__ int carry;
  __shared__ int wsum[16];
  const int tid = threadIdx.x;
  const int lane = tid & 63, w = tid >> 6;
  if (tid == 0) { carry = 0; rowstart[0] = 0; }
  __syncthreads();
  for (int base = 0; base < n; base += 1024) {
    const int idx = base + tid;
    int x = (idx < n) ? deg[idx] : 0;
#pragma unroll
    for (int o = 1; o < 64; o <<= 1) { int y = __shfl_up(x, o); if (lane >= o) x += y; }
    if (lane == 63) wsum[w] = x;
    __syncthreads();
    if (w == 0) {
      int s = (lane < 16) ? wsum[lane] : 0;
#pragma unroll
      for (int o = 1; o < 16; o <<= 1) { int y = __shfl_up(s, o); if (lane >= o) s += y; }
      if (lane < 16) wsum[lane] = s;
    }
    __syncthreads();
    const int add = (w > 0 ? wsum[w - 1] : 0) + carry;
    if (idx < n) rowstart[idx + 1] = x + add;
    __syncthreads();
    if (tid == 0) carry += wsum[15];
    __syncthreads();
  }
}

__global__ void scatter_kernel(const int* __restrict__ src, const int* __restrict__ dst,
    const int* __restrict__ rowstart, int* __restrict__ fill, int* __restrict__ scol,
    int E) {
  const int e = blockIdx.x * blockDim.x + threadIdx.x;
  if (e < E) {
    const int r = src[e];
    const int pos = rowstart[r] + atomicAdd(&fill[r], 1);
    scol[pos] = dst[e];
  }
}

// ---------------- fused softmax + aggregation, ONE WAVE PER NODE ---------------
// All 4 heads handled by one wave. Each lane loads a float4 of the full
// HEADS*C row -> one 1KB (layer0) / 640B (layer1) row load per edge, one instr.
// CONCAT_RELU: layer0 (concat heads + relu). else: mean over heads (layer1).
template <int C, bool CONCAT_RELU>
__global__ __launch_bounds__(256) void gat_agg2(const float* __restrict__ h,
    const float* __restrict__ al, const float* __restrict__ ar,
    const int* __restrict__ rowstart, const int* __restrict__ scol,
    const float* __restrict__ bias, float* __restrict__ out, int n) {
  constexpr int ROW = HEADS * C;       // 256 or 160
  constexpr int NL = ROW / 4;          // lanes carrying the row: 64 or 40
  __shared__ float sm[4][CONCAT_RELU ? 1 : ROW];
  const int wid = threadIdx.x >> 6, lane = threadIdx.x & 63;
  const int i = blockIdx.x * 4 + wid;
  if (i >= n) return;                  // never taken: N_NODES % 4 == 0
  const int s0 = rowstart[i], s1 = rowstart[i + 1];

  const float4 al4 = *reinterpret_cast<const float4*>(al + (size_t)i * 4);
  const float4 ari = *reinterpret_cast<const float4*>(ar + (size_t)i * 4);
  const float as0 = lrelu(al4.x + ari.x), as1 = lrelu(al4.y + ari.y);
  const float as2 = lrelu(al4.z + ari.z), as3 = lrelu(al4.w + ari.w);

  // ---- pass 1: per-head max (lane-parallel over edges, 4 heads per lane) ----
  float m0 = as0, m1 = as1, m2 = as2, m3 = as3;
  for (int e = s0 + lane; e < s1; e += 64) {
    const int j = scol[e];
    const float4 a = *reinterpret_cast<const float4*>(ar + (size_t)j * 4);
    m0 = fmaxf(m0, lrelu(al4.x + a.x));
    m1 = fmaxf(m1, lrelu(al4.y + a.y));
    m2 = fmaxf(m2, lrelu(al4.z + a.z));
    m3 = fmaxf(m3, lrelu(al4.w + a.w));
  }
#pragma unroll
  for (int o = 32; o; o >>= 1) {
    m0 = fmaxf(m0, __shfl_xor(m0, o)); m1 = fmaxf(m1, __shfl_xor(m1, o));
    m2 = fmaxf(m2, __shfl_xor(m2, o)); m3 = fmaxf(m3, __shfl_xor(m3, o));
  }
  // ---- pass 2: per-head sum of exp ----
  float t0 = 0.f, t1 = 0.f, t2 = 0.f, t3 = 0.f;
  for (int e = s0 + lane; e < s1; e += 64) {
    const int j = scol[e];
    const float4 a = *reinterpret_cast<const float4*>(ar + (size_t)j * 4);
    t0 += __expf(lrelu(al4.x + a.x) - m0);
    t1 += __expf(lrelu(al4.y + a.y) - m1);
    t2 += __expf(lrelu(al4.z + a.z) - m2);
    t3 += __expf(lrelu(al4.w + a.w) - m3);
  }
#pragma unroll
  for (int o = 32; o; o >>= 1) {
    t0 += __shfl_xor(t0, o); t1 += __shfl_xor(t1, o);
    t2 += __shfl_xor(t2, o); t3 += __shfl_xor(t3, o);
  }
  const float ws0 = __expf(as0 - m0), ws1 = __expf(as1 - m1);
  const float ws2 = __expf(as2 - m2), ws3 = __expf(as3 - m3);
  const float i0 = 1.f / (t0 + ws0 + EPSV), i1 = 1.f / (t1 + ws1 + EPSV);
  const float i2 = 1.f / (t2 + ws2 + EPSV), i3 = 1.f / (t3 + ws3 + EPSV);

  // ---- per-lane head selection (branchless selects, no runtime-indexed array)
  const int hd = CONCAT_RELU ? (lane >> 4) : (lane < NL ? (4 * lane) / C : 3);
  const float al_h  = hd < 2 ? (hd == 0 ? al4.x : al4.y) : (hd == 2 ? al4.z : al4.w);
  const float m_h   = hd < 2 ? (hd == 0 ? m0 : m1) : (hd == 2 ? m2 : m3);
  const float inv_h = hd < 2 ? (hd == 0 ? i0 : i1) : (hd == 2 ? i2 : i3);
  const float ws_h  = hd < 2 ? (hd == 0 ? ws0 : ws1) : (hd == 2 ? ws2 : ws3);

  // ---- pass 3: weighted aggregation, float4 per lane over the full row ----
  const bool act = lane < NL;
  float4 acc = make_float4(0.f, 0.f, 0.f, 0.f);
  {
    const float wself = ws_h * inv_h;
    if (act) {
      const float4 hv = *reinterpret_cast<const float4*>(h + (size_t)i * ROW + 4 * lane);
      acc.x = wself * hv.x; acc.y = wself * hv.y;
      acc.z = wself * hv.z; acc.w = wself * hv.w;
    }
  }
  for (int e0 = s0; e0 < s1; e0 += 64) {
    const int cnt = min(64, s1 - e0);
    int jl = 0;
    if (lane < cnt) jl = scol[e0 + lane];
    for (int t = 0; t < cnt; ++t) {
      const int j = __shfl(jl, t);
      const float arj = ar[(size_t)j * 4 + hd];            // 4B, 16-lane broadcast
      const float w = __expf(lrelu(al_h + arj) - m_h) * inv_h;
      if (act) {
        const float4 hv = *reinterpret_cast<const float4*>(h + (size_t)j * ROW + 4 * lane);
        acc.x = fmaf(w, hv.x, acc.x); acc.y = fmaf(w, hv.y, acc.y);
        acc.z = fmaf(w, hv.z, acc.z); acc.w = fmaf(w, hv.w, acc.w);
      }
    }
  }

  if (CONCAT_RELU) {
    // out row = ROW floats; add bias, relu, float4 store
    const float4 b4 = *reinterpret_cast<const float4*>(bias + 4 * lane);
    float4 v;
    v.x = fmaxf(acc.x + b4.x, 0.f); v.y = fmaxf(acc.y + b4.y, 0.f);
    v.z = fmaxf(acc.z + b4.z, 0.f); v.w = fmaxf(acc.w + b4.w, 0.f);
    *reinterpret_cast<float4*>(out + (size_t)i * ROW + 4 * lane) = v;
  } else {
    if (act) *reinterpret_cast<float4*>(&sm[wid][4 * lane]) = acc;
    __syncthreads();   // all 256 threads reach (no early return for this grid)
    if (lane < C / 4) {
      const float4 v0 = *reinterpret_cast<const float4*>(&sm[wid][0 * C + 4 * lane]);
      const float4 v1 = *reinterpret_cast<const float4*>(&sm[wid][1 * C + 4 * lane]);
      const float4 v2 = *reinterpret_cast<const float4*>(&sm[wid][2 * C + 4 * lane]);
      const float4 v3 = *reinterpret_cast<const float4*>(&sm[wid][3 * C + 4 * lane]);
      const float4 b4 = *reinterpret_cast<const float4*>(bias + 4 * lane);
      float4 v;
      v.x = (v0.x + v1.x + v2.x + v3.x) * 0.25f + b4.x;
      v.y = (v0.y + v1.y + v2.y + v3.y) * 0.25f + b4.y;
      v.z = (v0.z + v1.z + v2.z + v3.z) * 0.25f + b4.z;
      v.w = (v0.w + v1.w + v2.w + v3.w) * 0.25f + b4.w;
      *reinterpret_cast<float4*>(out + (size_t)i * C + 4 * lane) = v;
    }
  }
}

// ---------------- launch -------------------------------------------------------
extern "C" void kernel_launch(void* const* d_in, const int* in_sizes, int n_in,
                              void* d_out, int out_size, void* d_ws, size_t ws_size,
                              hipStream_t stream) {
  const float* x    = (const float*)d_in[0];
  const int*   ei   = (const int*)d_in[1];
  const float* w0   = (const float*)d_in[2];
  const float* att0 = (const float*)d_in[3];
  const float* b0   = (const float*)d_in[4];
  const float* w1   = (const float*)d_in[5];
  const float* att1 = (const float*)d_in[6];
  const float* b1   = (const float*)d_in[7];
  float* out = (float*)d_out;

  char* ws = (char*)d_ws;
  size_t off = 0;
  auto alloc = [&](size_t bytes) -> void* {
    void* p = ws + off;
    off += (bytes + 255) & ~(size_t)255;
    return p;
  };
  float* h0  = (float*)alloc((size_t)N_NODES * HC0 * 4);   // 30.72 MB
  float* o0  = (float*)alloc((size_t)N_NODES * HC0 * 4);   // 30.72 MB
  float* al0 = (float*)alloc((size_t)N_NODES * HEADS * 4);
  float* ar0 = (float*)alloc((size_t)N_NODES * HEADS * 4);
  int* deg      = (int*)alloc((size_t)N_NODES * 4);
  int* rowstart = (int*)alloc((size_t)(N_NODES + 1) * 4);
  int* fill     = (int*)alloc((size_t)N_NODES * 4);
  int* scol     = (int*)alloc((size_t)N_EDGESN * 4);
  // aliases: layer-0 buffers are dead once layer-0 aggregation finished
  float* h1  = h0;    // N x 160 fits in N x 256 region
  float* al1 = al0;
  float* ar1 = ar0;

  const int* srcp = ei;
  const int* dstp = ei + N_EDGESN;

  hipMemsetAsync(deg, 0, N_NODES * 4, stream);
  hipMemsetAsync(fill, 0, N_NODES * 4, stream);
  hist_kernel<<<(N_EDGESN + 255) / 256, 256, 0, stream>>>(srcp, deg, N_EDGESN);
  scan_kernel<<<1, 1024, 0, stream>>>(deg, rowstart, N_NODES);
  scatter_kernel<<<(N_EDGESN + 255) / 256, 256, 0, stream>>>(srcp, dstp, rowstart,
                                                             fill, scol, N_EDGESN);
  // layer 0
  dim3 g0((N_NODES + 63) / 64, HC0 / 64);
  gemm_f32<<<g0, 256, 0, stream>>>(x, w0, h0, N_NODES, NFEAT, HC0);
  att_dots<C0V><<<N_NODES, 256, 0, stream>>>(h0, att0, al0, ar0, N_NODES);
  gat_agg2<C0V, true><<<(N_NODES + 3) / 4, 256, 0, stream>>>(h0, al0, ar0, rowstart,
                                                             scol, b0, o0, N_NODES);
  // layer 1
  dim3 g1((N_NODES + 63) / 64, (HC1 + 63) / 64);
  gemm_f32<<<g1, 256, 0, stream>>>(o0, w1, h1, N_NODES, HC0, HC1);
  att_dots<C1V><<<N_NODES, 256, 0, stream>>>(h1, att1, al1, ar1, N_NODES);
  gat_agg2<C1V, false><<<(N_NODES + 3) / 4, 256, 0, stream>>>(h1, al1, ar1, rowstart,
                                                              scol, b1, out, N_NODES);
}

// Round 3
// 333.815 us; speedup vs baseline: 1.5097x; 1.0896x over previous
//
#include <hip/hip_runtime.h>
#include <math.h>

#define N_NODES 30000
#define N_EDGESN 480000
#define NFEAT 256
#define HEADS 4
#define C0V 64
#define C1V 40
#define HC0 (HEADS*C0V)   // 256
#define HC1 (HEADS*C1V)   // 160
#define NEG_SLOPE 0.2f
#define EPSV 1e-16f

__device__ __forceinline__ float lrelu(float x) { return x >= 0.f ? x : x * NEG_SLOPE; }

__device__ __forceinline__ float b2f(unsigned int u16) {
  union { unsigned int u; float f; } v; v.u = u16 << 16; return v.f;
}
__device__ __forceinline__ unsigned short f2b(float f) {
  union { float f; unsigned int u; } v; v.f = f;
  unsigned int u = v.u + 0x7FFFu + ((v.u >> 16) & 1u);   // round-nearest-even
  return (unsigned short)(u >> 16);
}

// ---- GEMM: C[n,M] = A[n,K] @ W[K,M], f32 math, bf16 output, 64x64 tile --------
__global__ __launch_bounds__(256) void gemm_f32_b16o(const float* __restrict__ A,
    const float* __restrict__ W, unsigned short* __restrict__ C, int n, int K, int M) {
  __shared__ float As[16][64];
  __shared__ float Bs[16][64];
  const int tid = threadIdx.x;
  const int tx = tid & 15, ty = tid >> 4;
  const int row0 = blockIdx.x * 64;
  const int col0 = blockIdx.y * 64;
  const int ar_ = tid >> 2;
  const int ak = (tid & 3) << 2;
  const int bk = tid >> 4;
  const int bn = (tid & 15) << 2;
  float acc[4][4] = {};
  for (int k0 = 0; k0 < K; k0 += 16) {
    float4 va = make_float4(0.f, 0.f, 0.f, 0.f);
    const int grow = row0 + ar_;
    if (grow < n) va = *reinterpret_cast<const float4*>(A + (size_t)grow * K + k0 + ak);
    float4 vb = make_float4(0.f, 0.f, 0.f, 0.f);
    const int gcol = col0 + bn;
    if (gcol < M) vb = *reinterpret_cast<const float4*>(W + (size_t)(k0 + bk) * M + gcol);
    __syncthreads();
    As[ak + 0][ar_] = va.x; As[ak + 1][ar_] = va.y;
    As[ak + 2][ar_] = va.z; As[ak + 3][ar_] = va.w;
    *reinterpret_cast<float4*>(&Bs[bk][bn]) = vb;
    __syncthreads();
#pragma unroll
    for (int k = 0; k < 16; ++k) {
      float4 a = *reinterpret_cast<const float4*>(&As[k][ty << 2]);
      float4 b = *reinterpret_cast<const float4*>(&Bs[k][tx << 2]);
      acc[0][0] = fmaf(a.x, b.x, acc[0][0]); acc[0][1] = fmaf(a.x, b.y, acc[0][1]);
      acc[0][2] = fmaf(a.x, b.z, acc[0][2]); acc[0][3] = fmaf(a.x, b.w, acc[0][3]);
      acc[1][0] = fmaf(a.y, b.x, acc[1][0]); acc[1][1] = fmaf(a.y, b.y, acc[1][1]);
      acc[1][2] = fmaf(a.y, b.z, acc[1][2]); acc[1][3] = fmaf(a.y, b.w, acc[1][3]);
      acc[2][0] = fmaf(a.z, b.x, acc[2][0]); acc[2][1] = fmaf(a.z, b.y, acc[2][1]);
      acc[2][2] = fmaf(a.z, b.z, acc[2][2]); acc[2][3] = fmaf(a.z, b.w, acc[2][3]);
      acc[3][0] = fmaf(a.w, b.x, acc[3][0]); acc[3][1] = fmaf(a.w, b.y, acc[3][1]);
      acc[3][2] = fmaf(a.w, b.z, acc[3][2]); acc[3][3] = fmaf(a.w, b.w, acc[3][3]);
    }
  }
#pragma unroll
  for (int i2 = 0; i2 < 4; ++i2) {
    const int r = row0 + (ty << 2) + i2;
    if (r < n) {
      const int c = col0 + (tx << 2);
      if (c < M) {
        ushort4 v;
        v.x = f2b(acc[i2][0]); v.y = f2b(acc[i2][1]);
        v.z = f2b(acc[i2][2]); v.w = f2b(acc[i2][3]);
        *reinterpret_cast<ushort4*>(C + (size_t)r * M + c) = v;  // M%4==0
      }
    }
  }
}

// ---- per-node attention dot products (bf16 h) ---------------------------------
template <int C>
__global__ __launch_bounds__(256) void att_dots(const unsigned short* __restrict__ h,
    const float* __restrict__ att, float* __restrict__ al, float* __restrict__ ar,
    int n) {
  const int i = blockIdx.x;
  const int hd = threadIdx.x >> 6, lane = threadIdx.x & 63;
  float hv = 0.f, wl = 0.f, wr = 0.f;
  if (lane < C) {
    hv = b2f(h[((size_t)i * HEADS + hd) * C + lane]);
    wl = att[hd * 2 * C + lane];
    wr = att[hd * 2 * C + C + lane];
  }
  float pl = hv * wl, pr = hv * wr;
#pragma unroll
  for (int o = 32; o; o >>= 1) { pl += __shfl_xor(pl, o); pr += __shfl_xor(pr, o); }
  if (lane == 0) { al[(size_t)i * HEADS + hd] = pl; ar[(size_t)i * HEADS + hd] = pr; }
}

// ---- CSR build ----------------------------------------------------------------
__global__ void hist_kernel(const int* __restrict__ src, int* __restrict__ deg, int E) {
  const int e = blockIdx.x * blockDim.x + threadIdx.x;
  if (e < E) atomicAdd(&deg[src[e]], 1);
}

__global__ __launch_bounds__(1024) void scan_kernel(const int* __restrict__ deg,
    int* __restrict__ rowstart, int n) {
  __shared__ int carry;
  __shared__ int wsum[16];
  const int tid = threadIdx.x;
  const int lane = tid & 63, w = tid >> 6;
  if (tid == 0) { carry = 0; rowstart[0] = 0; }
  __syncthreads();
  for (int base = 0; base < n; base += 1024) {
    const int idx = base + tid;
    int x = (idx < n) ? deg[idx] : 0;
#pragma unroll
    for (int o = 1; o < 64; o <<= 1) { int y = __shfl_up(x, o); if (lane >= o) x += y; }
    if (lane == 63) wsum[w] = x;
    __syncthreads();
    if (w == 0) {
      int s = (lane < 16) ? wsum[lane] : 0;
#pragma unroll
      for (int o = 1; o < 16; o <<= 1) { int y = __shfl_up(s, o); if (lane >= o) s += y; }
      if (lane < 16) wsum[lane] = s;
    }
    __syncthreads();
    const int add = (w > 0 ? wsum[w - 1] : 0) + carry;
    if (idx < n) rowstart[idx + 1] = x + add;
    __syncthreads();
    if (tid == 0) carry += wsum[15];
    __syncthreads();
  }
}

__global__ void scatter_kernel(const int* __restrict__ src, const int* __restrict__ dst,
    const int* __restrict__ rowstart, int* __restrict__ fill, int* __restrict__ scol,
    int E) {
  const int e = blockIdx.x * blockDim.x + threadIdx.x;
  if (e < E) {
    const int r = src[e];
    const int pos = rowstart[r] + atomicAdd(&fill[r], 1);
    scol[pos] = dst[e];
  }
}

// ---- fused softmax + aggregation, one wave per node, bf16 h gather ------------
template <int C, bool CONCAT_RELU>
__global__ __launch_bounds__(256) void gat_agg2(const unsigned short* __restrict__ h,
    const float* __restrict__ al, const float* __restrict__ ar,
    const int* __restrict__ rowstart, const int* __restrict__ scol,
    const float* __restrict__ bias, float* __restrict__ out, int n) {
  constexpr int ROW = HEADS * C;       // 256 or 160
  constexpr int NL = ROW / 4;          // lanes carrying the row: 64 or 40
  __shared__ float sm[4][CONCAT_RELU ? 1 : ROW];
  const int wid = threadIdx.x >> 6, lane = threadIdx.x & 63;
  const int i = blockIdx.x * 4 + wid;
  if (i >= n) return;                  // never taken: grid covers n%4==0 padding
  const int s0 = rowstart[i], s1 = rowstart[i + 1];

  const float4 al4 = *reinterpret_cast<const float4*>(al + (size_t)i * 4);
  const float4 ari = *reinterpret_cast<const float4*>(ar + (size_t)i * 4);
  const float as0 = lrelu(al4.x + ari.x), as1 = lrelu(al4.y + ari.y);
  const float as2 = lrelu(al4.z + ari.z), as3 = lrelu(al4.w + ari.w);

  float m0 = as0, m1 = as1, m2 = as2, m3 = as3;
  for (int e = s0 + lane; e < s1; e += 64) {
    const int j = scol[e];
    const float4 a = *reinterpret_cast<const float4*>(ar + (size_t)j * 4);
    m0 = fmaxf(m0, lrelu(al4.x + a.x));
    m1 = fmaxf(m1, lrelu(al4.y + a.y));
    m2 = fmaxf(m2, lrelu(al4.z + a.z));
    m3 = fmaxf(m3, lrelu(al4.w + a.w));
  }
#pragma unroll
  for (int o = 32; o; o >>= 1) {
    m0 = fmaxf(m0, __shfl_xor(m0, o)); m1 = fmaxf(m1, __shfl_xor(m1, o));
    m2 = fmaxf(m2, __shfl_xor(m2, o)); m3 = fmaxf(m3, __shfl_xor(m3, o));
  }
  float t0 = 0.f, t1 = 0.f, t2 = 0.f, t3 = 0.f;
  for (int e = s0 + lane; e < s1; e += 64) {
    const int j = scol[e];
    const float4 a = *reinterpret_cast<const float4*>(ar + (size_t)j * 4);
    t0 += __expf(lrelu(al4.x + a.x) - m0);
    t1 += __expf(lrelu(al4.y + a.y) - m1);
    t2 += __expf(lrelu(al4.z + a.z) - m2);
    t3 += __expf(lrelu(al4.w + a.w) - m3);
  }
#pragma unroll
  for (int o = 32; o; o >>= 1) {
    t0 += __shfl_xor(t0, o); t1 += __shfl_xor(t1, o);
    t2 += __shfl_xor(t2, o); t3 += __shfl_xor(t3, o);
  }
  const float ws0 = __expf(as0 - m0), ws1 = __expf(as1 - m1);
  const float ws2 = __expf(as2 - m2), ws3 = __expf(as3 - m3);
  const float i0 = 1.f / (t0 + ws0 + EPSV), i1 = 1.f / (t1 + ws1 + EPSV);
  const float i2 = 1.f / (t2 + ws2 + EPSV), i3 = 1.f / (t3 + ws3 + EPSV);

  const int hd = CONCAT_RELU ? (lane >> 4) : (lane < NL ? (4 * lane) / C : 3);
  const float al_h  = hd < 2 ? (hd == 0 ? al4.x : al4.y) : (hd == 2 ? al4.z : al4.w);
  const float m_h   = hd < 2 ? (hd == 0 ? m0 : m1) : (hd == 2 ? m2 : m3);
  const float inv_h = hd < 2 ? (hd == 0 ? i0 : i1) : (hd == 2 ? i2 : i3);
  const float ws_h  = hd < 2 ? (hd == 0 ? ws0 : ws1) : (hd == 2 ? ws2 : ws3);

  const bool act = lane < NL;
  float4 acc = make_float4(0.f, 0.f, 0.f, 0.f);
  {
    const float wself = ws_h * inv_h;
    if (act) {
      const uint2 hv = *reinterpret_cast<const uint2*>(h + (size_t)i * ROW + 4 * lane);
      acc.x = wself * b2f(hv.x & 0xffffu); acc.y = wself * b2f(hv.x >> 16);
      acc.z = wself * b2f(hv.y & 0xffffu); acc.w = wself * b2f(hv.y >> 16);
    }
  }
  for (int e0 = s0; e0 < s1; e0 += 64) {
    const int cnt = min(64, s1 - e0);
    int jl = 0;
    if (lane < cnt) jl = scol[e0 + lane];
    for (int t = 0; t < cnt; ++t) {
      const int j = __shfl(jl, t);
      const float arj = ar[(size_t)j * 4 + hd];
      const float w = __expf(lrelu(al_h + arj) - m_h) * inv_h;
      if (act) {
        const uint2 hv = *reinterpret_cast<const uint2*>(h + (size_t)j * ROW + 4 * lane);
        acc.x = fmaf(w, b2f(hv.x & 0xffffu), acc.x);
        acc.y = fmaf(w, b2f(hv.x >> 16),     acc.y);
        acc.z = fmaf(w, b2f(hv.y & 0xffffu), acc.z);
        acc.w = fmaf(w, b2f(hv.y >> 16),     acc.w);
      }
    }
  }

  if (CONCAT_RELU) {
    const float4 b4 = *reinterpret_cast<const float4*>(bias + 4 * lane);
    float4 v;
    v.x = fmaxf(acc.x + b4.x, 0.f); v.y = fmaxf(acc.y + b4.y, 0.f);
    v.z = fmaxf(acc.z + b4.z, 0.f); v.w = fmaxf(acc.w + b4.w, 0.f);
    *reinterpret_cast<float4*>(out + (size_t)i * ROW + 4 * lane) = v;
  } else {
    if (act) *reinterpret_cast<float4*>(&sm[wid][4 * lane]) = acc;
    __syncthreads();
    if (lane < C / 4) {
      const float4 v0 = *reinterpret_cast<const float4*>(&sm[wid][0 * C + 4 * lane]);
      const float4 v1 = *reinterpret_cast<const float4*>(&sm[wid][1 * C + 4 * lane]);
      const float4 v2 = *reinterpret_cast<const float4*>(&sm[wid][2 * C + 4 * lane]);
      const float4 v3 = *reinterpret_cast<const float4*>(&sm[wid][3 * C + 4 * lane]);
      const float4 b4 = *reinterpret_cast<const float4*>(bias + 4 * lane);
      float4 v;
      v.x = (v0.x + v1.x + v2.x + v3.x) * 0.25f + b4.x;
      v.y = (v0.y + v1.y + v2.y + v3.y) * 0.25f + b4.y;
      v.z = (v0.z + v1.z + v2.z + v3.z) * 0.25f + b4.z;
      v.w = (v0.w + v1.w + v2.w + v3.w) * 0.25f + b4.w;
      *reinterpret_cast<float4*>(out + (size_t)i * C + 4 * lane) = v;
    }
  }
}

// ---- launch -------------------------------------------------------------------
extern "C" void kernel_launch(void* const* d_in, const int* in_sizes, int n_in,
                              void* d_out, int out_size, void* d_ws, size_t ws_size,
                              hipStream_t stream) {
  const float* x    = (const float*)d_in[0];
  const int*   ei   = (const int*)d_in[1];
  const float* w0   = (const float*)d_in[2];
  const float* att0 = (const float*)d_in[3];
  const float* b0   = (const float*)d_in[4];
  const float* w1   = (const float*)d_in[5];
  const float* att1 = (const float*)d_in[6];
  const float* b1   = (const float*)d_in[7];
  float* out = (float*)d_out;

  char* ws = (char*)d_ws;
  size_t off = 0;
  auto alloc = [&](size_t bytes) -> void* {
    void* p = ws + off;
    off += (bytes + 255) & ~(size_t)255;
    return p;
  };
  unsigned short* h0 = (unsigned short*)alloc((size_t)N_NODES * HC0 * 2);  // 15.4 MB
  float* o0  = (float*)alloc((size_t)N_NODES * HC0 * 4);                   // 30.7 MB
  float* al0 = (float*)alloc((size_t)N_NODES * HEADS * 4);
  float* ar0 = (float*)alloc((size_t)N_NODES * HEADS * 4);
  int* deg      = (int*)alloc((size_t)N_NODES * 4);
  int* rowstart = (int*)alloc((size_t)(N_NODES + 1) * 4);
  int* fill     = (int*)alloc((size_t)N_NODES * 4);
  int* scol     = (int*)alloc((size_t)N_EDGESN * 4);
  unsigned short* h1 = h0;    // N x 160 bf16 fits in N x 256 bf16 region
  float* al1 = al0;
  float* ar1 = ar0;

  const int* srcp = ei;
  const int* dstp = ei + N_EDGESN;

  hipMemsetAsync(deg, 0, N_NODES * 4, stream);
  hipMemsetAsync(fill, 0, N_NODES * 4, stream);
  hist_kernel<<<(N_EDGESN + 255) / 256, 256, 0, stream>>>(srcp, deg, N_EDGESN);
  scan_kernel<<<1, 1024, 0, stream>>>(deg, rowstart, N_NODES);
  scatter_kernel<<<(N_EDGESN + 255) / 256, 256, 0, stream>>>(srcp, dstp, rowstart,
                                                             fill, scol, N_EDGESN);
  // layer 0
  dim3 g0((N_NODES + 63) / 64, HC0 / 64);
  gemm_f32_b16o<<<g0, 256, 0, stream>>>(x, w0, h0, N_NODES, NFEAT, HC0);
  att_dots<C0V><<<N_NODES, 256, 0, stream>>>(h0, att0, al0, ar0, N_NODES);
  gat_agg2<C0V, true><<<(N_NODES + 3) / 4, 256, 0, stream>>>(h0, al0, ar0, rowstart,
                                                             scol, b0, o0, N_NODES);
  // layer 1
  dim3 g1((N_NODES + 63) / 64, (HC1 + 63) / 64);
  gemm_f32_b16o<<<g1, 256, 0, stream>>>(o0, w1, h1, N_NODES, HC0, HC1);
  att_dots<C1V><<<N_NODES, 256, 0, stream>>>(h1, att1, al1, ar1, N_NODES);
  gat_agg2<C1V, false><<<(N_NODES + 3) / 4, 256, 0, stream>>>(h1, al1, ar1, rowstart,
                                                              scol, b1, out, N_NODES);
}

// Round 4
// 295.915 us; speedup vs baseline: 1.7031x; 1.1281x over previous
//
#include <hip/hip_runtime.h>
#include <math.h>

#define N_NODES 30000
#define N_EDGESN 480000
#define NFEAT 256
#define HEADS 4
#define C0V 64
#define C1V 40
#define HC0 (HEADS*C0V)   // 256
#define HC1 (HEADS*C1V)   // 160
#define NEG_SLOPE 0.2f
#define EPSV 1e-16f

typedef unsigned short ushort_t;
typedef __attribute__((ext_vector_type(8))) short short8v;
typedef __attribute__((ext_vector_type(4))) float f32x4;

__device__ __forceinline__ float lrelu(float x) { return x >= 0.f ? x : x * NEG_SLOPE; }

__device__ __forceinline__ float b2f(unsigned int u16) {
  union { unsigned int u; float f; } v; v.u = u16 << 16; return v.f;
}
__device__ __forceinline__ unsigned short f2b(float f) {
  union { float f; unsigned int u; } v; v.f = f;
  unsigned int u = v.u + 0x7FFFu + ((v.u >> 16) & 1u);   // round-nearest-even
  return (unsigned short)(u >> 16);
}

// ---- W[K][N] f32 -> Wt[N][K] bf16 (tiny) --------------------------------------
template <int KK, int NN>
__global__ __launch_bounds__(256) void wtrans(const float* __restrict__ W,
                                              ushort_t* __restrict__ Wt) {
  const int idx = blockIdx.x * 256 + threadIdx.x;
  if (idx >= KK * NN) return;
  const int k = idx / NN, nf = idx - k * NN;
  Wt[(size_t)nf * KK + k] = f2b(W[idx]);
}

// ---- MFMA GEMM: C[M,N]=A[M,K]@W[K,N], A row-major (f32 or bf16), Wt[N][K] bf16
// One wave per 16-row strip, full N width (NF 16-col fragments). No LDS;
// Wt is L2-resident (128KB), B-frags loaded per k-step (16 independent loads).
template <int NF, bool A_F32>
__global__ __launch_bounds__(256) void gemm_mfma(const void* __restrict__ Ap,
    const ushort_t* __restrict__ Wt, ushort_t* __restrict__ C, int M, int K) {
  const int lane = threadIdx.x & 63;
  const int wid = threadIdx.x >> 6;
  const int row0 = (blockIdx.x * 4 + wid) * 16;
  if (row0 >= M) return;                 // no __syncthreads below: safe
  const int r_a = lane & 15;             // A-row in strip / C-col in frag
  const int kg = lane >> 4;              // k-group 0..3 (8 k each)
  const int N = NF * 16;

  f32x4 acc[NF];
#pragma unroll
  for (int f = 0; f < NF; ++f) acc[f] = (f32x4){0.f, 0.f, 0.f, 0.f};

  for (int k0 = 0; k0 < K; k0 += 32) {
    short8v a;
    if (A_F32) {
      const float* A = (const float*)Ap;
      const float* p = A + (size_t)(row0 + r_a) * K + k0 + kg * 8;
      const float4 lo = *reinterpret_cast<const float4*>(p);
      const float4 hi = *reinterpret_cast<const float4*>(p + 4);
      a[0] = (short)f2b(lo.x); a[1] = (short)f2b(lo.y);
      a[2] = (short)f2b(lo.z); a[3] = (short)f2b(lo.w);
      a[4] = (short)f2b(hi.x); a[5] = (short)f2b(hi.y);
      a[6] = (short)f2b(hi.z); a[7] = (short)f2b(hi.w);
    } else {
      const ushort_t* A = (const ushort_t*)Ap;
      a = *reinterpret_cast<const short8v*>(A + (size_t)(row0 + r_a) * K + k0 + kg * 8);
    }
#pragma unroll
    for (int f = 0; f < NF; ++f) {
      const short8v b = *reinterpret_cast<const short8v*>(
          Wt + (size_t)(f * 16 + r_a) * K + k0 + kg * 8);
      acc[f] = __builtin_amdgcn_mfma_f32_16x16x32_bf16(a, b, acc[f], 0, 0, 0);
    }
  }
  // D layout: col = lane&15, row = (lane>>4)*4 + reg
#pragma unroll
  for (int f = 0; f < NF; ++f) {
#pragma unroll
    for (int r = 0; r < 4; ++r) {
      C[(size_t)(row0 + kg * 4 + r) * N + f * 16 + r_a] = f2b(acc[f][r]);
    }
  }
}

// ---- per-node attention dot products (bf16 h) ---------------------------------
template <int C>
__global__ __launch_bounds__(256) void att_dots(const ushort_t* __restrict__ h,
    const float* __restrict__ att, float* __restrict__ al, float* __restrict__ ar,
    int n) {
  const int i = blockIdx.x;
  const int hd = threadIdx.x >> 6, lane = threadIdx.x & 63;
  float hv = 0.f, wl = 0.f, wr = 0.f;
  if (lane < C) {
    hv = b2f(h[((size_t)i * HEADS + hd) * C + lane]);
    wl = att[hd * 2 * C + lane];
    wr = att[hd * 2 * C + C + lane];
  }
  float pl = hv * wl, pr = hv * wr;
#pragma unroll
  for (int o = 32; o; o >>= 1) { pl += __shfl_xor(pl, o); pr += __shfl_xor(pr, o); }
  if (lane == 0) { al[(size_t)i * HEADS + hd] = pl; ar[(size_t)i * HEADS + hd] = pr; }
}

// ---- CSR build ----------------------------------------------------------------
__global__ void hist_kernel(const int* __restrict__ src, int* __restrict__ deg, int E) {
  const int e = blockIdx.x * blockDim.x + threadIdx.x;
  if (e < E) atomicAdd(&deg[src[e]], 1);
}

__global__ __launch_bounds__(1024) void scan_kernel(const int* __restrict__ deg,
    int* __restrict__ rowstart, int n) {
  __shared__ int carry;
  __shared__ int wsum[16];
  const int tid = threadIdx.x;
  const int lane = tid & 63, w = tid >> 6;
  if (tid == 0) { carry = 0; rowstart[0] = 0; }
  __syncthreads();
  for (int base = 0; base < n; base += 1024) {
    const int idx = base + tid;
    int x = (idx < n) ? deg[idx] : 0;
#pragma unroll
    for (int o = 1; o < 64; o <<= 1) { int y = __shfl_up(x, o); if (lane >= o) x += y; }
    if (lane == 63) wsum[w] = x;
    __syncthreads();
    if (w == 0) {
      int s = (lane < 16) ? wsum[lane] : 0;
#pragma unroll
      for (int o = 1; o < 16; o <<= 1) { int y = __shfl_up(s, o); if (lane >= o) s += y; }
      if (lane < 16) wsum[lane] = s;
    }
    __syncthreads();
    const int add = (w > 0 ? wsum[w - 1] : 0) + carry;
    if (idx < n) rowstart[idx + 1] = x + add;
    __syncthreads();
    if (tid == 0) carry += wsum[15];
    __syncthreads();
  }
}

__global__ void scatter_kernel(const int* __restrict__ src, const int* __restrict__ dst,
    const int* __restrict__ rowstart, int* __restrict__ fill, int* __restrict__ scol,
    int E) {
  const int e = blockIdx.x * blockDim.x + threadIdx.x;
  if (e < E) {
    const int r = src[e];
    const int pos = rowstart[r] + atomicAdd(&fill[r], 1);
    scol[pos] = dst[e];
  }
}

// ---- fused softmax + aggregation, one wave per node, bf16 h gather ------------
// CONCAT_RELU: layer0, bf16 output (feeds MFMA GEMM1). else: f32 head-mean out.
template <int C, bool CONCAT_RELU>
__global__ __launch_bounds__(256) void gat_agg2(const ushort_t* __restrict__ h,
    const float* __restrict__ al, const float* __restrict__ ar,
    const int* __restrict__ rowstart, const int* __restrict__ scol,
    const float* __restrict__ bias, void* __restrict__ outv, int n) {
  constexpr int ROW = HEADS * C;       // 256 or 160
  constexpr int NL = ROW / 4;          // lanes carrying the row: 64 or 40
  __shared__ float sm[4][CONCAT_RELU ? 1 : ROW];
  const int wid = threadIdx.x >> 6, lane = threadIdx.x & 63;
  const int i = blockIdx.x * 4 + wid;
  if (i >= n) return;
  const int s0 = rowstart[i], s1 = rowstart[i + 1];

  const float4 al4 = *reinterpret_cast<const float4*>(al + (size_t)i * 4);
  const float4 ari = *reinterpret_cast<const float4*>(ar + (size_t)i * 4);
  const float as0 = lrelu(al4.x + ari.x), as1 = lrelu(al4.y + ari.y);
  const float as2 = lrelu(al4.z + ari.z), as3 = lrelu(al4.w + ari.w);

  float m0 = as0, m1 = as1, m2 = as2, m3 = as3;
  for (int e = s0 + lane; e < s1; e += 64) {
    const int j = scol[e];
    const float4 a = *reinterpret_cast<const float4*>(ar + (size_t)j * 4);
    m0 = fmaxf(m0, lrelu(al4.x + a.x));
    m1 = fmaxf(m1, lrelu(al4.y + a.y));
    m2 = fmaxf(m2, lrelu(al4.z + a.z));
    m3 = fmaxf(m3, lrelu(al4.w + a.w));
  }
#pragma unroll
  for (int o = 32; o; o >>= 1) {
    m0 = fmaxf(m0, __shfl_xor(m0, o)); m1 = fmaxf(m1, __shfl_xor(m1, o));
    m2 = fmaxf(m2, __shfl_xor(m2, o)); m3 = fmaxf(m3, __shfl_xor(m3, o));
  }
  float t0 = 0.f, t1 = 0.f, t2 = 0.f, t3 = 0.f;
  for (int e = s0 + lane; e < s1; e += 64) {
    const int j = scol[e];
    const float4 a = *reinterpret_cast<const float4*>(ar + (size_t)j * 4);
    t0 += __expf(lrelu(al4.x + a.x) - m0);
    t1 += __expf(lrelu(al4.y + a.y) - m1);
    t2 += __expf(lrelu(al4.z + a.z) - m2);
    t3 += __expf(lrelu(al4.w + a.w) - m3);
  }
#pragma unroll
  for (int o = 32; o; o >>= 1) {
    t0 += __shfl_xor(t0, o); t1 += __shfl_xor(t1, o);
    t2 += __shfl_xor(t2, o); t3 += __shfl_xor(t3, o);
  }
  const float ws0 = __expf(as0 - m0), ws1 = __expf(as1 - m1);
  const float ws2 = __expf(as2 - m2), ws3 = __expf(as3 - m3);
  const float i0 = 1.f / (t0 + ws0 + EPSV), i1 = 1.f / (t1 + ws1 + EPSV);
  const float i2 = 1.f / (t2 + ws2 + EPSV), i3 = 1.f / (t3 + ws3 + EPSV);

  const int hd = CONCAT_RELU ? (lane >> 4) : (lane < NL ? (4 * lane) / C : 3);
  const float al_h  = hd < 2 ? (hd == 0 ? al4.x : al4.y) : (hd == 2 ? al4.z : al4.w);
  const float m_h   = hd < 2 ? (hd == 0 ? m0 : m1) : (hd == 2 ? m2 : m3);
  const float inv_h = hd < 2 ? (hd == 0 ? i0 : i1) : (hd == 2 ? i2 : i3);
  const float ws_h  = hd < 2 ? (hd == 0 ? ws0 : ws1) : (hd == 2 ? ws2 : ws3);

  const bool act = lane < NL;
  float4 acc = make_float4(0.f, 0.f, 0.f, 0.f);
  {
    const float wself = ws_h * inv_h;
    if (act) {
      const uint2 hv = *reinterpret_cast<const uint2*>(h + (size_t)i * ROW + 4 * lane);
      acc.x = wself * b2f(hv.x & 0xffffu); acc.y = wself * b2f(hv.x >> 16);
      acc.z = wself * b2f(hv.y & 0xffffu); acc.w = wself * b2f(hv.y >> 16);
    }
  }
  for (int e0 = s0; e0 < s1; e0 += 64) {
    const int cnt = min(64, s1 - e0);
    int jl = 0;
    if (lane < cnt) jl = scol[e0 + lane];
    for (int t = 0; t < cnt; ++t) {
      const int j = __shfl(jl, t);
      const float arj = ar[(size_t)j * 4 + hd];
      const float w = __expf(lrelu(al_h + arj) - m_h) * inv_h;
      if (act) {
        const uint2 hv = *reinterpret_cast<const uint2*>(h + (size_t)j * ROW + 4 * lane);
        acc.x = fmaf(w, b2f(hv.x & 0xffffu), acc.x);
        acc.y = fmaf(w, b2f(hv.x >> 16),     acc.y);
        acc.z = fmaf(w, b2f(hv.y & 0xffffu), acc.z);
        acc.w = fmaf(w, b2f(hv.y >> 16),     acc.w);
      }
    }
  }

  if (CONCAT_RELU) {
    ushort_t* out = (ushort_t*)outv;
    const float4 b4 = *reinterpret_cast<const float4*>(bias + 4 * lane);
    ushort4 v;
    v.x = f2b(fmaxf(acc.x + b4.x, 0.f)); v.y = f2b(fmaxf(acc.y + b4.y, 0.f));
    v.z = f2b(fmaxf(acc.z + b4.z, 0.f)); v.w = f2b(fmaxf(acc.w + b4.w, 0.f));
    *reinterpret_cast<ushort4*>(out + (size_t)i * ROW + 4 * lane) = v;
  } else {
    float* out = (float*)outv;
    if (act) *reinterpret_cast<float4*>(&sm[wid][4 * lane]) = acc;
    __syncthreads();
    if (lane < C / 4) {
      const float4 v0 = *reinterpret_cast<const float4*>(&sm[wid][0 * C + 4 * lane]);
      const float4 v1 = *reinterpret_cast<const float4*>(&sm[wid][1 * C + 4 * lane]);
      const float4 v2 = *reinterpret_cast<const float4*>(&sm[wid][2 * C + 4 * lane]);
      const float4 v3 = *reinterpret_cast<const float4*>(&sm[wid][3 * C + 4 * lane]);
      const float4 b4 = *reinterpret_cast<const float4*>(bias + 4 * lane);
      float4 v;
      v.x = (v0.x + v1.x + v2.x + v3.x) * 0.25f + b4.x;
      v.y = (v0.y + v1.y + v2.y + v3.y) * 0.25f + b4.y;
      v.z = (v0.z + v1.z + v2.z + v3.z) * 0.25f + b4.z;
      v.w = (v0.w + v1.w + v2.w + v3.w) * 0.25f + b4.w;
      *reinterpret_cast<float4*>(out + (size_t)i * C + 4 * lane) = v;
    }
  }
}

// ---- launch -------------------------------------------------------------------
extern "C" void kernel_launch(void* const* d_in, const int* in_sizes, int n_in,
                              void* d_out, int out_size, void* d_ws, size_t ws_size,
                              hipStream_t stream) {
  const float* x    = (const float*)d_in[0];
  const int*   ei   = (const int*)d_in[1];
  const float* w0   = (const float*)d_in[2];
  const float* att0 = (const float*)d_in[3];
  const float* b0   = (const float*)d_in[4];
  const float* w1   = (const float*)d_in[5];
  const float* att1 = (const float*)d_in[6];
  const float* b1   = (const float*)d_in[7];
  float* out = (float*)d_out;

  char* ws = (char*)d_ws;
  size_t off = 0;
  auto alloc = [&](size_t bytes) -> void* {
    void* p = ws + off;
    off += (bytes + 255) & ~(size_t)255;
    return p;
  };
  ushort_t* h0b = (ushort_t*)alloc((size_t)N_NODES * HC0 * 2);  // 15.4 MB
  ushort_t* o0b = (ushort_t*)alloc((size_t)N_NODES * HC0 * 2);  // 15.4 MB
  float* al0 = (float*)alloc((size_t)N_NODES * HEADS * 4);
  float* ar0 = (float*)alloc((size_t)N_NODES * HEADS * 4);
  ushort_t* w0t = (ushort_t*)alloc((size_t)HC0 * NFEAT * 2);    // 128 KB
  ushort_t* w1t = (ushort_t*)alloc((size_t)HC1 * HC0 * 2);      // 80 KB
  int* deg      = (int*)alloc((size_t)N_NODES * 4);
  int* rowstart = (int*)alloc((size_t)(N_NODES + 1) * 4);
  int* fill     = (int*)alloc((size_t)N_NODES * 4);
  int* scol     = (int*)alloc((size_t)N_EDGESN * 4);
  ushort_t* h1b = h0b;   // layer-0 h dead after layer-0 agg; 30000x160 fits
  float* al1 = al0;
  float* ar1 = ar0;

  const int* srcp = ei;
  const int* dstp = ei + N_EDGESN;

  hipMemsetAsync(deg, 0, N_NODES * 4, stream);
  hipMemsetAsync(fill, 0, N_NODES * 4, stream);
  hist_kernel<<<(N_EDGESN + 255) / 256, 256, 0, stream>>>(srcp, deg, N_EDGESN);
  scan_kernel<<<1, 1024, 0, stream>>>(deg, rowstart, N_NODES);
  scatter_kernel<<<(N_EDGESN + 255) / 256, 256, 0, stream>>>(srcp, dstp, rowstart,
                                                             fill, scol, N_EDGESN);
  wtrans<NFEAT, HC0><<<(NFEAT * HC0 + 255) / 256, 256, 0, stream>>>(w0, w0t);
  wtrans<HC0, HC1><<<(HC0 * HC1 + 255) / 256, 256, 0, stream>>>(w1, w1t);

  // layer 0: h0 = bf16(x @ w0), MFMA
  gemm_mfma<HC0 / 16, true><<<(N_NODES + 63) / 64, 256, 0, stream>>>(
      x, w0t, h0b, N_NODES, NFEAT);
  att_dots<C0V><<<N_NODES, 256, 0, stream>>>(h0b, att0, al0, ar0, N_NODES);
  gat_agg2<C0V, true><<<(N_NODES + 3) / 4, 256, 0, stream>>>(h0b, al0, ar0, rowstart,
                                                             scol, b0, o0b, N_NODES);
  // layer 1: h1 = bf16(o0 @ w1), MFMA
  gemm_mfma<HC1 / 16, false><<<(N_NODES + 63) / 64, 256, 0, stream>>>(
      o0b, w1t, h1b, N_NODES, HC0);
  att_dots<C1V><<<N_NODES, 256, 0, stream>>>(h1b, att1, al1, ar1, N_NODES);
  gat_agg2<C1V, false><<<(N_NODES + 3) / 4, 256, 0, stream>>>(h1b, al1, ar1, rowstart,
                                                              scol, b1, out, N_NODES);
}

// Round 5
// 271.315 us; speedup vs baseline: 1.8575x; 1.0907x over previous
//
#include <hip/hip_runtime.h>
#include <math.h>

#define N_NODES 30000
#define N_EDGESN 480000
#define NFEAT 256
#define HEADS 4
#define C0V 64
#define C1V 40
#define HC0 (HEADS*C0V)   // 256
#define HC1 (HEADS*C1V)   // 160
#define NEG_SLOPE 0.2f
#define EPSV 1e-16f

typedef unsigned short ushort_t;
typedef __attribute__((ext_vector_type(8))) short short8v;
typedef __attribute__((ext_vector_type(4))) float f32x4;

__device__ __forceinline__ float lrelu(float x) { return x >= 0.f ? x : x * NEG_SLOPE; }

__device__ __forceinline__ float b2f(unsigned int u16) {
  union { unsigned int u; float f; } v; v.u = u16 << 16; return v.f;
}
__device__ __forceinline__ float b2f_lo(unsigned int u) {
  union { unsigned int u; float f; } v; v.u = u << 16; return v.f;
}
__device__ __forceinline__ float b2f_hi(unsigned int u) {
  union { unsigned int u; float f; } v; v.u = u & 0xffff0000u; return v.f;
}
__device__ __forceinline__ unsigned short f2b(float f) {
  union { float f; unsigned int u; } v; v.f = f;
  unsigned int u = v.u + 0x7FFFu + ((v.u >> 16) & 1u);   // round-nearest-even
  return (unsigned short)(u >> 16);
}

// ---- W[K][N] f32 -> Wt[N][K] bf16 (tiny) --------------------------------------
template <int KK, int NN>
__global__ __launch_bounds__(256) void wtrans(const float* __restrict__ W,
                                              ushort_t* __restrict__ Wt) {
  const int idx = blockIdx.x * 256 + threadIdx.x;
  if (idx >= KK * NN) return;
  const int k = idx / NN, nf = idx - k * NN;
  Wt[(size_t)nf * KK + k] = f2b(W[idx]);
}

// ---- MFMA GEMM: C[M,N]=A[M,K]@W[K,N], A row-major (f32 or bf16), Wt[N][K] bf16
template <int NF, bool A_F32>
__global__ __launch_bounds__(256) void gemm_mfma(const void* __restrict__ Ap,
    const ushort_t* __restrict__ Wt, ushort_t* __restrict__ C, int M, int K) {
  const int lane = threadIdx.x & 63;
  const int wid = threadIdx.x >> 6;
  const int row0 = (blockIdx.x * 4 + wid) * 16;
  if (row0 >= M) return;                 // no __syncthreads below: safe
  const int r_a = lane & 15;
  const int kg = lane >> 4;
  const int N = NF * 16;

  f32x4 acc[NF];
#pragma unroll
  for (int f = 0; f < NF; ++f) acc[f] = (f32x4){0.f, 0.f, 0.f, 0.f};

  for (int k0 = 0; k0 < K; k0 += 32) {
    short8v a;
    if (A_F32) {
      const float* A = (const float*)Ap;
      const float* p = A + (size_t)(row0 + r_a) * K + k0 + kg * 8;
      const float4 lo = *reinterpret_cast<const float4*>(p);
      const float4 hi = *reinterpret_cast<const float4*>(p + 4);
      a[0] = (short)f2b(lo.x); a[1] = (short)f2b(lo.y);
      a[2] = (short)f2b(lo.z); a[3] = (short)f2b(lo.w);
      a[4] = (short)f2b(hi.x); a[5] = (short)f2b(hi.y);
      a[6] = (short)f2b(hi.z); a[7] = (short)f2b(hi.w);
    } else {
      const ushort_t* A = (const ushort_t*)Ap;
      a = *reinterpret_cast<const short8v*>(A + (size_t)(row0 + r_a) * K + k0 + kg * 8);
    }
#pragma unroll
    for (int f = 0; f < NF; ++f) {
      const short8v b = *reinterpret_cast<const short8v*>(
          Wt + (size_t)(f * 16 + r_a) * K + k0 + kg * 8);
      acc[f] = __builtin_amdgcn_mfma_f32_16x16x32_bf16(a, b, acc[f], 0, 0, 0);
    }
  }
#pragma unroll
  for (int f = 0; f < NF; ++f) {
#pragma unroll
    for (int r = 0; r < 4; ++r) {
      C[(size_t)(row0 + kg * 4 + r) * N + f * 16 + r_a] = f2b(acc[f][r]);
    }
  }
}

// ---- per-node attention dot products (bf16 h) ---------------------------------
template <int C>
__global__ __launch_bounds__(256) void att_dots(const ushort_t* __restrict__ h,
    const float* __restrict__ att, float* __restrict__ al, float* __restrict__ ar,
    int n) {
  const int i = blockIdx.x;
  const int hd = threadIdx.x >> 6, lane = threadIdx.x & 63;
  float hv = 0.f, wl = 0.f, wr = 0.f;
  if (lane < C) {
    hv = b2f(h[((size_t)i * HEADS + hd) * C + lane]);
    wl = att[hd * 2 * C + lane];
    wr = att[hd * 2 * C + C + lane];
  }
  float pl = hv * wl, pr = hv * wr;
#pragma unroll
  for (int o = 32; o; o >>= 1) { pl += __shfl_xor(pl, o); pr += __shfl_xor(pr, o); }
  if (lane == 0) { al[(size_t)i * HEADS + hd] = pl; ar[(size_t)i * HEADS + hd] = pr; }
}

// ---- CSR build ----------------------------------------------------------------
__global__ void hist_kernel(const int* __restrict__ src, int* __restrict__ deg, int E) {
  const int e = blockIdx.x * blockDim.x + threadIdx.x;
  if (e < E) atomicAdd(&deg[src[e]], 1);
}

__global__ __launch_bounds__(1024) void scan_kernel(const int* __restrict__ deg,
    int* __restrict__ rowstart, int n) {
  __shared__ int carry;
  __shared__ int wsum[16];
  const int tid = threadIdx.x;
  const int lane = tid & 63, w = tid >> 6;
  if (tid == 0) { carry = 0; rowstart[0] = 0; }
  __syncthreads();
  for (int base = 0; base < n; base += 1024) {
    const int idx = base + tid;
    int x = (idx < n) ? deg[idx] : 0;
#pragma unroll
    for (int o = 1; o < 64; o <<= 1) { int y = __shfl_up(x, o); if (lane >= o) x += y; }
    if (lane == 63) wsum[w] = x;
    __syncthreads();
    if (w == 0) {
      int s = (lane < 16) ? wsum[lane] : 0;
#pragma unroll
      for (int o = 1; o < 16; o <<= 1) { int y = __shfl_up(s, o); if (lane >= o) s += y; }
      if (lane < 16) wsum[lane] = s;
    }
    __syncthreads();
    const int add = (w > 0 ? wsum[w - 1] : 0) + carry;
    if (idx < n) rowstart[idx + 1] = x + add;
    __syncthreads();
    if (tid == 0) carry += wsum[15];
    __syncthreads();
  }
}

__global__ void scatter_kernel(const int* __restrict__ src, const int* __restrict__ dst,
    const int* __restrict__ rowstart, int* __restrict__ fill, int* __restrict__ scol,
    int E) {
  const int e = blockIdx.x * blockDim.x + threadIdx.x;
  if (e < E) {
    const int r = src[e];
    const int pos = rowstart[r] + atomicAdd(&fill[r], 1);
    scol[pos] = dst[e];
  }
}

// ---- fused softmax + aggregation v3: one wave per node ------------------------
// Single sweep computes exp(alpha) per edge (no max-sub: |alpha| << 88),
// stores ew[edge][4] f32, accumulates denom. Gather pass: lane holds 8 bf16
// chans (uint4); NG groups process NG edges per iteration; weights come from
// ew (no exp/lrelu in the inner loop).
template <int C, bool CONCAT_RELU>
__global__ __launch_bounds__(256) void gat_agg3(const ushort_t* __restrict__ h,
    const float* __restrict__ al, const float* __restrict__ ar,
    const int* __restrict__ rowstart, const int* __restrict__ scol,
    float* __restrict__ ew, const float* __restrict__ bias,
    void* __restrict__ outv, int n) {
  constexpr int ROW = HEADS * C;     // 256 / 160
  constexpr int LPG = ROW / 8;       // lanes per group: 32 / 20
  constexpr int NG  = 64 / LPG;      // groups (edges per iteration): 2 / 3
  __shared__ float sm[4][CONCAT_RELU ? 1 : NG][CONCAT_RELU ? 1 : ROW];
  const int wid = threadIdx.x >> 6, lane = threadIdx.x & 63;
  const int i = blockIdx.x * 4 + wid;
  if (i >= n) return;                // never taken (30000 % 4 == 0)
  const int s0 = rowstart[i], s1 = rowstart[i + 1];

  const float4 al4 = *reinterpret_cast<const float4*>(al + (size_t)i * 4);
  const float4 ari = *reinterpret_cast<const float4*>(ar + (size_t)i * 4);
  const float es0 = __expf(lrelu(al4.x + ari.x));
  const float es1 = __expf(lrelu(al4.y + ari.y));
  const float es2 = __expf(lrelu(al4.z + ari.z));
  const float es3 = __expf(lrelu(al4.w + ari.w));

  // ---- single sweep: exp + denom-sum + store ew ----
  float t0 = 0.f, t1 = 0.f, t2 = 0.f, t3 = 0.f;
  for (int e = s0 + lane; e < s1; e += 64) {
    const int j = scol[e];
    const float4 a = *reinterpret_cast<const float4*>(ar + (size_t)j * 4);
    const float w0 = __expf(lrelu(al4.x + a.x));
    const float w1 = __expf(lrelu(al4.y + a.y));
    const float w2 = __expf(lrelu(al4.z + a.z));
    const float w3 = __expf(lrelu(al4.w + a.w));
    t0 += w0; t1 += w1; t2 += w2; t3 += w3;
    *reinterpret_cast<float4*>(ew + (size_t)e * 4) = make_float4(w0, w1, w2, w3);
  }
#pragma unroll
  for (int o = 32; o; o >>= 1) {
    t0 += __shfl_xor(t0, o); t1 += __shfl_xor(t1, o);
    t2 += __shfl_xor(t2, o); t3 += __shfl_xor(t3, o);
  }
  const float i0 = 1.f / (t0 + es0 + EPSV), i1 = 1.f / (t1 + es1 + EPSV);
  const float i2 = 1.f / (t2 + es2 + EPSV), i3 = 1.f / (t3 + es3 + EPSV);

  // ---- group geometry ----
  const int g  = lane / LPG;               // constexpr divisor
  const int cl = lane - g * LPG;           // channel-block in group
  const bool act = g < NG;
  const int hd = (cl * 8) / C;             // head of this lane's 8 channels
  const float inv_h = hd < 2 ? (hd == 0 ? i0 : i1) : (hd == 2 ? i2 : i3);
  const float es_h  = hd < 2 ? (hd == 0 ? es0 : es1) : (hd == 2 ? es2 : es3);

  float acc[8];
#pragma unroll
  for (int k = 0; k < 8; ++k) acc[k] = 0.f;

  // self-loop (group 0 only)
  if (g == 0) {
    const float w = es_h * inv_h;
    const uint4 hv = *reinterpret_cast<const uint4*>(h + (size_t)i * ROW + cl * 8);
    acc[0] = w * b2f_lo(hv.x); acc[1] = w * b2f_hi(hv.x);
    acc[2] = w * b2f_lo(hv.y); acc[3] = w * b2f_hi(hv.y);
    acc[4] = w * b2f_lo(hv.z); acc[5] = w * b2f_hi(hv.z);
    acc[6] = w * b2f_lo(hv.w); acc[7] = w * b2f_hi(hv.w);
  }

  // ---- gather pass: NG edges per iteration ----
  for (int e0 = s0; e0 < s1; e0 += 64) {
    const int cnt = min(64, s1 - e0);
    int jl = 0;
    if (lane < cnt) jl = scol[e0 + lane];
    const int niter = (cnt + NG - 1) / NG;
    for (int t = 0; t < niter; ++t) {
      const int eidx = t * NG + g;
      const bool ev = act && (eidx < cnt);
      const int j = __shfl(jl, eidx & 63);
      if (ev) {
        const float w = ew[(size_t)(e0 + eidx) * 4 + hd] * inv_h;
        const uint4 hv = *reinterpret_cast<const uint4*>(h + (size_t)j * ROW + cl * 8);
        acc[0] = fmaf(w, b2f_lo(hv.x), acc[0]); acc[1] = fmaf(w, b2f_hi(hv.x), acc[1]);
        acc[2] = fmaf(w, b2f_lo(hv.y), acc[2]); acc[3] = fmaf(w, b2f_hi(hv.y), acc[3]);
        acc[4] = fmaf(w, b2f_lo(hv.z), acc[4]); acc[5] = fmaf(w, b2f_hi(hv.z), acc[5]);
        acc[6] = fmaf(w, b2f_lo(hv.w), acc[6]); acc[7] = fmaf(w, b2f_hi(hv.w), acc[7]);
      }
    }
  }

  if (CONCAT_RELU) {
    // NG==2: fold group 1 into group 0 via xor-32, then lanes 0..31 store bf16
#pragma unroll
    for (int k = 0; k < 8; ++k) acc[k] += __shfl_xor(acc[k], 32);
    if (g == 0) {
      ushort_t* out = (ushort_t*)outv;
      const float4 blo = *reinterpret_cast<const float4*>(bias + cl * 8);
      const float4 bhi = *reinterpret_cast<const float4*>(bias + cl * 8 + 4);
      uint4 st;
      st.x = (unsigned)f2b(fmaxf(acc[0] + blo.x, 0.f)) |
             ((unsigned)f2b(fmaxf(acc[1] + blo.y, 0.f)) << 16);
      st.y = (unsigned)f2b(fmaxf(acc[2] + blo.z, 0.f)) |
             ((unsigned)f2b(fmaxf(acc[3] + blo.w, 0.f)) << 16);
      st.z = (unsigned)f2b(fmaxf(acc[4] + bhi.x, 0.f)) |
             ((unsigned)f2b(fmaxf(acc[5] + bhi.y, 0.f)) << 16);
      st.w = (unsigned)f2b(fmaxf(acc[6] + bhi.z, 0.f)) |
             ((unsigned)f2b(fmaxf(acc[7] + bhi.w, 0.f)) << 16);
      *reinterpret_cast<uint4*>((ushort_t*)outv + (size_t)i * ROW + cl * 8) = st;
      (void)out;
    }
    __syncthreads();   // uniform: keep block convergent (cheap)
  } else {
    // NG==3: partials -> LDS, then 40 lanes do group-sum + head-mean
    if (act) {
#pragma unroll
      for (int k = 0; k < 8; ++k) sm[wid][g][cl * 8 + k] = acc[k];
    }
    __syncthreads();
    if (lane < C) {
      float s = 0.f;
#pragma unroll
      for (int gg = 0; gg < NG; ++gg) {
#pragma unroll
        for (int hh = 0; hh < HEADS; ++hh) s += sm[wid][gg][hh * C + lane];
      }
      ((float*)outv)[(size_t)i * C + lane] = s * 0.25f + bias[lane];
    }
  }
}

// ---- launch -------------------------------------------------------------------
extern "C" void kernel_launch(void* const* d_in, const int* in_sizes, int n_in,
                              void* d_out, int out_size, void* d_ws, size_t ws_size,
                              hipStream_t stream) {
  const float* x    = (const float*)d_in[0];
  const int*   ei   = (const int*)d_in[1];
  const float* w0   = (const float*)d_in[2];
  const float* att0 = (const float*)d_in[3];
  const float* b0   = (const float*)d_in[4];
  const float* w1   = (const float*)d_in[5];
  const float* att1 = (const float*)d_in[6];
  const float* b1   = (const float*)d_in[7];
  float* out = (float*)d_out;

  char* ws = (char*)d_ws;
  size_t off = 0;
  auto alloc = [&](size_t bytes) -> void* {
    void* p = ws + off;
    off += (bytes + 255) & ~(size_t)255;
    return p;
  };
  ushort_t* h0b = (ushort_t*)alloc((size_t)N_NODES * HC0 * 2);  // 15.4 MB
  ushort_t* o0b = (ushort_t*)alloc((size_t)N_NODES * HC0 * 2);  // 15.4 MB
  float* al0 = (float*)alloc((size_t)N_NODES * HEADS * 4);
  float* ar0 = (float*)alloc((size_t)N_NODES * HEADS * 4);
  float* ew  = (float*)alloc((size_t)N_EDGESN * 4 * 4);         // 7.7 MB
  ushort_t* w0t = (ushort_t*)alloc((size_t)HC0 * NFEAT * 2);    // 128 KB
  ushort_t* w1t = (ushort_t*)alloc((size_t)HC1 * HC0 * 2);      // 80 KB
  int* deg      = (int*)alloc((size_t)N_NODES * 4);
  int* rowstart = (int*)alloc((size_t)(N_NODES + 1) * 4);
  int* fill     = (int*)alloc((size_t)N_NODES * 4);
  int* scol     = (int*)alloc((size_t)N_EDGESN * 4);
  ushort_t* h1b = h0b;   // layer-0 h dead after layer-0 agg
  float* al1 = al0;
  float* ar1 = ar0;

  const int* srcp = ei;
  const int* dstp = ei + N_EDGESN;

  hipMemsetAsync(deg, 0, N_NODES * 4, stream);
  hipMemsetAsync(fill, 0, N_NODES * 4, stream);
  hist_kernel<<<(N_EDGESN + 255) / 256, 256, 0, stream>>>(srcp, deg, N_EDGESN);
  scan_kernel<<<1, 1024, 0, stream>>>(deg, rowstart, N_NODES);
  scatter_kernel<<<(N_EDGESN + 255) / 256, 256, 0, stream>>>(srcp, dstp, rowstart,
                                                             fill, scol, N_EDGESN);
  wtrans<NFEAT, HC0><<<(NFEAT * HC0 + 255) / 256, 256, 0, stream>>>(w0, w0t);
  wtrans<HC0, HC1><<<(HC0 * HC1 + 255) / 256, 256, 0, stream>>>(w1, w1t);

  // layer 0
  gemm_mfma<HC0 / 16, true><<<(N_NODES + 63) / 64, 256, 0, stream>>>(
      x, w0t, h0b, N_NODES, NFEAT);
  att_dots<C0V><<<N_NODES, 256, 0, stream>>>(h0b, att0, al0, ar0, N_NODES);
  gat_agg3<C0V, true><<<(N_NODES + 3) / 4, 256, 0, stream>>>(
      h0b, al0, ar0, rowstart, scol, ew, b0, o0b, N_NODES);
  // layer 1
  gemm_mfma<HC1 / 16, false><<<(N_NODES + 63) / 64, 256, 0, stream>>>(
      o0b, w1t, h1b, N_NODES, HC0);
  att_dots<C1V><<<N_NODES, 256, 0, stream>>>(h1b, att1, al1, ar1, N_NODES);
  gat_agg3<C1V, false><<<(N_NODES + 3) / 4, 256, 0, stream>>>(
      h1b, al1, ar1, rowstart, scol, ew, b1, out, N_NODES);
}

// Round 6
// 247.802 us; speedup vs baseline: 2.0338x; 1.0949x over previous
//
#include <hip/hip_runtime.h>
#include <math.h>

#define N_NODES 30000
#define N_EDGESN 480000
#define NFEAT 256
#define HEADS 4
#define C0V 64
#define C1V 40
#define HC0 (HEADS*C0V)   // 256
#define HC1 (HEADS*C1V)   // 160
#define NEG_SLOPE 0.2f
#define EPSV 1e-16f

typedef unsigned short ushort_t;
typedef __attribute__((ext_vector_type(8))) short short8v;
typedef __attribute__((ext_vector_type(4))) float f32x4;

__device__ __forceinline__ float lrelu(float x) { return x >= 0.f ? x : x * NEG_SLOPE; }

__device__ __forceinline__ float b2f(unsigned int u16) {
  union { unsigned int u; float f; } v; v.u = u16 << 16; return v.f;
}
__device__ __forceinline__ float b2f_lo(unsigned int u) {
  union { unsigned int u; float f; } v; v.u = u << 16; return v.f;
}
__device__ __forceinline__ float b2f_hi(unsigned int u) {
  union { unsigned int u; float f; } v; v.u = u & 0xffff0000u; return v.f;
}
__device__ __forceinline__ unsigned short f2b(float f) {
  union { float f; unsigned int u; } v; v.f = f;
  unsigned int u = v.u + 0x7FFFu + ((v.u >> 16) & 1u);   // round-nearest-even
  return (unsigned short)(u >> 16);
}

// ---- W[K][N] f32 -> Wt[N][K] bf16 (tiny) --------------------------------------
template <int KK, int NN>
__global__ __launch_bounds__(256) void wtrans(const float* __restrict__ W,
                                              ushort_t* __restrict__ Wt) {
  const int idx = blockIdx.x * 256 + threadIdx.x;
  if (idx >= KK * NN) return;
  const int k = idx / NN, nf = idx - k * NN;
  Wt[(size_t)nf * KK + k] = f2b(W[idx]);
}

// ---- MFMA GEMM: C[M,N]=A[M,K]@W[K,N]; optional fused att-dots (C_head=64) -----
// FUSE_ATT: per-lane dot of live accumulator with attL/attR, 16-lane reduce,
// writes al/ar[row][4] as float4. head = f>>2 is compile-time (C0V==64 only).
template <int NF, bool A_F32, bool FUSE_ATT>
__global__ __launch_bounds__(256) void gemm_mfma(const void* __restrict__ Ap,
    const ushort_t* __restrict__ Wt, ushort_t* __restrict__ C, int M, int K,
    const float* __restrict__ att, float* __restrict__ al, float* __restrict__ ar) {
  const int lane = threadIdx.x & 63;
  const int wid = threadIdx.x >> 6;
  const int row0 = (blockIdx.x * 4 + wid) * 16;
  if (row0 >= M) return;                 // no __syncthreads below: safe
  const int r_a = lane & 15;
  const int kg = lane >> 4;
  const int N = NF * 16;

  f32x4 acc[NF];
#pragma unroll
  for (int f = 0; f < NF; ++f) acc[f] = (f32x4){0.f, 0.f, 0.f, 0.f};

  for (int k0 = 0; k0 < K; k0 += 32) {
    short8v a;
    if (A_F32) {
      const float* A = (const float*)Ap;
      const float* p = A + (size_t)(row0 + r_a) * K + k0 + kg * 8;
      const float4 lo = *reinterpret_cast<const float4*>(p);
      const float4 hi = *reinterpret_cast<const float4*>(p + 4);
      a[0] = (short)f2b(lo.x); a[1] = (short)f2b(lo.y);
      a[2] = (short)f2b(lo.z); a[3] = (short)f2b(lo.w);
      a[4] = (short)f2b(hi.x); a[5] = (short)f2b(hi.y);
      a[6] = (short)f2b(hi.z); a[7] = (short)f2b(hi.w);
    } else {
      const ushort_t* A = (const ushort_t*)Ap;
      a = *reinterpret_cast<const short8v*>(A + (size_t)(row0 + r_a) * K + k0 + kg * 8);
    }
#pragma unroll
    for (int f = 0; f < NF; ++f) {
      const short8v b = *reinterpret_cast<const short8v*>(
          Wt + (size_t)(f * 16 + r_a) * K + k0 + kg * 8);
      acc[f] = __builtin_amdgcn_mfma_f32_16x16x32_bf16(a, b, acc[f], 0, 0, 0);
    }
  }
  // C store: D layout col = lane&15, row = (lane>>4)*4 + reg
#pragma unroll
  for (int f = 0; f < NF; ++f) {
#pragma unroll
    for (int r = 0; r < 4; ++r) {
      C[(size_t)(row0 + kg * 4 + r) * N + f * 16 + r_a] = f2b(acc[f][r]);
    }
  }
  if (FUSE_ATT) {
    // al[row][hh] = sum_c h[row][hh*64+c]*attL[hh][c]; lane covers cols f*16+r_a
    float hpl[4][4], hpr[4][4];
#pragma unroll
    for (int hh = 0; hh < 4; ++hh)
#pragma unroll
      for (int r = 0; r < 4; ++r) { hpl[hh][r] = 0.f; hpr[hh][r] = 0.f; }
#pragma unroll
    for (int f = 0; f < NF; ++f) {
      const int hh = f >> 2;                    // valid for C_head = 64
      const int cc = (f & 3) * 16 + r_a;
      const float wlv = att[hh * 128 + cc];
      const float wrv = att[hh * 128 + 64 + cc];
#pragma unroll
      for (int r = 0; r < 4; ++r) {
        hpl[hh][r] = fmaf(acc[f][r], wlv, hpl[hh][r]);
        hpr[hh][r] = fmaf(acc[f][r], wrv, hpr[hh][r]);
      }
    }
#pragma unroll
    for (int o = 1; o < 16; o <<= 1) {
#pragma unroll
      for (int hh = 0; hh < 4; ++hh)
#pragma unroll
        for (int r = 0; r < 4; ++r) {
          hpl[hh][r] += __shfl_xor(hpl[hh][r], o);
          hpr[hh][r] += __shfl_xor(hpr[hh][r], o);
        }
    }
    if (r_a == 0) {
#pragma unroll
      for (int r = 0; r < 4; ++r) {
        const int row = row0 + kg * 4 + r;
        *reinterpret_cast<float4*>(al + (size_t)row * 4) =
            make_float4(hpl[0][r], hpl[1][r], hpl[2][r], hpl[3][r]);
        *reinterpret_cast<float4*>(ar + (size_t)row * 4) =
            make_float4(hpr[0][r], hpr[1][r], hpr[2][r], hpr[3][r]);
      }
    }
  }
}

// ---- per-node attention dot products (bf16 h) — layer 1 only ------------------
template <int C>
__global__ __launch_bounds__(256) void att_dots(const ushort_t* __restrict__ h,
    const float* __restrict__ att, float* __restrict__ al, float* __restrict__ ar,
    int n) {
  const int i = blockIdx.x;
  const int hd = threadIdx.x >> 6, lane = threadIdx.x & 63;
  float hv = 0.f, wl = 0.f, wr = 0.f;
  if (lane < C) {
    hv = b2f(h[((size_t)i * HEADS + hd) * C + lane]);
    wl = att[hd * 2 * C + lane];
    wr = att[hd * 2 * C + C + lane];
  }
  float pl = hv * wl, pr = hv * wr;
#pragma unroll
  for (int o = 32; o; o >>= 1) { pl += __shfl_xor(pl, o); pr += __shfl_xor(pr, o); }
  if (lane == 0) { al[(size_t)i * HEADS + hd] = pl; ar[(size_t)i * HEADS + hd] = pr; }
}

// ---- CSR build ----------------------------------------------------------------
__global__ void hist_kernel(const int* __restrict__ src, int* __restrict__ deg, int E) {
  const int e = blockIdx.x * blockDim.x + threadIdx.x;
  if (e < E) atomicAdd(&deg[src[e]], 1);
}

__global__ __launch_bounds__(1024) void scan_kernel(const int* __restrict__ deg,
    int* __restrict__ rowstart, int n) {
  __shared__ int carry;
  __shared__ int wsum[16];
  const int tid = threadIdx.x;
  const int lane = tid & 63, w = tid >> 6;
  if (tid == 0) { carry = 0; rowstart[0] = 0; }
  __syncthreads();
  for (int base = 0; base < n; base += 1024) {
    const int idx = base + tid;
    int x = (idx < n) ? deg[idx] : 0;
#pragma unroll
    for (int o = 1; o < 64; o <<= 1) { int y = __shfl_up(x, o); if (lane >= o) x += y; }
    if (lane == 63) wsum[w] = x;
    __syncthreads();
    if (w == 0) {
      int s = (lane < 16) ? wsum[lane] : 0;
#pragma unroll
      for (int o = 1; o < 16; o <<= 1) { int y = __shfl_up(s, o); if (lane >= o) s += y; }
      if (lane < 16) wsum[lane] = s;
    }
    __syncthreads();
    const int add = (w > 0 ? wsum[w - 1] : 0) + carry;
    if (idx < n) rowstart[idx + 1] = x + add;
    __syncthreads();
    if (tid == 0) carry += wsum[15];
    __syncthreads();
  }
}

__global__ void scatter_kernel(const int* __restrict__ src, const int* __restrict__ dst,
    const int* __restrict__ rowstart, int* __restrict__ fill, int* __restrict__ scol,
    int E) {
  const int e = blockIdx.x * blockDim.x + threadIdx.x;
  if (e < E) {
    const int r = src[e];
    const int pos = rowstart[r] + atomicAdd(&fill[r], 1);
    scol[pos] = dst[e];
  }
}

// ---- fused softmax + aggregation v4: one wave per node ------------------------
// Sweep 1: lane-parallel exp(alpha) per edge -> ew[e][4] + denom sum (no max-sub:
// |alpha| << 88). Gather: NG groups, uniform scol loads (no shfl), unroll-2 with
// next-iteration index prefetch -> 2 row loads + 2 index loads in flight/wave.
template <int C, bool CONCAT_RELU>
__global__ __launch_bounds__(256) void gat_agg4(const ushort_t* __restrict__ h,
    const float* __restrict__ al, const float* __restrict__ ar,
    const int* __restrict__ rowstart, const int* __restrict__ scol,
    float* __restrict__ ew, const float* __restrict__ bias,
    void* __restrict__ outv, int n) {
  constexpr int ROW = HEADS * C;     // 256 / 160
  constexpr int LPG = ROW / 8;       // lanes per group: 32 / 20
  constexpr int NG  = 64 / LPG;      // groups: 2 / 3
  __shared__ float sm[4][CONCAT_RELU ? 1 : NG][CONCAT_RELU ? 1 : ROW];
  const int wid = threadIdx.x >> 6, lane = threadIdx.x & 63;
  const int i = blockIdx.x * 4 + wid;
  if (i >= n) return;                // never taken (30000 % 4 == 0)
  const int s0 = rowstart[i], s1 = rowstart[i + 1];

  const float4 al4 = *reinterpret_cast<const float4*>(al + (size_t)i * 4);
  const float4 ari = *reinterpret_cast<const float4*>(ar + (size_t)i * 4);
  const float es0 = __expf(lrelu(al4.x + ari.x));
  const float es1 = __expf(lrelu(al4.y + ari.y));
  const float es2 = __expf(lrelu(al4.z + ari.z));
  const float es3 = __expf(lrelu(al4.w + ari.w));

  // ---- sweep 1: exp + denom-sum + store ew ----
  float t0 = 0.f, t1 = 0.f, t2 = 0.f, t3 = 0.f;
  for (int e = s0 + lane; e < s1; e += 64) {
    const int j = scol[e];
    const float4 a = *reinterpret_cast<const float4*>(ar + (size_t)j * 4);
    const float w0 = __expf(lrelu(al4.x + a.x));
    const float w1 = __expf(lrelu(al4.y + a.y));
    const float w2 = __expf(lrelu(al4.z + a.z));
    const float w3 = __expf(lrelu(al4.w + a.w));
    t0 += w0; t1 += w1; t2 += w2; t3 += w3;
    *reinterpret_cast<float4*>(ew + (size_t)e * 4) = make_float4(w0, w1, w2, w3);
  }
#pragma unroll
  for (int o = 32; o; o >>= 1) {
    t0 += __shfl_xor(t0, o); t1 += __shfl_xor(t1, o);
    t2 += __shfl_xor(t2, o); t3 += __shfl_xor(t3, o);
  }
  const float i0 = 1.f / (t0 + es0 + EPSV), i1 = 1.f / (t1 + es1 + EPSV);
  const float i2 = 1.f / (t2 + es2 + EPSV), i3 = 1.f / (t3 + es3 + EPSV);

  // ---- group geometry ----
  const int g  = lane / LPG;
  const int cl = lane - g * LPG;
  const bool act = g < NG;
  const int hd = (cl * 8) / C;
  const float inv_h = hd < 2 ? (hd == 0 ? i0 : i1) : (hd == 2 ? i2 : i3);
  const float es_h  = hd < 2 ? (hd == 0 ? es0 : es1) : (hd == 2 ? es2 : es3);

  float acc[8];
#pragma unroll
  for (int k = 0; k < 8; ++k) acc[k] = 0.f;

  // self-loop (group 0 only)
  if (g == 0) {
    const float w = es_h * inv_h;
    const uint4 hv = *reinterpret_cast<const uint4*>(h + (size_t)i * ROW + cl * 8);
    acc[0] = w * b2f_lo(hv.x); acc[1] = w * b2f_hi(hv.x);
    acc[2] = w * b2f_lo(hv.y); acc[3] = w * b2f_hi(hv.y);
    acc[4] = w * b2f_lo(hv.z); acc[5] = w * b2f_hi(hv.z);
    acc[6] = w * b2f_lo(hv.w); acc[7] = w * b2f_hi(hv.w);
  }

  // ---- gather: uniform scol loads, unroll-2, index prefetch ----
  if (act) {
    int e = s0 + g;
    int ja = scol[min(e, N_EDGESN - 1)];
    int jb = scol[min(e + NG, N_EDGESN - 1)];
    for (; e + NG < s1; e += 2 * NG) {
      const int jc = scol[min(e + 2 * NG, N_EDGESN - 1)];
      const int jd = scol[min(e + 3 * NG, N_EDGESN - 1)];
      const uint4 ha = *reinterpret_cast<const uint4*>(h + (size_t)ja * ROW + cl * 8);
      const uint4 hb = *reinterpret_cast<const uint4*>(h + (size_t)jb * ROW + cl * 8);
      const float wa = ew[(size_t)e * 4 + hd] * inv_h;
      const float wb = ew[(size_t)(e + NG) * 4 + hd] * inv_h;
      acc[0] = fmaf(wa, b2f_lo(ha.x), acc[0]); acc[1] = fmaf(wa, b2f_hi(ha.x), acc[1]);
      acc[2] = fmaf(wa, b2f_lo(ha.y), acc[2]); acc[3] = fmaf(wa, b2f_hi(ha.y), acc[3]);
      acc[4] = fmaf(wa, b2f_lo(ha.z), acc[4]); acc[5] = fmaf(wa, b2f_hi(ha.z), acc[5]);
      acc[6] = fmaf(wa, b2f_lo(ha.w), acc[6]); acc[7] = fmaf(wa, b2f_hi(ha.w), acc[7]);
      acc[0] = fmaf(wb, b2f_lo(hb.x), acc[0]); acc[1] = fmaf(wb, b2f_hi(hb.x), acc[1]);
      acc[2] = fmaf(wb, b2f_lo(hb.y), acc[2]); acc[3] = fmaf(wb, b2f_hi(hb.y), acc[3]);
      acc[4] = fmaf(wb, b2f_lo(hb.z), acc[4]); acc[5] = fmaf(wb, b2f_hi(hb.z), acc[5]);
      acc[6] = fmaf(wb, b2f_lo(hb.w), acc[6]); acc[7] = fmaf(wb, b2f_hi(hb.w), acc[7]);
      ja = jc; jb = jd;
    }
    if (e < s1) {
      const uint4 ha = *reinterpret_cast<const uint4*>(h + (size_t)ja * ROW + cl * 8);
      const float wa = ew[(size_t)e * 4 + hd] * inv_h;
      acc[0] = fmaf(wa, b2f_lo(ha.x), acc[0]); acc[1] = fmaf(wa, b2f_hi(ha.x), acc[1]);
      acc[2] = fmaf(wa, b2f_lo(ha.y), acc[2]); acc[3] = fmaf(wa, b2f_hi(ha.y), acc[3]);
      acc[4] = fmaf(wa, b2f_lo(ha.z), acc[4]); acc[5] = fmaf(wa, b2f_hi(ha.z), acc[5]);
      acc[6] = fmaf(wa, b2f_lo(ha.w), acc[6]); acc[7] = fmaf(wa, b2f_hi(ha.w), acc[7]);
    }
  }

  if (CONCAT_RELU) {
    // NG==2: fold group 1 into group 0 via xor-32, lanes 0..31 store bf16
#pragma unroll
    for (int k = 0; k < 8; ++k) acc[k] += __shfl_xor(acc[k], 32);
    if (g == 0) {
      const float4 blo = *reinterpret_cast<const float4*>(bias + cl * 8);
      const float4 bhi = *reinterpret_cast<const float4*>(bias + cl * 8 + 4);
      uint4 st;
      st.x = (unsigned)f2b(fmaxf(acc[0] + blo.x, 0.f)) |
             ((unsigned)f2b(fmaxf(acc[1] + blo.y, 0.f)) << 16);
      st.y = (unsigned)f2b(fmaxf(acc[2] + blo.z, 0.f)) |
             ((unsigned)f2b(fmaxf(acc[3] + blo.w, 0.f)) << 16);
      st.z = (unsigned)f2b(fmaxf(acc[4] + bhi.x, 0.f)) |
             ((unsigned)f2b(fmaxf(acc[5] + bhi.y, 0.f)) << 16);
      st.w = (unsigned)f2b(fmaxf(acc[6] + bhi.z, 0.f)) |
             ((unsigned)f2b(fmaxf(acc[7] + bhi.w, 0.f)) << 16);
      *reinterpret_cast<uint4*>((ushort_t*)outv + (size_t)i * ROW + cl * 8) = st;
    }
  } else {
    // NG==3: partials -> LDS, 40 lanes do group-sum + head-mean
    if (act) {
#pragma unroll
      for (int k = 0; k < 8; ++k) sm[wid][g][cl * 8 + k] = acc[k];
    }
    __syncthreads();
    if (lane < C) {
      float s = 0.f;
#pragma unroll
      for (int gg = 0; gg < NG; ++gg) {
#pragma unroll
        for (int hh = 0; hh < HEADS; ++hh) s += sm[wid][gg][hh * C + lane];
      }
      ((float*)outv)[(size_t)i * C + lane] = s * 0.25f + bias[lane];
    }
  }
}

// ---- launch -------------------------------------------------------------------
extern "C" void kernel_launch(void* const* d_in, const int* in_sizes, int n_in,
                              void* d_out, int out_size, void* d_ws, size_t ws_size,
                              hipStream_t stream) {
  const float* x    = (const float*)d_in[0];
  const int*   ei   = (const int*)d_in[1];
  const float* w0   = (const float*)d_in[2];
  const float* att0 = (const float*)d_in[3];
  const float* b0   = (const float*)d_in[4];
  const float* w1   = (const float*)d_in[5];
  const float* att1 = (const float*)d_in[6];
  const float* b1   = (const float*)d_in[7];
  float* out = (float*)d_out;

  char* ws = (char*)d_ws;
  size_t off = 0;
  auto alloc = [&](size_t bytes) -> void* {
    void* p = ws + off;
    off += (bytes + 255) & ~(size_t)255;
    return p;
  };
  ushort_t* h0b = (ushort_t*)alloc((size_t)N_NODES * HC0 * 2);  // 15.4 MB
  ushort_t* o0b = (ushort_t*)alloc((size_t)N_NODES * HC0 * 2);  // 15.4 MB
  float* al0 = (float*)alloc((size_t)N_NODES * HEADS * 4);
  float* ar0 = (float*)alloc((size_t)N_NODES * HEADS * 4);
  float* ew  = (float*)alloc((size_t)N_EDGESN * 4 * 4);         // 7.7 MB
  ushort_t* w0t = (ushort_t*)alloc((size_t)HC0 * NFEAT * 2);    // 128 KB
  ushort_t* w1t = (ushort_t*)alloc((size_t)HC1 * HC0 * 2);      // 80 KB
  int* deg      = (int*)alloc((size_t)N_NODES * 4);
  int* rowstart = (int*)alloc((size_t)(N_NODES + 1) * 4);
  int* fill     = (int*)alloc((size_t)N_NODES * 4);
  int* scol     = (int*)alloc((size_t)N_EDGESN * 4);
  ushort_t* h1b = h0b;   // layer-0 h dead after layer-0 agg
  float* al1 = al0;
  float* ar1 = ar0;

  const int* srcp = ei;
  const int* dstp = ei + N_EDGESN;

  hipMemsetAsync(deg, 0, N_NODES * 4, stream);
  hipMemsetAsync(fill, 0, N_NODES * 4, stream);
  hist_kernel<<<(N_EDGESN + 255) / 256, 256, 0, stream>>>(srcp, deg, N_EDGESN);
  scan_kernel<<<1, 1024, 0, stream>>>(deg, rowstart, N_NODES);
  scatter_kernel<<<(N_EDGESN + 255) / 256, 256, 0, stream>>>(srcp, dstp, rowstart,
                                                             fill, scol, N_EDGESN);
  wtrans<NFEAT, HC0><<<(NFEAT * HC0 + 255) / 256, 256, 0, stream>>>(w0, w0t);
  wtrans<HC0, HC1><<<(HC0 * HC1 + 255) / 256, 256, 0, stream>>>(w1, w1t);

  // layer 0 (att-dots fused into GEMM epilogue)
  gemm_mfma<HC0 / 16, true, true><<<(N_NODES + 63) / 64, 256, 0, stream>>>(
      x, w0t, h0b, N_NODES, NFEAT, att0, al0, ar0);
  gat_agg4<C0V, true><<<(N_NODES + 3) / 4, 256, 0, stream>>>(
      h0b, al0, ar0, rowstart, scol, ew, b0, o0b, N_NODES);
  // layer 1
  gemm_mfma<HC1 / 16, false, false><<<(N_NODES + 63) / 64, 256, 0, stream>>>(
      o0b, w1t, h1b, N_NODES, HC0, nullptr, nullptr, nullptr);
  att_dots<C1V><<<N_NODES, 256, 0, stream>>>(h1b, att1, al1, ar1, N_NODES);
  gat_agg4<C1V, false><<<(N_NODES + 3) / 4, 256, 0, stream>>>(
      h1b, al1, ar1, rowstart, scol, ew, b1, out, N_NODES);
}

// Round 7
// 228.781 us; speedup vs baseline: 2.2029x; 1.0831x over previous
//
#include <hip/hip_runtime.h>
#include <math.h>

#define N_NODES 30000
#define N_EDGESN 480000
#define NFEAT 256
#define HEADS 4
#define C0V 64
#define C1V 40
#define HC0 (HEADS*C0V)   // 256
#define HC1 (HEADS*C1V)   // 160
#define NEG_SLOPE 0.2f
#define EPSV 1e-16f

typedef unsigned short ushort_t;
typedef __attribute__((ext_vector_type(8))) short short8v;
typedef __attribute__((ext_vector_type(4))) float f32x4;

__device__ __forceinline__ float lrelu(float x) { return x >= 0.f ? x : x * NEG_SLOPE; }

__device__ __forceinline__ float b2f(unsigned int u16) {
  union { unsigned int u; float f; } v; v.u = u16 << 16; return v.f;
}
__device__ __forceinline__ float b2f_lo(unsigned int u) {
  union { unsigned int u; float f; } v; v.u = u << 16; return v.f;
}
__device__ __forceinline__ float b2f_hi(unsigned int u) {
  union { unsigned int u; float f; } v; v.u = u & 0xffff0000u; return v.f;
}
__device__ __forceinline__ unsigned short f2b(float f) {
  union { float f; unsigned int u; } v; v.f = f;
  unsigned int u = v.u + 0x7FFFu + ((v.u >> 16) & 1u);   // round-nearest-even
  return (unsigned short)(u >> 16);
}

// ---- W[K][N] f32 -> Wt[N][K] bf16 (tiny) --------------------------------------
template <int KK, int NN>
__global__ __launch_bounds__(256) void wtrans(const float* __restrict__ W,
                                              ushort_t* __restrict__ Wt) {
  const int idx = blockIdx.x * 256 + threadIdx.x;
  if (idx >= KK * NN) return;
  const int k = idx / NN, nf = idx - k * NN;
  Wt[(size_t)nf * KK + k] = f2b(W[idx]);
}

// ---- MFMA GEMM v2: C[M,N]=A[M,K]@W[K,N], K=256 fixed --------------------------
// Block: NSTRIP 16-row strips x CG col-groups (NSTRIP*CG waves of 64).
// A strip staged in LDS once (f32->bf16 at staging if A_F32); each wave does
// NFW 16-col fragments. FUSE: 0=none, 1=layer0 att (head==cg), 2=layer1 att
// (two heads per cg, C_head=40).
#define KDIM 256
#define KPAD 264
template <int NFW, int CG, int NSTRIP, bool A_F32, int FUSE>
__global__ __launch_bounds__(256) void gemm_mfma2(const void* __restrict__ Ap,
    const ushort_t* __restrict__ Wt, ushort_t* __restrict__ C, int M,
    const float* __restrict__ att, float* __restrict__ al, float* __restrict__ ar) {
  __shared__ ushort_t As[NSTRIP][16][KPAD];
  const int tid = threadIdx.x;
  const int row_base = blockIdx.x * (NSTRIP * 16);
  // ---- stage A strip(s) into LDS ----
  constexpr int CHUNKS = NSTRIP * 16 * (KDIM / 8);
  for (int c = tid; c < CHUNKS; c += 256) {
    const int r = c / (KDIM / 8);
    const int ko = (c - r * (KDIM / 8)) * 8;
    const int s = r >> 4, rr = r & 15;
    uint4 w = make_uint4(0u, 0u, 0u, 0u);
    if (row_base + r < M) {
      if (A_F32) {
        const float* A = (const float*)Ap + (size_t)(row_base + r) * KDIM + ko;
        const float4 lo = *reinterpret_cast<const float4*>(A);
        const float4 hi = *reinterpret_cast<const float4*>(A + 4);
        w.x = (unsigned)f2b(lo.x) | ((unsigned)f2b(lo.y) << 16);
        w.y = (unsigned)f2b(lo.z) | ((unsigned)f2b(lo.w) << 16);
        w.z = (unsigned)f2b(hi.x) | ((unsigned)f2b(hi.y) << 16);
        w.w = (unsigned)f2b(hi.z) | ((unsigned)f2b(hi.w) << 16);
      } else {
        w = *reinterpret_cast<const uint4*>(
            (const ushort_t*)Ap + (size_t)(row_base + r) * KDIM + ko);
      }
    }
    *reinterpret_cast<uint4*>(&As[s][rr][ko]) = w;
  }
  __syncthreads();

  const int wid = tid >> 6, lane = tid & 63;
  const int s = wid / CG, cg = wid - s * CG;
  const int r_a = lane & 15, kg = lane >> 4;
  const int row0 = row_base + s * 16;
  constexpr int N = CG * NFW * 16;

  f32x4 acc[NFW];
#pragma unroll
  for (int f = 0; f < NFW; ++f) acc[f] = (f32x4){0.f, 0.f, 0.f, 0.f};

  for (int k0 = 0; k0 < KDIM; k0 += 32) {
    const short8v a = *reinterpret_cast<const short8v*>(&As[s][r_a][k0 + kg * 8]);
#pragma unroll
    for (int f = 0; f < NFW; ++f) {
      const short8v b = *reinterpret_cast<const short8v*>(
          Wt + (size_t)((cg * NFW + f) * 16 + r_a) * KDIM + k0 + kg * 8);
      acc[f] = __builtin_amdgcn_mfma_f32_16x16x32_bf16(a, b, acc[f], 0, 0, 0);
    }
  }
  if (row0 >= M) return;   // after barrier: safe
  // C store: D layout col = lane&15, row = (lane>>4)*4 + reg
#pragma unroll
  for (int f = 0; f < NFW; ++f) {
#pragma unroll
    for (int r = 0; r < 4; ++r) {
      C[(size_t)(row0 + kg * 4 + r) * N + (cg * NFW + f) * 16 + r_a] = f2b(acc[f][r]);
    }
  }
  if (FUSE == 1) {
    // head == cg (64 cols per head): dot over this wave's 64 cols
    float hpl[4] = {0.f, 0.f, 0.f, 0.f}, hpr[4] = {0.f, 0.f, 0.f, 0.f};
#pragma unroll
    for (int f = 0; f < NFW; ++f) {
      const int cc = f * 16 + r_a;
      const float wlv = att[cg * 128 + cc];
      const float wrv = att[cg * 128 + 64 + cc];
#pragma unroll
      for (int r = 0; r < 4; ++r) {
        hpl[r] = fmaf(acc[f][r], wlv, hpl[r]);
        hpr[r] = fmaf(acc[f][r], wrv, hpr[r]);
      }
    }
#pragma unroll
    for (int o = 1; o < 16; o <<= 1) {
#pragma unroll
      for (int r = 0; r < 4; ++r) {
        hpl[r] += __shfl_xor(hpl[r], o);
        hpr[r] += __shfl_xor(hpr[r], o);
      }
    }
    if (r_a == 0) {
#pragma unroll
      for (int r = 0; r < 4; ++r) {
        const int row = row0 + kg * 4 + r;
        al[(size_t)row * 4 + cg] = hpl[r];
        ar[(size_t)row * 4 + cg] = hpr[r];
      }
    }
  } else if (FUSE == 2) {
    // two heads per cg (C_head=40): predicated accumulation per lane
    float hpa[4] = {0,0,0,0}, hpb[4] = {0,0,0,0};
    float hra[4] = {0,0,0,0}, hrb[4] = {0,0,0,0};
#pragma unroll
    for (int f = 0; f < NFW; ++f) {
      const int col = cg * 80 + f * 16 + r_a;
      const int hd = col / 40;
      const int cc = col - hd * 40;
      const float wlv = att[hd * 80 + cc];
      const float wrv = att[hd * 80 + 40 + cc];
      const bool isB = (hd & 1);
#pragma unroll
      for (int r = 0; r < 4; ++r) {
        const float v = acc[f][r];
        if (isB) { hpb[r] = fmaf(v, wlv, hpb[r]); hrb[r] = fmaf(v, wrv, hrb[r]); }
        else     { hpa[r] = fmaf(v, wlv, hpa[r]); hra[r] = fmaf(v, wrv, hra[r]); }
      }
    }
#pragma unroll
    for (int o = 1; o < 16; o <<= 1) {
#pragma unroll
      for (int r = 0; r < 4; ++r) {
        hpa[r] += __shfl_xor(hpa[r], o); hpb[r] += __shfl_xor(hpb[r], o);
        hra[r] += __shfl_xor(hra[r], o); hrb[r] += __shfl_xor(hrb[r], o);
      }
    }
    if (r_a == 0) {
#pragma unroll
      for (int r = 0; r < 4; ++r) {
        const int row = row0 + kg * 4 + r;
        al[(size_t)row * 4 + cg * 2 + 0] = hpa[r];
        al[(size_t)row * 4 + cg * 2 + 1] = hpb[r];
        ar[(size_t)row * 4 + cg * 2 + 0] = hra[r];
        ar[(size_t)row * 4 + cg * 2 + 1] = hrb[r];
      }
    }
  }
}

// ---- CSR build ----------------------------------------------------------------
__global__ void hist_kernel(const int* __restrict__ src, int* __restrict__ deg, int E) {
  const int e = blockIdx.x * blockDim.x + threadIdx.x;
  if (e < E) atomicAdd(&deg[src[e]], 1);
}

__global__ __launch_bounds__(1024) void scan_kernel(const int* __restrict__ deg,
    int* __restrict__ rowstart, int n) {
  __shared__ int carry;
  __shared__ int wsum[16];
  const int tid = threadIdx.x;
  const int lane = tid & 63, w = tid >> 6;
  if (tid == 0) { carry = 0; rowstart[0] = 0; }
  __syncthreads();
  for (int base = 0; base < n; base += 1024) {
    const int idx = base + tid;
    int x = (idx < n) ? deg[idx] : 0;
#pragma unroll
    for (int o = 1; o < 64; o <<= 1) { int y = __shfl_up(x, o); if (lane >= o) x += y; }
    if (lane == 63) wsum[w] = x;
    __syncthreads();
    if (w == 0) {
      int s = (lane < 16) ? wsum[lane] : 0;
#pragma unroll
      for (int o = 1; o < 16; o <<= 1) { int y = __shfl_up(s, o); if (lane >= o) s += y; }
      if (lane < 16) wsum[lane] = s;
    }
    __syncthreads();
    const int add = (w > 0 ? wsum[w - 1] : 0) + carry;
    if (idx < n) rowstart[idx + 1] = x + add;
    __syncthreads();
    if (tid == 0) carry += wsum[15];
    __syncthreads();
  }
}

__global__ void scatter_kernel(const int* __restrict__ src, const int* __restrict__ dst,
    const int* __restrict__ rowstart, int* __restrict__ fill, int* __restrict__ scol,
    int E) {
  const int e = blockIdx.x * blockDim.x + threadIdx.x;
  if (e < E) {
    const int r = src[e];
    const int pos = rowstart[r] + atomicAdd(&fill[r], 1);
    scol[pos] = dst[e];
  }
}

// ---- fused softmax + aggregation v4: one wave per node ------------------------
template <int C, bool CONCAT_RELU>
__global__ __launch_bounds__(256) void gat_agg4(const ushort_t* __restrict__ h,
    const float* __restrict__ al, const float* __restrict__ ar,
    const int* __restrict__ rowstart, const int* __restrict__ scol,
    float* __restrict__ ew, const float* __restrict__ bias,
    void* __restrict__ outv, int n) {
  constexpr int ROW = HEADS * C;     // 256 / 160
  constexpr int LPG = ROW / 8;       // lanes per group: 32 / 20
  constexpr int NG  = 64 / LPG;      // groups: 2 / 3
  __shared__ float sm[4][CONCAT_RELU ? 1 : NG][CONCAT_RELU ? 1 : ROW];
  const int wid = threadIdx.x >> 6, lane = threadIdx.x & 63;
  const int i = blockIdx.x * 4 + wid;
  if (i >= n) return;                // never taken (30000 % 4 == 0)
  const int s0 = rowstart[i], s1 = rowstart[i + 1];

  const float4 al4 = *reinterpret_cast<const float4*>(al + (size_t)i * 4);
  const float4 ari = *reinterpret_cast<const float4*>(ar + (size_t)i * 4);
  const float es0 = __expf(lrelu(al4.x + ari.x));
  const float es1 = __expf(lrelu(al4.y + ari.y));
  const float es2 = __expf(lrelu(al4.z + ari.z));
  const float es3 = __expf(lrelu(al4.w + ari.w));

  // ---- sweep 1: exp + denom-sum + store ew ----
  float t0 = 0.f, t1 = 0.f, t2 = 0.f, t3 = 0.f;
  for (int e = s0 + lane; e < s1; e += 64) {
    const int j = scol[e];
    const float4 a = *reinterpret_cast<const float4*>(ar + (size_t)j * 4);
    const float w0 = __expf(lrelu(al4.x + a.x));
    const float w1 = __expf(lrelu(al4.y + a.y));
    const float w2 = __expf(lrelu(al4.z + a.z));
    const float w3 = __expf(lrelu(al4.w + a.w));
    t0 += w0; t1 += w1; t2 += w2; t3 += w3;
    *reinterpret_cast<float4*>(ew + (size_t)e * 4) = make_float4(w0, w1, w2, w3);
  }
#pragma unroll
  for (int o = 32; o; o >>= 1) {
    t0 += __shfl_xor(t0, o); t1 += __shfl_xor(t1, o);
    t2 += __shfl_xor(t2, o); t3 += __shfl_xor(t3, o);
  }
  const float i0 = 1.f / (t0 + es0 + EPSV), i1 = 1.f / (t1 + es1 + EPSV);
  const float i2 = 1.f / (t2 + es2 + EPSV), i3 = 1.f / (t3 + es3 + EPSV);

  // ---- group geometry ----
  const int g  = lane / LPG;
  const int cl = lane - g * LPG;
  const bool act = g < NG;
  const int hd = (cl * 8) / C;
  const float inv_h = hd < 2 ? (hd == 0 ? i0 : i1) : (hd == 2 ? i2 : i3);
  const float es_h  = hd < 2 ? (hd == 0 ? es0 : es1) : (hd == 2 ? es2 : es3);

  float acc[8];
#pragma unroll
  for (int k = 0; k < 8; ++k) acc[k] = 0.f;

  // self-loop (group 0 only)
  if (g == 0) {
    const float w = es_h * inv_h;
    const uint4 hv = *reinterpret_cast<const uint4*>(h + (size_t)i * ROW + cl * 8);
    acc[0] = w * b2f_lo(hv.x); acc[1] = w * b2f_hi(hv.x);
    acc[2] = w * b2f_lo(hv.y); acc[3] = w * b2f_hi(hv.y);
    acc[4] = w * b2f_lo(hv.z); acc[5] = w * b2f_hi(hv.z);
    acc[6] = w * b2f_lo(hv.w); acc[7] = w * b2f_hi(hv.w);
  }

  // ---- gather: uniform scol loads, unroll-2, index prefetch ----
  if (act) {
    int e = s0 + g;
    int ja = scol[min(e, N_EDGESN - 1)];
    int jb = scol[min(e + NG, N_EDGESN - 1)];
    for (; e + NG < s1; e += 2 * NG) {
      const int jc = scol[min(e + 2 * NG, N_EDGESN - 1)];
      const int jd = scol[min(e + 3 * NG, N_EDGESN - 1)];
      const uint4 ha = *reinterpret_cast<const uint4*>(h + (size_t)ja * ROW + cl * 8);
      const uint4 hb = *reinterpret_cast<const uint4*>(h + (size_t)jb * ROW + cl * 8);
      const float wa = ew[(size_t)e * 4 + hd] * inv_h;
      const float wb = ew[(size_t)(e + NG) * 4 + hd] * inv_h;
      acc[0] = fmaf(wa, b2f_lo(ha.x), acc[0]); acc[1] = fmaf(wa, b2f_hi(ha.x), acc[1]);
      acc[2] = fmaf(wa, b2f_lo(ha.y), acc[2]); acc[3] = fmaf(wa, b2f_hi(ha.y), acc[3]);
      acc[4] = fmaf(wa, b2f_lo(ha.z), acc[4]); acc[5] = fmaf(wa, b2f_hi(ha.z), acc[5]);
      acc[6] = fmaf(wa, b2f_lo(ha.w), acc[6]); acc[7] = fmaf(wa, b2f_hi(ha.w), acc[7]);
      acc[0] = fmaf(wb, b2f_lo(hb.x), acc[0]); acc[1] = fmaf(wb, b2f_hi(hb.x), acc[1]);
      acc[2] = fmaf(wb, b2f_lo(hb.y), acc[2]); acc[3] = fmaf(wb, b2f_hi(hb.y), acc[3]);
      acc[4] = fmaf(wb, b2f_lo(hb.z), acc[4]); acc[5] = fmaf(wb, b2f_hi(hb.z), acc[5]);
      acc[6] = fmaf(wb, b2f_lo(hb.w), acc[6]); acc[7] = fmaf(wb, b2f_hi(hb.w), acc[7]);
      ja = jc; jb = jd;
    }
    if (e < s1) {
      const uint4 ha = *reinterpret_cast<const uint4*>(h + (size_t)ja * ROW + cl * 8);
      const float wa = ew[(size_t)e * 4 + hd] * inv_h;
      acc[0] = fmaf(wa, b2f_lo(ha.x), acc[0]); acc[1] = fmaf(wa, b2f_hi(ha.x), acc[1]);
      acc[2] = fmaf(wa, b2f_lo(ha.y), acc[2]); acc[3] = fmaf(wa, b2f_hi(ha.y), acc[3]);
      acc[4] = fmaf(wa, b2f_lo(ha.z), acc[4]); acc[5] = fmaf(wa, b2f_hi(ha.z), acc[5]);
      acc[6] = fmaf(wa, b2f_lo(ha.w), acc[6]); acc[7] = fmaf(wa, b2f_hi(ha.w), acc[7]);
    }
  }

  if (CONCAT_RELU) {
#pragma unroll
    for (int k = 0; k < 8; ++k) acc[k] += __shfl_xor(acc[k], 32);
    if (g == 0) {
      const float4 blo = *reinterpret_cast<const float4*>(bias + cl * 8);
      const float4 bhi = *reinterpret_cast<const float4*>(bias + cl * 8 + 4);
      uint4 st;
      st.x = (unsigned)f2b(fmaxf(acc[0] + blo.x, 0.f)) |
             ((unsigned)f2b(fmaxf(acc[1] + blo.y, 0.f)) << 16);
      st.y = (unsigned)f2b(fmaxf(acc[2] + blo.z, 0.f)) |
             ((unsigned)f2b(fmaxf(acc[3] + blo.w, 0.f)) << 16);
      st.z = (unsigned)f2b(fmaxf(acc[4] + bhi.x, 0.f)) |
             ((unsigned)f2b(fmaxf(acc[5] + bhi.y, 0.f)) << 16);
      st.w = (unsigned)f2b(fmaxf(acc[6] + bhi.z, 0.f)) |
             ((unsigned)f2b(fmaxf(acc[7] + bhi.w, 0.f)) << 16);
      *reinterpret_cast<uint4*>((ushort_t*)outv + (size_t)i * ROW + cl * 8) = st;
    }
  } else {
    if (act) {
#pragma unroll
      for (int k = 0; k < 8; ++k) sm[wid][g][cl * 8 + k] = acc[k];
    }
    __syncthreads();
    if (lane < C) {
      float s = 0.f;
#pragma unroll
      for (int gg = 0; gg < NG; ++gg) {
#pragma unroll
        for (int hh = 0; hh < HEADS; ++hh) s += sm[wid][gg][hh * C + lane];
      }
      ((float*)outv)[(size_t)i * C + lane] = s * 0.25f + bias[lane];
    }
  }
}

// ---- launch -------------------------------------------------------------------
extern "C" void kernel_launch(void* const* d_in, const int* in_sizes, int n_in,
                              void* d_out, int out_size, void* d_ws, size_t ws_size,
                              hipStream_t stream) {
  const float* x    = (const float*)d_in[0];
  const int*   ei   = (const int*)d_in[1];
  const float* w0   = (const float*)d_in[2];
  const float* att0 = (const float*)d_in[3];
  const float* b0   = (const float*)d_in[4];
  const float* w1   = (const float*)d_in[5];
  const float* att1 = (const float*)d_in[6];
  const float* b1   = (const float*)d_in[7];
  float* out = (float*)d_out;

  char* ws = (char*)d_ws;
  size_t off = 0;
  auto alloc = [&](size_t bytes) -> void* {
    void* p = ws + off;
    off += (bytes + 255) & ~(size_t)255;
    return p;
  };
  ushort_t* h0b = (ushort_t*)alloc((size_t)N_NODES * HC0 * 2);  // 15.4 MB
  ushort_t* o0b = (ushort_t*)alloc((size_t)N_NODES * HC0 * 2);  // 15.4 MB
  float* al0 = (float*)alloc((size_t)N_NODES * HEADS * 4);
  float* ar0 = (float*)alloc((size_t)N_NODES * HEADS * 4);
  float* ew  = (float*)alloc((size_t)N_EDGESN * 4 * 4);         // 7.7 MB
  ushort_t* w0t = (ushort_t*)alloc((size_t)HC0 * NFEAT * 2);    // 128 KB
  ushort_t* w1t = (ushort_t*)alloc((size_t)HC1 * HC0 * 2);      // 80 KB
  int* deg      = (int*)alloc((size_t)N_NODES * 4);
  int* rowstart = (int*)alloc((size_t)(N_NODES + 1) * 4);
  int* fill     = (int*)alloc((size_t)N_NODES * 4);
  int* scol     = (int*)alloc((size_t)N_EDGESN * 4);
  ushort_t* h1b = h0b;   // layer-0 h dead after layer-0 agg
  float* al1 = al0;
  float* ar1 = ar0;

  const int* srcp = ei;
  const int* dstp = ei + N_EDGESN;

  hipMemsetAsync(deg, 0, N_NODES * 4, stream);
  hipMemsetAsync(fill, 0, N_NODES * 4, stream);
  hist_kernel<<<(N_EDGESN + 255) / 256, 256, 0, stream>>>(srcp, deg, N_EDGESN);
  scan_kernel<<<1, 1024, 0, stream>>>(deg, rowstart, N_NODES);
  scatter_kernel<<<(N_EDGESN + 255) / 256, 256, 0, stream>>>(srcp, dstp, rowstart,
                                                             fill, scol, N_EDGESN);
  wtrans<NFEAT, HC0><<<(NFEAT * HC0 + 255) / 256, 256, 0, stream>>>(w0, w0t);
  wtrans<HC0, HC1><<<(HC0 * HC1 + 255) / 256, 256, 0, stream>>>(w1, w1t);

  // layer 0: 4 col-groups (head each) x NFW=4, 1 strip/block -> 7500 waves
  gemm_mfma2<4, 4, 1, true, 1><<<N_NODES / 16, 256, 0, stream>>>(
      x, w0t, h0b, N_NODES, att0, al0, ar0);
  gat_agg4<C0V, true><<<(N_NODES + 3) / 4, 256, 0, stream>>>(
      h0b, al0, ar0, rowstart, scol, ew, b0, o0b, N_NODES);
  // layer 1: 2 col-groups x NFW=5, 2 strips/block -> 3750 waves; att fused
  gemm_mfma2<5, 2, 2, false, 2><<<(N_NODES + 31) / 32, 256, 0, stream>>>(
      o0b, w1t, h1b, N_NODES, att1, al1, ar1);
  gat_agg4<C1V, false><<<(N_NODES + 3) / 4, 256, 0, stream>>>(
      h1b, al1, ar1, rowstart, scol, ew, b1, out, N_NODES);
}

// Round 8
// 228.664 us; speedup vs baseline: 2.2040x; 1.0005x over previous
//
#include <hip/hip_runtime.h>
#include <math.h>

#define N_NODES 30000
#define N_EDGESN 480000
#define NFEAT 256
#define HEADS 4
#define C0V 64
#define C1V 40
#define HC0 (HEADS*C0V)   // 256
#define HC1 (HEADS*C1V)   // 160
#define NEG_SLOPE 0.2f
#define EPSV 1e-16f

typedef unsigned short ushort_t;
typedef __attribute__((ext_vector_type(8))) short short8v;
typedef __attribute__((ext_vector_type(4))) float f32x4;

__device__ __forceinline__ float lrelu(float x) { return x >= 0.f ? x : x * NEG_SLOPE; }

__device__ __forceinline__ float b2f(unsigned int u16) {
  union { unsigned int u; float f; } v; v.u = u16 << 16; return v.f;
}
__device__ __forceinline__ float b2f_lo(unsigned int u) {
  union { unsigned int u; float f; } v; v.u = u << 16; return v.f;
}
__device__ __forceinline__ float b2f_hi(unsigned int u) {
  union { unsigned int u; float f; } v; v.u = u & 0xffff0000u; return v.f;
}
__device__ __forceinline__ unsigned short f2b(float f) {
  union { float f; unsigned int u; } v; v.f = f;
  unsigned int u = v.u + 0x7FFFu + ((v.u >> 16) & 1u);   // round-nearest-even
  return (unsigned short)(u >> 16);
}

// ---- both weight transposes in one kernel (tiny) ------------------------------
__global__ __launch_bounds__(256) void wtrans_both(const float* __restrict__ W0,
    const float* __restrict__ W1, ushort_t* __restrict__ W0t,
    ushort_t* __restrict__ W1t) {
  const int idx = blockIdx.x * 256 + threadIdx.x;
  constexpr int T0 = NFEAT * HC0;   // 65536
  constexpr int T1 = HC0 * HC1;     // 40960
  if (idx < T0) {
    const int k = idx / HC0, nf = idx - k * HC0;
    W0t[(size_t)nf * NFEAT + k] = f2b(W0[idx]);
  } else if (idx < T0 + T1) {
    const int i2 = idx - T0;
    const int k = i2 / HC1, nf = i2 - k * HC1;
    W1t[(size_t)nf * HC0 + k] = f2b(W1[i2]);
  }
}

// ---- MFMA GEMM v2: C[M,N]=A[M,K]@W[K,N], K=256 fixed --------------------------
#define KDIM 256
#define KPAD 264
template <int NFW, int CG, int NSTRIP, bool A_F32, int FUSE>
__global__ __launch_bounds__(256) void gemm_mfma2(const void* __restrict__ Ap,
    const ushort_t* __restrict__ Wt, ushort_t* __restrict__ C, int M,
    const float* __restrict__ att, float* __restrict__ al, float* __restrict__ ar) {
  __shared__ ushort_t As[NSTRIP][16][KPAD];
  const int tid = threadIdx.x;
  const int row_base = blockIdx.x * (NSTRIP * 16);
  constexpr int CHUNKS = NSTRIP * 16 * (KDIM / 8);
  for (int c = tid; c < CHUNKS; c += 256) {
    const int r = c / (KDIM / 8);
    const int ko = (c - r * (KDIM / 8)) * 8;
    const int s = r >> 4, rr = r & 15;
    uint4 w = make_uint4(0u, 0u, 0u, 0u);
    if (row_base + r < M) {
      if (A_F32) {
        const float* A = (const float*)Ap + (size_t)(row_base + r) * KDIM + ko;
        const float4 lo = *reinterpret_cast<const float4*>(A);
        const float4 hi = *reinterpret_cast<const float4*>(A + 4);
        w.x = (unsigned)f2b(lo.x) | ((unsigned)f2b(lo.y) << 16);
        w.y = (unsigned)f2b(lo.z) | ((unsigned)f2b(lo.w) << 16);
        w.z = (unsigned)f2b(hi.x) | ((unsigned)f2b(hi.y) << 16);
        w.w = (unsigned)f2b(hi.z) | ((unsigned)f2b(hi.w) << 16);
      } else {
        w = *reinterpret_cast<const uint4*>(
            (const ushort_t*)Ap + (size_t)(row_base + r) * KDIM + ko);
      }
    }
    *reinterpret_cast<uint4*>(&As[s][rr][ko]) = w;
  }
  __syncthreads();

  const int wid = tid >> 6, lane = tid & 63;
  const int s = wid / CG, cg = wid - s * CG;
  const int r_a = lane & 15, kg = lane >> 4;
  const int row0 = row_base + s * 16;
  constexpr int N = CG * NFW * 16;

  f32x4 acc[NFW];
#pragma unroll
  for (int f = 0; f < NFW; ++f) acc[f] = (f32x4){0.f, 0.f, 0.f, 0.f};

  for (int k0 = 0; k0 < KDIM; k0 += 32) {
    const short8v a = *reinterpret_cast<const short8v*>(&As[s][r_a][k0 + kg * 8]);
#pragma unroll
    for (int f = 0; f < NFW; ++f) {
      const short8v b = *reinterpret_cast<const short8v*>(
          Wt + (size_t)((cg * NFW + f) * 16 + r_a) * KDIM + k0 + kg * 8);
      acc[f] = __builtin_amdgcn_mfma_f32_16x16x32_bf16(a, b, acc[f], 0, 0, 0);
    }
  }
  if (row0 >= M) return;   // after barrier: safe
#pragma unroll
  for (int f = 0; f < NFW; ++f) {
#pragma unroll
    for (int r = 0; r < 4; ++r) {
      C[(size_t)(row0 + kg * 4 + r) * N + (cg * NFW + f) * 16 + r_a] = f2b(acc[f][r]);
    }
  }
  if (FUSE == 1) {
    float hpl[4] = {0.f, 0.f, 0.f, 0.f}, hpr[4] = {0.f, 0.f, 0.f, 0.f};
#pragma unroll
    for (int f = 0; f < NFW; ++f) {
      const int cc = f * 16 + r_a;
      const float wlv = att[cg * 128 + cc];
      const float wrv = att[cg * 128 + 64 + cc];
#pragma unroll
      for (int r = 0; r < 4; ++r) {
        hpl[r] = fmaf(acc[f][r], wlv, hpl[r]);
        hpr[r] = fmaf(acc[f][r], wrv, hpr[r]);
      }
    }
#pragma unroll
    for (int o = 1; o < 16; o <<= 1) {
#pragma unroll
      for (int r = 0; r < 4; ++r) {
        hpl[r] += __shfl_xor(hpl[r], o);
        hpr[r] += __shfl_xor(hpr[r], o);
      }
    }
    if (r_a == 0) {
#pragma unroll
      for (int r = 0; r < 4; ++r) {
        const int row = row0 + kg * 4 + r;
        al[(size_t)row * 4 + cg] = hpl[r];
        ar[(size_t)row * 4 + cg] = hpr[r];
      }
    }
  } else if (FUSE == 2) {
    float hpa[4] = {0,0,0,0}, hpb[4] = {0,0,0,0};
    float hra[4] = {0,0,0,0}, hrb[4] = {0,0,0,0};
#pragma unroll
    for (int f = 0; f < NFW; ++f) {
      const int col = cg * 80 + f * 16 + r_a;
      const int hd = col / 40;
      const int cc = col - hd * 40;
      const float wlv = att[hd * 80 + cc];
      const float wrv = att[hd * 80 + 40 + cc];
      const bool isB = (hd & 1);
#pragma unroll
      for (int r = 0; r < 4; ++r) {
        const float v = acc[f][r];
        if (isB) { hpb[r] = fmaf(v, wlv, hpb[r]); hrb[r] = fmaf(v, wrv, hrb[r]); }
        else     { hpa[r] = fmaf(v, wlv, hpa[r]); hra[r] = fmaf(v, wrv, hra[r]); }
      }
    }
#pragma unroll
    for (int o = 1; o < 16; o <<= 1) {
#pragma unroll
      for (int r = 0; r < 4; ++r) {
        hpa[r] += __shfl_xor(hpa[r], o); hpb[r] += __shfl_xor(hpb[r], o);
        hra[r] += __shfl_xor(hra[r], o); hrb[r] += __shfl_xor(hrb[r], o);
      }
    }
    if (r_a == 0) {
#pragma unroll
      for (int r = 0; r < 4; ++r) {
        const int row = row0 + kg * 4 + r;
        al[(size_t)row * 4 + cg * 2 + 0] = hpa[r];
        al[(size_t)row * 4 + cg * 2 + 1] = hpb[r];
        ar[(size_t)row * 4 + cg * 2 + 0] = hra[r];
        ar[(size_t)row * 4 + cg * 2 + 1] = hrb[r];
      }
    }
  }
}

// ---- CSR build ----------------------------------------------------------------
__global__ void hist_kernel(const int* __restrict__ src, int* __restrict__ deg, int E) {
  const int e = blockIdx.x * blockDim.x + threadIdx.x;
  if (e < E) atomicAdd(&deg[src[e]], 1);
}

__global__ __launch_bounds__(1024) void scan_kernel(const int* __restrict__ deg,
    int* __restrict__ rowstart, int n) {
  __shared__ int carry;
  __shared__ int wsum[16];
  const int tid = threadIdx.x;
  const int lane = tid & 63, w = tid >> 6;
  if (tid == 0) { carry = 0; rowstart[0] = 0; }
  __syncthreads();
  for (int base = 0; base < n; base += 1024) {
    const int idx = base + tid;
    int x = (idx < n) ? deg[idx] : 0;
#pragma unroll
    for (int o = 1; o < 64; o <<= 1) { int y = __shfl_up(x, o); if (lane >= o) x += y; }
    if (lane == 63) wsum[w] = x;
    __syncthreads();
    if (w == 0) {
      int s = (lane < 16) ? wsum[lane] : 0;
#pragma unroll
      for (int o = 1; o < 16; o <<= 1) { int y = __shfl_up(s, o); if (lane >= o) s += y; }
      if (lane < 16) wsum[lane] = s;
    }
    __syncthreads();
    const int add = (w > 0 ? wsum[w - 1] : 0) + carry;
    if (idx < n) rowstart[idx + 1] = x + add;
    __syncthreads();
    if (tid == 0) carry += wsum[15];
    __syncthreads();
  }
}

__global__ void scatter_kernel(const int* __restrict__ src, const int* __restrict__ dst,
    const int* __restrict__ rowstart, int* __restrict__ fill, int* __restrict__ scol,
    int E) {
  const int e = blockIdx.x * blockDim.x + threadIdx.x;
  if (e < E) {
    const int r = src[e];
    const int pos = rowstart[r] + atomicAdd(&fill[r], 1);
    scol[pos] = dst[e];
  }
}

// ---- fused softmax + aggregation v5: one wave per node, unroll-4 gather -------
template <int C, bool CONCAT_RELU>
__global__ __launch_bounds__(256) void gat_agg5(const ushort_t* __restrict__ h,
    const float* __restrict__ al, const float* __restrict__ ar,
    const int* __restrict__ rowstart, const int* __restrict__ scol,
    float* __restrict__ ew, const float* __restrict__ bias,
    void* __restrict__ outv, int n) {
  constexpr int ROW = HEADS * C;     // 256 / 160
  constexpr int LPG = ROW / 8;       // lanes per group: 32 / 20
  constexpr int NG  = 64 / LPG;      // groups: 2 / 3
  constexpr int EMAX = N_EDGESN - 1;
  __shared__ float sm[4][CONCAT_RELU ? 1 : NG][CONCAT_RELU ? 1 : ROW];
  const int wid = threadIdx.x >> 6, lane = threadIdx.x & 63;
  const int i = blockIdx.x * 4 + wid;
  if (i >= n) return;                // never taken (30000 % 4 == 0)
  const int s0 = rowstart[i], s1 = rowstart[i + 1];

  const float4 al4 = *reinterpret_cast<const float4*>(al + (size_t)i * 4);
  const float4 ari = *reinterpret_cast<const float4*>(ar + (size_t)i * 4);
  const float es0 = __expf(lrelu(al4.x + ari.x));
  const float es1 = __expf(lrelu(al4.y + ari.y));
  const float es2 = __expf(lrelu(al4.z + ari.z));
  const float es3 = __expf(lrelu(al4.w + ari.w));

  // ---- sweep 1: exp + denom-sum + store ew (lane-parallel) ----
  float t0 = 0.f, t1 = 0.f, t2 = 0.f, t3 = 0.f;
  for (int e = s0 + lane; e < s1; e += 64) {
    const int j = scol[e];
    const float4 a = *reinterpret_cast<const float4*>(ar + (size_t)j * 4);
    const float w0 = __expf(lrelu(al4.x + a.x));
    const float w1 = __expf(lrelu(al4.y + a.y));
    const float w2 = __expf(lrelu(al4.z + a.z));
    const float w3 = __expf(lrelu(al4.w + a.w));
    t0 += w0; t1 += w1; t2 += w2; t3 += w3;
    *reinterpret_cast<float4*>(ew + (size_t)e * 4) = make_float4(w0, w1, w2, w3);
  }
#pragma unroll
  for (int o = 32; o; o >>= 1) {
    t0 += __shfl_xor(t0, o); t1 += __shfl_xor(t1, o);
    t2 += __shfl_xor(t2, o); t3 += __shfl_xor(t3, o);
  }
  const float i0 = 1.f / (t0 + es0 + EPSV), i1 = 1.f / (t1 + es1 + EPSV);
  const float i2 = 1.f / (t2 + es2 + EPSV), i3 = 1.f / (t3 + es3 + EPSV);

  // ---- group geometry ----
  const int g  = lane / LPG;
  const int cl = lane - g * LPG;
  const bool act = g < NG;
  const int hd = (cl * 8) / C;
  const float inv_h = hd < 2 ? (hd == 0 ? i0 : i1) : (hd == 2 ? i2 : i3);
  const float es_h  = hd < 2 ? (hd == 0 ? es0 : es1) : (hd == 2 ? es2 : es3);

  float acc[8];
#pragma unroll
  for (int k = 0; k < 8; ++k) acc[k] = 0.f;

  if (g == 0) {   // self-loop
    const float w = es_h * inv_h;
    const uint4 hv = *reinterpret_cast<const uint4*>(h + (size_t)i * ROW + cl * 8);
    acc[0] = w * b2f_lo(hv.x); acc[1] = w * b2f_hi(hv.x);
    acc[2] = w * b2f_lo(hv.y); acc[3] = w * b2f_hi(hv.y);
    acc[4] = w * b2f_lo(hv.z); acc[5] = w * b2f_hi(hv.z);
    acc[6] = w * b2f_lo(hv.w); acc[7] = w * b2f_hi(hv.w);
  }

#define FMA8(W, HV) \
  acc[0] = fmaf(W, b2f_lo(HV.x), acc[0]); acc[1] = fmaf(W, b2f_hi(HV.x), acc[1]); \
  acc[2] = fmaf(W, b2f_lo(HV.y), acc[2]); acc[3] = fmaf(W, b2f_hi(HV.y), acc[3]); \
  acc[4] = fmaf(W, b2f_lo(HV.z), acc[4]); acc[5] = fmaf(W, b2f_hi(HV.z), acc[5]); \
  acc[6] = fmaf(W, b2f_lo(HV.w), acc[6]); acc[7] = fmaf(W, b2f_hi(HV.w), acc[7])

  // ---- gather: unroll-4, 4 prefetched indices -> 4 row loads in flight ----
  if (act) {
    int e = s0 + g;
    int j0 = scol[min(e, EMAX)];
    int j1 = scol[min(e + NG, EMAX)];
    int j2 = scol[min(e + 2 * NG, EMAX)];
    int j3 = scol[min(e + 3 * NG, EMAX)];
    for (; e + 3 * NG < s1; e += 4 * NG) {
      const int p0 = scol[min(e + 4 * NG, EMAX)];
      const int p1 = scol[min(e + 5 * NG, EMAX)];
      const int p2 = scol[min(e + 6 * NG, EMAX)];
      const int p3 = scol[min(e + 7 * NG, EMAX)];
      const uint4 h0 = *reinterpret_cast<const uint4*>(h + (size_t)j0 * ROW + cl * 8);
      const uint4 h1 = *reinterpret_cast<const uint4*>(h + (size_t)j1 * ROW + cl * 8);
      const uint4 h2 = *reinterpret_cast<const uint4*>(h + (size_t)j2 * ROW + cl * 8);
      const uint4 h3 = *reinterpret_cast<const uint4*>(h + (size_t)j3 * ROW + cl * 8);
      const float w0 = ew[(size_t)e * 4 + hd] * inv_h;
      const float w1 = ew[(size_t)(e + NG) * 4 + hd] * inv_h;
      const float w2 = ew[(size_t)(e + 2 * NG) * 4 + hd] * inv_h;
      const float w3 = ew[(size_t)(e + 3 * NG) * 4 + hd] * inv_h;
      FMA8(w0, h0); FMA8(w1, h1); FMA8(w2, h2); FMA8(w3, h3);
      j0 = p0; j1 = p1; j2 = p2; j3 = p3;
    }
    for (; e < s1; e += NG) {
      const int j = scol[e];
      const float wa = ew[(size_t)e * 4 + hd] * inv_h;
      const uint4 ha = *reinterpret_cast<const uint4*>(h + (size_t)j * ROW + cl * 8);
      FMA8(wa, ha);
    }
  }
#undef FMA8

  if (CONCAT_RELU) {
#pragma unroll
    for (int k = 0; k < 8; ++k) acc[k] += __shfl_xor(acc[k], 32);
    if (g == 0) {
      const float4 blo = *reinterpret_cast<const float4*>(bias + cl * 8);
      const float4 bhi = *reinterpret_cast<const float4*>(bias + cl * 8 + 4);
      uint4 st;
      st.x = (unsigned)f2b(fmaxf(acc[0] + blo.x, 0.f)) |
             ((unsigned)f2b(fmaxf(acc[1] + blo.y, 0.f)) << 16);
      st.y = (unsigned)f2b(fmaxf(acc[2] + blo.z, 0.f)) |
             ((unsigned)f2b(fmaxf(acc[3] + blo.w, 0.f)) << 16);
      st.z = (unsigned)f2b(fmaxf(acc[4] + bhi.x, 0.f)) |
             ((unsigned)f2b(fmaxf(acc[5] + bhi.y, 0.f)) << 16);
      st.w = (unsigned)f2b(fmaxf(acc[6] + bhi.z, 0.f)) |
             ((unsigned)f2b(fmaxf(acc[7] + bhi.w, 0.f)) << 16);
      *reinterpret_cast<uint4*>((ushort_t*)outv + (size_t)i * ROW + cl * 8) = st;
    }
  } else {
    if (act) {
#pragma unroll
      for (int k = 0; k < 8; ++k) sm[wid][g][cl * 8 + k] = acc[k];
    }
    __syncthreads();
    if (lane < C) {
      float s = 0.f;
#pragma unroll
      for (int gg = 0; gg < NG; ++gg) {
#pragma unroll
        for (int hh = 0; hh < HEADS; ++hh) s += sm[wid][gg][hh * C + lane];
      }
      ((float*)outv)[(size_t)i * C + lane] = s * 0.25f + bias[lane];
    }
  }
}

// ---- launch -------------------------------------------------------------------
extern "C" void kernel_launch(void* const* d_in, const int* in_sizes, int n_in,
                              void* d_out, int out_size, void* d_ws, size_t ws_size,
                              hipStream_t stream) {
  const float* x    = (const float*)d_in[0];
  const int*   ei   = (const int*)d_in[1];
  const float* w0   = (const float*)d_in[2];
  const float* att0 = (const float*)d_in[3];
  const float* b0   = (const float*)d_in[4];
  const float* w1   = (const float*)d_in[5];
  const float* att1 = (const float*)d_in[6];
  const float* b1   = (const float*)d_in[7];
  float* out = (float*)d_out;

  char* ws = (char*)d_ws;
  size_t off = 0;
  auto alloc = [&](size_t bytes) -> void* {
    void* p = ws + off;
    off += (bytes + 255) & ~(size_t)255;
    return p;
  };
  ushort_t* h0b = (ushort_t*)alloc((size_t)N_NODES * HC0 * 2);  // 15.4 MB
  ushort_t* o0b = (ushort_t*)alloc((size_t)N_NODES * HC0 * 2);  // 15.4 MB
  float* al0 = (float*)alloc((size_t)N_NODES * HEADS * 4);
  float* ar0 = (float*)alloc((size_t)N_NODES * HEADS * 4);
  float* ew  = (float*)alloc((size_t)N_EDGESN * 4 * 4);         // 7.7 MB
  ushort_t* w0t = (ushort_t*)alloc((size_t)HC0 * NFEAT * 2);    // 128 KB
  ushort_t* w1t = (ushort_t*)alloc((size_t)HC1 * HC0 * 2);      // 80 KB
  int* deg      = (int*)alloc((size_t)N_NODES * 4);
  int* fill     = (int*)alloc((size_t)N_NODES * 4);   // adjacent to deg: one memset
  int* rowstart = (int*)alloc((size_t)(N_NODES + 1) * 4);
  int* scol     = (int*)alloc((size_t)N_EDGESN * 4);
  ushort_t* h1b = h0b;   // layer-0 h dead after layer-0 agg
  float* al1 = al0;
  float* ar1 = ar0;

  const int* srcp = ei;
  const int* dstp = ei + N_EDGESN;

  const size_t zlen = (size_t)((char*)fill - (char*)deg) + (size_t)N_NODES * 4;
  hipMemsetAsync(deg, 0, zlen, stream);   // zeroes deg + fill in one dispatch
  hist_kernel<<<(N_EDGESN + 255) / 256, 256, 0, stream>>>(srcp, deg, N_EDGESN);
  scan_kernel<<<1, 1024, 0, stream>>>(deg, rowstart, N_NODES);
  scatter_kernel<<<(N_EDGESN + 255) / 256, 256, 0, stream>>>(srcp, dstp, rowstart,
                                                             fill, scol, N_EDGESN);
  wtrans_both<<<(NFEAT * HC0 + HC0 * HC1 + 255) / 256, 256, 0, stream>>>(
      w0, w1, w0t, w1t);

  // layer 0
  gemm_mfma2<4, 4, 1, true, 1><<<N_NODES / 16, 256, 0, stream>>>(
      x, w0t, h0b, N_NODES, att0, al0, ar0);
  gat_agg5<C0V, true><<<(N_NODES + 3) / 4, 256, 0, stream>>>(
      h0b, al0, ar0, rowstart, scol, ew, b0, o0b, N_NODES);
  // layer 1
  gemm_mfma2<5, 2, 2, false, 2><<<(N_NODES + 31) / 32, 256, 0, stream>>>(
      o0b, w1t, h1b, N_NODES, att1, al1, ar1);
  gat_agg5<C1V, false><<<(N_NODES + 3) / 4, 256, 0, stream>>>(
      h1b, al1, ar1, rowstart, scol, ew, b1, out, N_NODES);
}

// Round 10
// 213.875 us; speedup vs baseline: 2.3564x; 1.0691x over previous
//
#include <hip/hip_runtime.h>
#include <math.h>

#define N_NODES 30000
#define N_EDGESN 480000
#define NFEAT 256
#define HEADS 4
#define C0V 64
#define C1V 40
#define HC0 (HEADS*C0V)   // 256
#define HC1 (HEADS*C1V)   // 160
#define NEG_SLOPE 0.2f
#define EPSV 1e-16f

typedef unsigned short ushort_t;
typedef __attribute__((ext_vector_type(8))) short short8v;
typedef __attribute__((ext_vector_type(4))) float f32x4;

__device__ __forceinline__ float lrelu(float x) { return x >= 0.f ? x : x * NEG_SLOPE; }

__device__ __forceinline__ float b2f(unsigned int u16) {
  union { unsigned int u; float f; } v; v.u = u16 << 16; return v.f;
}
__device__ __forceinline__ float b2f_lo(unsigned int u) {
  union { unsigned int u; float f; } v; v.u = u << 16; return v.f;
}
__device__ __forceinline__ float b2f_hi(unsigned int u) {
  union { unsigned int u; float f; } v; v.u = u & 0xffff0000u; return v.f;
}
__device__ __forceinline__ unsigned short f2b(float f) {
  union { float f; unsigned int u; } v; v.f = f;
  unsigned int u = v.u + 0x7FFFu + ((v.u >> 16) & 1u);   // round-nearest-even
  return (unsigned short)(u >> 16);
}

// ---- both weight transposes in one kernel (tiny) ------------------------------
__global__ __launch_bounds__(256) void wtrans_both(const float* __restrict__ W0,
    const float* __restrict__ W1, ushort_t* __restrict__ W0t,
    ushort_t* __restrict__ W1t) {
  const int idx = blockIdx.x * 256 + threadIdx.x;
  constexpr int T0 = NFEAT * HC0;   // 65536
  constexpr int T1 = HC0 * HC1;     // 40960
  if (idx < T0) {
    const int k = idx / HC0, nf = idx - k * HC0;
    W0t[(size_t)nf * NFEAT + k] = f2b(W0[idx]);
  } else if (idx < T0 + T1) {
    const int i2 = idx - T0;
    const int k = i2 / HC1, nf = i2 - k * HC1;
    W1t[(size_t)nf * HC0 + k] = f2b(W1[i2]);
  }
}

// ---- MFMA GEMM v2: C[M,N]=A[M,K]@W[K,N], K=256 fixed --------------------------
#define KDIM 256
#define KPAD 264
template <int NFW, int CG, int NSTRIP, bool A_F32, int FUSE>
__global__ __launch_bounds__(256) void gemm_mfma2(const void* __restrict__ Ap,
    const ushort_t* __restrict__ Wt, ushort_t* __restrict__ C, int M,
    const float* __restrict__ att, float* __restrict__ al, float* __restrict__ ar) {
  __shared__ ushort_t As[NSTRIP][16][KPAD];
  const int tid = threadIdx.x;
  const int row_base = blockIdx.x * (NSTRIP * 16);
  constexpr int CHUNKS = NSTRIP * 16 * (KDIM / 8);
  for (int c = tid; c < CHUNKS; c += 256) {
    const int r = c / (KDIM / 8);
    const int ko = (c - r * (KDIM / 8)) * 8;
    const int s = r >> 4, rr = r & 15;
    uint4 w = make_uint4(0u, 0u, 0u, 0u);
    if (row_base + r < M) {
      if (A_F32) {
        const float* A = (const float*)Ap + (size_t)(row_base + r) * KDIM + ko;
        const float4 lo = *reinterpret_cast<const float4*>(A);
        const float4 hi = *reinterpret_cast<const float4*>(A + 4);
        w.x = (unsigned)f2b(lo.x) | ((unsigned)f2b(lo.y) << 16);
        w.y = (unsigned)f2b(lo.z) | ((unsigned)f2b(lo.w) << 16);
        w.z = (unsigned)f2b(hi.x) | ((unsigned)f2b(hi.y) << 16);
        w.w = (unsigned)f2b(hi.z) | ((unsigned)f2b(hi.w) << 16);
      } else {
        w = *reinterpret_cast<const uint4*>(
            (const ushort_t*)Ap + (size_t)(row_base + r) * KDIM + ko);
      }
    }
    *reinterpret_cast<uint4*>(&As[s][rr][ko]) = w;
  }
  __syncthreads();

  const int wid = tid >> 6, lane = tid & 63;
  const int s = wid / CG, cg = wid - s * CG;
  const int r_a = lane & 15, kg = lane >> 4;
  const int row0 = row_base + s * 16;
  constexpr int N = CG * NFW * 16;

  f32x4 acc[NFW];
#pragma unroll
  for (int f = 0; f < NFW; ++f) acc[f] = (f32x4){0.f, 0.f, 0.f, 0.f};

#pragma unroll
  for (int k0 = 0; k0 < KDIM; k0 += 32) {
    const short8v a = *reinterpret_cast<const short8v*>(&As[s][r_a][k0 + kg * 8]);
#pragma unroll
    for (int f = 0; f < NFW; ++f) {
      const short8v b = *reinterpret_cast<const short8v*>(
          Wt + (size_t)((cg * NFW + f) * 16 + r_a) * KDIM + k0 + kg * 8);
      acc[f] = __builtin_amdgcn_mfma_f32_16x16x32_bf16(a, b, acc[f], 0, 0, 0);
    }
  }
  if (row0 >= M) return;   // after barrier: safe
#pragma unroll
  for (int f = 0; f < NFW; ++f) {
#pragma unroll
    for (int r = 0; r < 4; ++r) {
      C[(size_t)(row0 + kg * 4 + r) * N + (cg * NFW + f) * 16 + r_a] = f2b(acc[f][r]);
    }
  }
  if (FUSE == 1) {
    float hpl[4] = {0.f, 0.f, 0.f, 0.f}, hpr[4] = {0.f, 0.f, 0.f, 0.f};
#pragma unroll
    for (int f = 0; f < NFW; ++f) {
      const int cc = f * 16 + r_a;
      const float wlv = att[cg * 128 + cc];
      const float wrv = att[cg * 128 + 64 + cc];
#pragma unroll
      for (int r = 0; r < 4; ++r) {
        hpl[r] = fmaf(acc[f][r], wlv, hpl[r]);
        hpr[r] = fmaf(acc[f][r], wrv, hpr[r]);
      }
    }
#pragma unroll
    for (int o = 1; o < 16; o <<= 1) {
#pragma unroll
      for (int r = 0; r < 4; ++r) {
        hpl[r] += __shfl_xor(hpl[r], o);
        hpr[r] += __shfl_xor(hpr[r], o);
      }
    }
    if (r_a == 0) {
#pragma unroll
      for (int r = 0; r < 4; ++r) {
        const int row = row0 + kg * 4 + r;
        al[(size_t)row * 4 + cg] = hpl[r];
        ar[(size_t)row * 4 + cg] = hpr[r];
      }
    }
  } else if (FUSE == 2) {
    float hpa[4] = {0,0,0,0}, hpb[4] = {0,0,0,0};
    float hra[4] = {0,0,0,0}, hrb[4] = {0,0,0,0};
#pragma unroll
    for (int f = 0; f < NFW; ++f) {
      const int col = cg * 80 + f * 16 + r_a;
      const int hd = col / 40;
      const int cc = col - hd * 40;
      const float wlv = att[hd * 80 + cc];
      const float wrv = att[hd * 80 + 40 + cc];
      const bool isB = (hd & 1);
#pragma unroll
      for (int r = 0; r < 4; ++r) {
        const float v = acc[f][r];
        if (isB) { hpb[r] = fmaf(v, wlv, hpb[r]); hrb[r] = fmaf(v, wrv, hrb[r]); }
        else     { hpa[r] = fmaf(v, wlv, hpa[r]); hra[r] = fmaf(v, wrv, hra[r]); }
      }
    }
#pragma unroll
    for (int o = 1; o < 16; o <<= 1) {
#pragma unroll
      for (int r = 0; r < 4; ++r) {
        hpa[r] += __shfl_xor(hpa[r], o); hpb[r] += __shfl_xor(hpb[r], o);
        hra[r] += __shfl_xor(hra[r], o); hrb[r] += __shfl_xor(hrb[r], o);
      }
    }
    if (r_a == 0) {
#pragma unroll
      for (int r = 0; r < 4; ++r) {
        const int row = row0 + kg * 4 + r;
        al[(size_t)row * 4 + cg * 2 + 0] = hpa[r];
        al[(size_t)row * 4 + cg * 2 + 1] = hpb[r];
        ar[(size_t)row * 4 + cg * 2 + 0] = hra[r];
        ar[(size_t)row * 4 + cg * 2 + 1] = hrb[r];
      }
    }
  }
}

// ---- CSR build ----------------------------------------------------------------
__global__ void hist_kernel(const int* __restrict__ src, int* __restrict__ deg, int E) {
  const int e = blockIdx.x * blockDim.x + threadIdx.x;
  if (e < E) atomicAdd(&deg[src[e]], 1);
}

__global__ __launch_bounds__(1024) void scan_kernel(const int* __restrict__ deg,
    int* __restrict__ rowstart, int n) {
  __shared__ int carry;
  __shared__ int wsum[16];
  const int tid = threadIdx.x;
  const int lane = tid & 63, w = tid >> 6;
  if (tid == 0) { carry = 0; rowstart[0] = 0; }
  __syncthreads();
  for (int base = 0; base < n; base += 1024) {
    const int idx = base + tid;
    int x = (idx < n) ? deg[idx] : 0;
#pragma unroll
    for (int o = 1; o < 64; o <<= 1) { int y = __shfl_up(x, o); if (lane >= o) x += y; }
    if (lane == 63) wsum[w] = x;
    __syncthreads();
    if (w == 0) {
      int s = (lane < 16) ? wsum[lane] : 0;
#pragma unroll
      for (int o = 1; o < 16; o <<= 1) { int y = __shfl_up(s, o); if (lane >= o) s += y; }
      if (lane < 16) wsum[lane] = s;
    }
    __syncthreads();
    const int add = (w > 0 ? wsum[w - 1] : 0) + carry;
    if (idx < n) rowstart[idx + 1] = x + add;
    __syncthreads();
    if (tid == 0) carry += wsum[15];
    __syncthreads();
  }
}

__global__ void scatter_kernel(const int* __restrict__ src, const int* __restrict__ dst,
    const int* __restrict__ rowstart, int* __restrict__ fill, int* __restrict__ scol,
    int E) {
  const int e = blockIdx.x * blockDim.x + threadIdx.x;
  if (e < E) {
    const int r = src[e];
    const int pos = rowstart[r] + atomicAdd(&fill[r], 1);
    scol[pos] = dst[e];
  }
}

// ---- agg v6b: single pass, normalize after aggregation (FIXED reductions) -----
// All lanes of one head within a group compute IDENTICAL t (same edges, same
// weight) -> t is already the per-group head denom. Only combine across GROUPS:
// layer0 via xor32 (group partner has same head), layer1 via one representative
// smT entry per group.
template <int C, bool CONCAT_RELU>
__global__ __launch_bounds__(256) void gat_agg6(const ushort_t* __restrict__ h,
    const float* __restrict__ al, const float* __restrict__ ar,
    const int* __restrict__ rowstart, const int* __restrict__ scol,
    const float* __restrict__ bias, void* __restrict__ outv, int n) {
  constexpr int ROW = HEADS * C;     // 256 / 160
  constexpr int LPG = ROW / 8;       // lanes per group: 32 / 20
  constexpr int NG  = 64 / LPG;      // groups: 2 / 3
  constexpr int EMAX = N_EDGESN - 1;
  __shared__ float smA[CONCAT_RELU ? 1 : 4][CONCAT_RELU ? 1 : NG]
                      [CONCAT_RELU ? 1 : ROW];
  __shared__ float smT[CONCAT_RELU ? 1 : 4][CONCAT_RELU ? 1 : NG * LPG];
  const int wid = threadIdx.x >> 6, lane = threadIdx.x & 63;
  const int i = blockIdx.x * 4 + wid;
  if (i >= n) return;                // never taken (30000 % 4 == 0)
  const int s0 = rowstart[i], s1 = rowstart[i + 1];

  const float4 al4 = *reinterpret_cast<const float4*>(al + (size_t)i * 4);
  const float4 ari = *reinterpret_cast<const float4*>(ar + (size_t)i * 4);
  const float es0 = __expf(lrelu(al4.x + ari.x));
  const float es1 = __expf(lrelu(al4.y + ari.y));
  const float es2 = __expf(lrelu(al4.z + ari.z));
  const float es3 = __expf(lrelu(al4.w + ari.w));

  // ---- group geometry ----
  const int g  = lane / LPG;
  const int cl = lane - g * LPG;
  const bool act = g < NG;
  const int hd = (cl * 8) / C;       // lane's 8 channels are within one head
  const float al_h = hd < 2 ? (hd == 0 ? al4.x : al4.y) : (hd == 2 ? al4.z : al4.w);
  const float es_h = hd < 2 ? (hd == 0 ? es0 : es1) : (hd == 2 ? es2 : es3);

  float t = 0.f;                     // this group's denom for this head
  float acc[8];
#pragma unroll
  for (int k = 0; k < 8; ++k) acc[k] = 0.f;

  if (g == 0) {   // self-loop contribution (unnormalized)
    const uint4 hv = *reinterpret_cast<const uint4*>(h + (size_t)i * ROW + cl * 8);
    acc[0] = es_h * b2f_lo(hv.x); acc[1] = es_h * b2f_hi(hv.x);
    acc[2] = es_h * b2f_lo(hv.y); acc[3] = es_h * b2f_hi(hv.y);
    acc[4] = es_h * b2f_lo(hv.z); acc[5] = es_h * b2f_hi(hv.z);
    acc[6] = es_h * b2f_lo(hv.w); acc[7] = es_h * b2f_hi(hv.w);
  }

#define FMA8(W, HV) \
  acc[0] = fmaf(W, b2f_lo(HV.x), acc[0]); acc[1] = fmaf(W, b2f_hi(HV.x), acc[1]); \
  acc[2] = fmaf(W, b2f_lo(HV.y), acc[2]); acc[3] = fmaf(W, b2f_hi(HV.y), acc[3]); \
  acc[4] = fmaf(W, b2f_lo(HV.z), acc[4]); acc[5] = fmaf(W, b2f_hi(HV.z), acc[5]); \
  acc[6] = fmaf(W, b2f_lo(HV.w), acc[6]); acc[7] = fmaf(W, b2f_hi(HV.w), acc[7])

  // ---- single gather pass: unroll-2, index prefetch ----
  if (act) {
    int e = s0 + g;
    int ja = scol[min(e, EMAX)];
    int jb = scol[min(e + NG, EMAX)];
    for (; e + NG < s1; e += 2 * NG) {
      const int jc = scol[min(e + 2 * NG, EMAX)];
      const int jd = scol[min(e + 3 * NG, EMAX)];
      const float ara = ar[(size_t)ja * 4 + hd];
      const float arb = ar[(size_t)jb * 4 + hd];
      const uint4 ha = *reinterpret_cast<const uint4*>(h + (size_t)ja * ROW + cl * 8);
      const uint4 hb = *reinterpret_cast<const uint4*>(h + (size_t)jb * ROW + cl * 8);
      const float wa = __expf(lrelu(al_h + ara));
      const float wb = __expf(lrelu(al_h + arb));
      t += wa + wb;
      FMA8(wa, ha); FMA8(wb, hb);
      ja = jc; jb = jd;
    }
    if (e < s1) {
      const float ara = ar[(size_t)ja * 4 + hd];
      const uint4 ha = *reinterpret_cast<const uint4*>(h + (size_t)ja * ROW + cl * 8);
      const float wa = __expf(lrelu(al_h + ara));
      t += wa;
      FMA8(wa, ha);
    }
  }
#undef FMA8

  if (CONCAT_RELU) {
    // combine the two groups ONLY (all lanes of a head already hold the full
    // per-group sum; xor32 partner has the same head)
    t += __shfl_xor(t, 32);
    const float inv = 1.f / (t + es_h + EPSV);
#pragma unroll
    for (int k = 0; k < 8; ++k) acc[k] *= inv;
    // fold group 1 into group 0, lanes 0..31 store bf16
#pragma unroll
    for (int k = 0; k < 8; ++k) acc[k] += __shfl_xor(acc[k], 32);
    if (g == 0) {
      const float4 blo = *reinterpret_cast<const float4*>(bias + cl * 8);
      const float4 bhi = *reinterpret_cast<const float4*>(bias + cl * 8 + 4);
      uint4 st;
      st.x = (unsigned)f2b(fmaxf(acc[0] + blo.x, 0.f)) |
             ((unsigned)f2b(fmaxf(acc[1] + blo.y, 0.f)) << 16);
      st.y = (unsigned)f2b(fmaxf(acc[2] + blo.z, 0.f)) |
             ((unsigned)f2b(fmaxf(acc[3] + blo.w, 0.f)) << 16);
      st.z = (unsigned)f2b(fmaxf(acc[4] + bhi.x, 0.f)) |
             ((unsigned)f2b(fmaxf(acc[5] + bhi.y, 0.f)) << 16);
      st.w = (unsigned)f2b(fmaxf(acc[6] + bhi.z, 0.f)) |
             ((unsigned)f2b(fmaxf(acc[7] + bhi.w, 0.f)) << 16);
      *reinterpret_cast<uint4*>((ushort_t*)outv + (size_t)i * ROW + cl * 8) = st;
    }
  } else {
    // stage acc partials + denom partials, then per-head normalize + head-mean
    if (act) {
#pragma unroll
      for (int k = 0; k < 8; ++k) smA[wid][g][cl * 8 + k] = acc[k];
      smT[wid][g * LPG + cl] = t;
    }
    __syncthreads();
    if (lane < C) {
      const float es[4] = {es0, es1, es2, es3};
      float s = 0.f;
#pragma unroll
      for (int hh = 0; hh < HEADS; ++hh) {
        float den = es[hh];
#pragma unroll
        for (int gg = 0; gg < NG; ++gg)
          den += smT[wid][gg * LPG + hh * 5];   // ONE representative per group
        float chan = 0.f;
#pragma unroll
        for (int gg = 0; gg < NG; ++gg) chan += smA[wid][gg][hh * C + lane];
        s += chan / (den + EPSV);
      }
      ((float*)outv)[(size_t)i * C + lane] = s * 0.25f + bias[lane];
    }
  }
}

// ---- launch -------------------------------------------------------------------
extern "C" void kernel_launch(void* const* d_in, const int* in_sizes, int n_in,
                              void* d_out, int out_size, void* d_ws, size_t ws_size,
                              hipStream_t stream) {
  const float* x    = (const float*)d_in[0];
  const int*   ei   = (const int*)d_in[1];
  const float* w0   = (const float*)d_in[2];
  const float* att0 = (const float*)d_in[3];
  const float* b0   = (const float*)d_in[4];
  const float* w1   = (const float*)d_in[5];
  const float* att1 = (const float*)d_in[6];
  const float* b1   = (const float*)d_in[7];
  float* out = (float*)d_out;

  char* ws = (char*)d_ws;
  size_t off = 0;
  auto alloc = [&](size_t bytes) -> void* {
    void* p = ws + off;
    off += (bytes + 255) & ~(size_t)255;
    return p;
  };
  ushort_t* h0b = (ushort_t*)alloc((size_t)N_NODES * HC0 * 2);  // 15.4 MB
  ushort_t* o0b = (ushort_t*)alloc((size_t)N_NODES * HC0 * 2);  // 15.4 MB
  float* al0 = (float*)alloc((size_t)N_NODES * HEADS * 4);
  float* ar0 = (float*)alloc((size_t)N_NODES * HEADS * 4);
  ushort_t* w0t = (ushort_t*)alloc((size_t)HC0 * NFEAT * 2);    // 128 KB
  ushort_t* w1t = (ushort_t*)alloc((size_t)HC1 * HC0 * 2);      // 80 KB
  int* deg      = (int*)alloc((size_t)N_NODES * 4);
  int* fill     = (int*)alloc((size_t)N_NODES * 4);   // adjacent to deg: one memset
  int* rowstart = (int*)alloc((size_t)(N_NODES + 1) * 4);
  int* scol     = (int*)alloc((size_t)N_EDGESN * 4);
  ushort_t* h1b = h0b;   // layer-0 h dead after layer-0 agg
  float* al1 = al0;
  float* ar1 = ar0;

  const int* srcp = ei;
  const int* dstp = ei + N_EDGESN;

  const size_t zlen = (size_t)((char*)fill - (char*)deg) + (size_t)N_NODES * 4;
  hipMemsetAsync(deg, 0, zlen, stream);   // zeroes deg + fill in one dispatch
  hist_kernel<<<(N_EDGESN + 255) / 256, 256, 0, stream>>>(srcp, deg, N_EDGESN);
  scan_kernel<<<1, 1024, 0, stream>>>(deg, rowstart, N_NODES);
  scatter_kernel<<<(N_EDGESN + 255) / 256, 256, 0, stream>>>(srcp, dstp, rowstart,
                                                             fill, scol, N_EDGESN);
  wtrans_both<<<(NFEAT * HC0 + HC0 * HC1 + 255) / 256, 256, 0, stream>>>(
      w0, w1, w0t, w1t);

  // layer 0
  gemm_mfma2<4, 4, 1, true, 1><<<N_NODES / 16, 256, 0, stream>>>(
      x, w0t, h0b, N_NODES, att0, al0, ar0);
  gat_agg6<C0V, true><<<(N_NODES + 3) / 4, 256, 0, stream>>>(
      h0b, al0, ar0, rowstart, scol, b0, o0b, N_NODES);
  // layer 1
  gemm_mfma2<5, 2, 2, false, 2><<<(N_NODES + 31) / 32, 256, 0, stream>>>(
      o0b, w1t, h1b, N_NODES, att1, al1, ar1);
  gat_agg6<C1V, false><<<(N_NODES + 3) / 4, 256, 0, stream>>>(
      h1b, al1, ar1, rowstart, scol, b1, out, N_NODES);
}

// Round 11
// 196.882 us; speedup vs baseline: 2.5598x; 1.0863x over previous
//
#include <hip/hip_runtime.h>
#include <math.h>

#define N_NODES 30000
#define N_EDGESN 480000
#define NFEAT 256
#define HEADS 4
#define C0V 64
#define C1V 40
#define HC0 (HEADS*C0V)   // 256
#define HC1 (HEADS*C1V)   // 160
#define NEG_SLOPE 0.2f
#define EPSV 1e-16f
#define KDIM 256
#define KPAD 264

typedef unsigned short ushort_t;
typedef __attribute__((ext_vector_type(8))) short short8v;
typedef __attribute__((ext_vector_type(4))) float f32x4;

__device__ __forceinline__ float lrelu(float x) { return x >= 0.f ? x : x * NEG_SLOPE; }

__device__ __forceinline__ float b2f_lo(unsigned int u) {
  union { unsigned int u; float f; } v; v.u = u << 16; return v.f;
}
__device__ __forceinline__ float b2f_hi(unsigned int u) {
  union { unsigned int u; float f; } v; v.u = u & 0xffff0000u; return v.f;
}
__device__ __forceinline__ unsigned short f2b(float f) {
  union { float f; unsigned int u; } v; v.f = f;
  unsigned int u = v.u + 0x7FFFu + ((v.u >> 16) & 1u);   // round-nearest-even
  return (unsigned short)(u >> 16);
}

// ---- zero kernel (replaces runtime fillBuffer) --------------------------------
__global__ __launch_bounds__(256) void zero_kernel(int* __restrict__ p, int n) {
  const int i = blockIdx.x * 256 + threadIdx.x;
  if (i < n) p[i] = 0;
}

// ---- both weight transposes in one kernel (tiny) ------------------------------
__global__ __launch_bounds__(256) void wtrans_both(const float* __restrict__ W0,
    const float* __restrict__ W1, ushort_t* __restrict__ W0t,
    ushort_t* __restrict__ W1t) {
  const int idx = blockIdx.x * 256 + threadIdx.x;
  constexpr int T0 = NFEAT * HC0;   // 65536
  constexpr int T1 = HC0 * HC1;     // 40960
  if (idx < T0) {
    const int k = idx / HC0, nf = idx - k * HC0;
    W0t[(size_t)nf * NFEAT + k] = f2b(W0[idx]);
  } else if (idx < T0 + T1) {
    const int i2 = idx - T0;
    const int k = i2 / HC1, nf = i2 - k * HC1;
    W1t[(size_t)nf * HC0 + k] = f2b(W1[i2]);
  }
}

// ---- MFMA GEMM v3: B in registers, multi-strip blocks, double-buffered A ------
// Wave cg owns cols [cg*NFW*16, (cg+1)*NFW*16). B-frags (NFW x 8 ksteps) loaded
// ONCE per block into VGPRs. Each block processes strips blockIdx.x + k*nblk
// with LDS double-buffer: issue next strip's global loads, compute current,
// ds_write, one barrier per strip. FUSE: 1=layer0 att (head==cg), 2=layer1 att.
template <int NFW, int CG, bool A_F32, int FUSE, int NT>
__global__ __launch_bounds__(NT) void gemm_mfma3(const void* __restrict__ Ap,
    const ushort_t* __restrict__ Wt, ushort_t* __restrict__ C, int nblk,
    const float* __restrict__ att, float* __restrict__ al, float* __restrict__ ar) {
  constexpr int S = N_NODES / 16;           // 1875 strips (M % 16 == 0)
  constexpr int N = CG * NFW * 16;
  constexpr int NCH = 16 * (KDIM / 8) / NT; // staging chunks per thread
  __shared__ ushort_t As[2][16][KPAD];
  const int tid = threadIdx.x;
  const int lane = tid & 63, cg = tid >> 6;
  const int r_a = lane & 15, kg = lane >> 4;

  // ---- B fragments: registers for entire kernel ----
  short8v B[8][NFW];
#pragma unroll
  for (int ks = 0; ks < 8; ++ks)
#pragma unroll
    for (int f = 0; f < NFW; ++f)
      B[ks][f] = *reinterpret_cast<const short8v*>(
          Wt + (size_t)((cg * NFW + f) * 16 + r_a) * KDIM + ks * 32 + kg * 8);

#define STAGE_LOAD(STRIP, STG)                                                   \
  _Pragma("unroll")                                                              \
  for (int q = 0; q < NCH; ++q) {                                                \
    const int c = tid + q * NT;                                                  \
    const int r = c >> 5, ko = (c & 31) * 8;                                     \
    if (A_F32) {                                                                 \
      const float* A = (const float*)Ap + (size_t)((STRIP) * 16 + r) * KDIM + ko;\
      const float4 lo = *reinterpret_cast<const float4*>(A);                     \
      const float4 hi = *reinterpret_cast<const float4*>(A + 4);                 \
      STG[q].x = (unsigned)f2b(lo.x) | ((unsigned)f2b(lo.y) << 16);              \
      STG[q].y = (unsigned)f2b(lo.z) | ((unsigned)f2b(lo.w) << 16);              \
      STG[q].z = (unsigned)f2b(hi.x) | ((unsigned)f2b(hi.y) << 16);              \
      STG[q].w = (unsigned)f2b(hi.z) | ((unsigned)f2b(hi.w) << 16);              \
    } else {                                                                     \
      STG[q] = *reinterpret_cast<const uint4*>(                                  \
          (const ushort_t*)Ap + (size_t)((STRIP) * 16 + r) * KDIM + ko);         \
    }                                                                            \
  }
#define STAGE_WRITE(BUF, STG)                                                    \
  _Pragma("unroll")                                                              \
  for (int q = 0; q < NCH; ++q) {                                                \
    const int c = tid + q * NT;                                                  \
    const int r = c >> 5, ko = (c & 31) * 8;                                     \
    *reinterpret_cast<uint4*>(&As[BUF][r][ko]) = STG[q];                         \
  }

  int strip = blockIdx.x;
  {
    uint4 stg[NCH];
    STAGE_LOAD(strip, stg)
    STAGE_WRITE(0, stg)
  }
  __syncthreads();

  int buf = 0;
  while (true) {
    const int next = strip + nblk;
    const bool has_next = next < S;
    uint4 stg[NCH];
    if (has_next) { STAGE_LOAD(next, stg) }   // loads in flight during compute

    // ---- compute current strip: A from LDS, B from registers ----
    f32x4 acc[NFW];
#pragma unroll
    for (int f = 0; f < NFW; ++f) acc[f] = (f32x4){0.f, 0.f, 0.f, 0.f};
#pragma unroll
    for (int ks = 0; ks < 8; ++ks) {
      const short8v a =
          *reinterpret_cast<const short8v*>(&As[buf][r_a][ks * 32 + kg * 8]);
#pragma unroll
      for (int f = 0; f < NFW; ++f)
        acc[f] = __builtin_amdgcn_mfma_f32_16x16x32_bf16(a, B[ks][f], acc[f], 0, 0, 0);
    }
    const int row0 = strip * 16;
    // C store: D layout col = lane&15, row = (lane>>4)*4 + reg
#pragma unroll
    for (int f = 0; f < NFW; ++f) {
#pragma unroll
      for (int r = 0; r < 4; ++r) {
        C[(size_t)(row0 + kg * 4 + r) * N + (cg * NFW + f) * 16 + r_a] =
            f2b(acc[f][r]);
      }
    }
    if (FUSE == 1) {
      float hpl[4] = {0.f, 0.f, 0.f, 0.f}, hpr[4] = {0.f, 0.f, 0.f, 0.f};
#pragma unroll
      for (int f = 0; f < NFW; ++f) {
        const int cc = f * 16 + r_a;
        const float wlv = att[cg * 128 + cc];
        const float wrv = att[cg * 128 + 64 + cc];
#pragma unroll
        for (int r = 0; r < 4; ++r) {
          hpl[r] = fmaf(acc[f][r], wlv, hpl[r]);
          hpr[r] = fmaf(acc[f][r], wrv, hpr[r]);
        }
      }
#pragma unroll
      for (int o = 1; o < 16; o <<= 1) {
#pragma unroll
        for (int r = 0; r < 4; ++r) {
          hpl[r] += __shfl_xor(hpl[r], o);
          hpr[r] += __shfl_xor(hpr[r], o);
        }
      }
      if (r_a == 0) {
#pragma unroll
        for (int r = 0; r < 4; ++r) {
          const int row = row0 + kg * 4 + r;
          al[(size_t)row * 4 + cg] = hpl[r];
          ar[(size_t)row * 4 + cg] = hpr[r];
        }
      }
    } else if (FUSE == 2) {
      float hpa[4] = {0,0,0,0}, hpb[4] = {0,0,0,0};
      float hra[4] = {0,0,0,0}, hrb[4] = {0,0,0,0};
#pragma unroll
      for (int f = 0; f < NFW; ++f) {
        const int col = cg * 80 + f * 16 + r_a;
        const int hd = col / 40;
        const int cc = col - hd * 40;
        const float wlv = att[hd * 80 + cc];
        const float wrv = att[hd * 80 + 40 + cc];
        const bool isB = (hd & 1);
#pragma unroll
        for (int r = 0; r < 4; ++r) {
          const float v = acc[f][r];
          if (isB) { hpb[r] = fmaf(v, wlv, hpb[r]); hrb[r] = fmaf(v, wrv, hrb[r]); }
          else     { hpa[r] = fmaf(v, wlv, hpa[r]); hra[r] = fmaf(v, wrv, hra[r]); }
        }
      }
#pragma unroll
      for (int o = 1; o < 16; o <<= 1) {
#pragma unroll
        for (int r = 0; r < 4; ++r) {
          hpa[r] += __shfl_xor(hpa[r], o); hpb[r] += __shfl_xor(hpb[r], o);
          hra[r] += __shfl_xor(hra[r], o); hrb[r] += __shfl_xor(hrb[r], o);
        }
      }
      if (r_a == 0) {
#pragma unroll
        for (int r = 0; r < 4; ++r) {
          const int row = row0 + kg * 4 + r;
          al[(size_t)row * 4 + cg * 2 + 0] = hpa[r];
          al[(size_t)row * 4 + cg * 2 + 1] = hpb[r];
          ar[(size_t)row * 4 + cg * 2 + 0] = hra[r];
          ar[(size_t)row * 4 + cg * 2 + 1] = hrb[r];
        }
      }
    }

    if (!has_next) break;
    STAGE_WRITE(buf ^ 1, stg)
    __syncthreads();
    strip = next; buf ^= 1;
  }
#undef STAGE_LOAD
#undef STAGE_WRITE
}

// ---- CSR build ----------------------------------------------------------------
__global__ void hist_kernel(const int* __restrict__ src, int* __restrict__ deg, int E) {
  const int e = blockIdx.x * blockDim.x + threadIdx.x;
  if (e < E) atomicAdd(&deg[src[e]], 1);
}

__global__ __launch_bounds__(1024) void scan_kernel(const int* __restrict__ deg,
    int* __restrict__ rowstart, int n) {
  __shared__ int carry;
  __shared__ int wsum[16];
  const int tid = threadIdx.x;
  const int lane = tid & 63, w = tid >> 6;
  if (tid == 0) { carry = 0; rowstart[0] = 0; }
  __syncthreads();
  for (int base = 0; base < n; base += 1024) {
    const int idx = base + tid;
    int x = (idx < n) ? deg[idx] : 0;
#pragma unroll
    for (int o = 1; o < 64; o <<= 1) { int y = __shfl_up(x, o); if (lane >= o) x += y; }
    if (lane == 63) wsum[w] = x;
    __syncthreads();
    if (w == 0) {
      int s = (lane < 16) ? wsum[lane] : 0;
#pragma unroll
      for (int o = 1; o < 16; o <<= 1) { int y = __shfl_up(s, o); if (lane >= o) s += y; }
      if (lane < 16) wsum[lane] = s;
    }
    __syncthreads();
    const int add = (w > 0 ? wsum[w - 1] : 0) + carry;
    if (idx < n) rowstart[idx + 1] = x + add;
    __syncthreads();
    if (tid == 0) carry += wsum[15];
    __syncthreads();
  }
}

__global__ void scatter_kernel(const int* __restrict__ src, const int* __restrict__ dst,
    const int* __restrict__ rowstart, int* __restrict__ fill, int* __restrict__ scol,
    int E) {
  const int e = blockIdx.x * blockDim.x + threadIdx.x;
  if (e < E) {
    const int r = src[e];
    const int pos = rowstart[r] + atomicAdd(&fill[r], 1);
    scol[pos] = dst[e];
  }
}

// ---- agg v6b: single pass, normalize after aggregation ------------------------
template <int C, bool CONCAT_RELU>
__global__ __launch_bounds__(256) void gat_agg6(const ushort_t* __restrict__ h,
    const float* __restrict__ al, const float* __restrict__ ar,
    const int* __restrict__ rowstart, const int* __restrict__ scol,
    const float* __restrict__ bias, void* __restrict__ outv, int n) {
  constexpr int ROW = HEADS * C;     // 256 / 160
  constexpr int LPG = ROW / 8;       // lanes per group: 32 / 20
  constexpr int NG  = 64 / LPG;      // groups: 2 / 3
  constexpr int EMAX = N_EDGESN - 1;
  __shared__ float smA[CONCAT_RELU ? 1 : 4][CONCAT_RELU ? 1 : NG]
                      [CONCAT_RELU ? 1 : ROW];
  __shared__ float smT[CONCAT_RELU ? 1 : 4][CONCAT_RELU ? 1 : NG * LPG];
  const int wid = threadIdx.x >> 6, lane = threadIdx.x & 63;
  const int i = blockIdx.x * 4 + wid;
  if (i >= n) return;                // never taken (30000 % 4 == 0)
  const int s0 = rowstart[i], s1 = rowstart[i + 1];

  const float4 al4 = *reinterpret_cast<const float4*>(al + (size_t)i * 4);
  const float4 ari = *reinterpret_cast<const float4*>(ar + (size_t)i * 4);
  const float es0 = __expf(lrelu(al4.x + ari.x));
  const float es1 = __expf(lrelu(al4.y + ari.y));
  const float es2 = __expf(lrelu(al4.z + ari.z));
  const float es3 = __expf(lrelu(al4.w + ari.w));

  const int g  = lane / LPG;
  const int cl = lane - g * LPG;
  const bool act = g < NG;
  const int hd = (cl * 8) / C;
  const float al_h = hd < 2 ? (hd == 0 ? al4.x : al4.y) : (hd == 2 ? al4.z : al4.w);
  const float es_h = hd < 2 ? (hd == 0 ? es0 : es1) : (hd == 2 ? es2 : es3);

  float t = 0.f;
  float acc[8];
#pragma unroll
  for (int k = 0; k < 8; ++k) acc[k] = 0.f;

  if (g == 0) {   // self-loop contribution (unnormalized)
    const uint4 hv = *reinterpret_cast<const uint4*>(h + (size_t)i * ROW + cl * 8);
    acc[0] = es_h * b2f_lo(hv.x); acc[1] = es_h * b2f_hi(hv.x);
    acc[2] = es_h * b2f_lo(hv.y); acc[3] = es_h * b2f_hi(hv.y);
    acc[4] = es_h * b2f_lo(hv.z); acc[5] = es_h * b2f_hi(hv.z);
    acc[6] = es_h * b2f_lo(hv.w); acc[7] = es_h * b2f_hi(hv.w);
  }

#define FMA8(W, HV) \
  acc[0] = fmaf(W, b2f_lo(HV.x), acc[0]); acc[1] = fmaf(W, b2f_hi(HV.x), acc[1]); \
  acc[2] = fmaf(W, b2f_lo(HV.y), acc[2]); acc[3] = fmaf(W, b2f_hi(HV.y), acc[3]); \
  acc[4] = fmaf(W, b2f_lo(HV.z), acc[4]); acc[5] = fmaf(W, b2f_hi(HV.z), acc[5]); \
  acc[6] = fmaf(W, b2f_lo(HV.w), acc[6]); acc[7] = fmaf(W, b2f_hi(HV.w), acc[7])

  if (act) {
    int e = s0 + g;
    int ja = scol[min(e, EMAX)];
    int jb = scol[min(e + NG, EMAX)];
    for (; e + NG < s1; e += 2 * NG) {
      const int jc = scol[min(e + 2 * NG, EMAX)];
      const int jd = scol[min(e + 3 * NG, EMAX)];
      const float ara = ar[(size_t)ja * 4 + hd];
      const float arb = ar[(size_t)jb * 4 + hd];
      const uint4 ha = *reinterpret_cast<const uint4*>(h + (size_t)ja * ROW + cl * 8);
      const uint4 hb = *reinterpret_cast<const uint4*>(h + (size_t)jb * ROW + cl * 8);
      const float wa = __expf(lrelu(al_h + ara));
      const float wb = __expf(lrelu(al_h + arb));
      t += wa + wb;
      FMA8(wa, ha); FMA8(wb, hb);
      ja = jc; jb = jd;
    }
    if (e < s1) {
      const float ara = ar[(size_t)ja * 4 + hd];
      const uint4 ha = *reinterpret_cast<const uint4*>(h + (size_t)ja * ROW + cl * 8);
      const float wa = __expf(lrelu(al_h + ara));
      t += wa;
      FMA8(wa, ha);
    }
  }
#undef FMA8

  if (CONCAT_RELU) {
    t += __shfl_xor(t, 32);            // combine the two groups ONLY
    const float inv = 1.f / (t + es_h + EPSV);
#pragma unroll
    for (int k = 0; k < 8; ++k) acc[k] *= inv;
#pragma unroll
    for (int k = 0; k < 8; ++k) acc[k] += __shfl_xor(acc[k], 32);
    if (g == 0) {
      const float4 blo = *reinterpret_cast<const float4*>(bias + cl * 8);
      const float4 bhi = *reinterpret_cast<const float4*>(bias + cl * 8 + 4);
      uint4 st;
      st.x = (unsigned)f2b(fmaxf(acc[0] + blo.x, 0.f)) |
             ((unsigned)f2b(fmaxf(acc[1] + blo.y, 0.f)) << 16);
      st.y = (unsigned)f2b(fmaxf(acc[2] + blo.z, 0.f)) |
             ((unsigned)f2b(fmaxf(acc[3] + blo.w, 0.f)) << 16);
      st.z = (unsigned)f2b(fmaxf(acc[4] + bhi.x, 0.f)) |
             ((unsigned)f2b(fmaxf(acc[5] + bhi.y, 0.f)) << 16);
      st.w = (unsigned)f2b(fmaxf(acc[6] + bhi.z, 0.f)) |
             ((unsigned)f2b(fmaxf(acc[7] + bhi.w, 0.f)) << 16);
      *reinterpret_cast<uint4*>((ushort_t*)outv + (size_t)i * ROW + cl * 8) = st;
    }
  } else {
    if (act) {
#pragma unroll
      for (int k = 0; k < 8; ++k) smA[wid][g][cl * 8 + k] = acc[k];
      smT[wid][g * LPG + cl] = t;
    }
    __syncthreads();
    if (lane < C) {
      const float es[4] = {es0, es1, es2, es3};
      float s = 0.f;
#pragma unroll
      for (int hh = 0; hh < HEADS; ++hh) {
        float den = es[hh];
#pragma unroll
        for (int gg = 0; gg < NG; ++gg)
          den += smT[wid][gg * LPG + hh * 5];   // ONE representative per group
        float chan = 0.f;
#pragma unroll
        for (int gg = 0; gg < NG; ++gg) chan += smA[wid][gg][hh * C + lane];
        s += chan / (den + EPSV);
      }
      ((float*)outv)[(size_t)i * C + lane] = s * 0.25f + bias[lane];
    }
  }
}

// ---- launch -------------------------------------------------------------------
extern "C" void kernel_launch(void* const* d_in, const int* in_sizes, int n_in,
                              void* d_out, int out_size, void* d_ws, size_t ws_size,
                              hipStream_t stream) {
  const float* x    = (const float*)d_in[0];
  const int*   ei   = (const int*)d_in[1];
  const float* w0   = (const float*)d_in[2];
  const float* att0 = (const float*)d_in[3];
  const float* b0   = (const float*)d_in[4];
  const float* w1   = (const float*)d_in[5];
  const float* att1 = (const float*)d_in[6];
  const float* b1   = (const float*)d_in[7];
  float* out = (float*)d_out;

  char* ws = (char*)d_ws;
  size_t off = 0;
  auto alloc = [&](size_t bytes) -> void* {
    void* p = ws + off;
    off += (bytes + 255) & ~(size_t)255;
    return p;
  };
  ushort_t* h0b = (ushort_t*)alloc((size_t)N_NODES * HC0 * 2);  // 15.4 MB
  ushort_t* o0b = (ushort_t*)alloc((size_t)N_NODES * HC0 * 2);  // 15.4 MB
  float* al0 = (float*)alloc((size_t)N_NODES * HEADS * 4);
  float* ar0 = (float*)alloc((size_t)N_NODES * HEADS * 4);
  ushort_t* w0t = (ushort_t*)alloc((size_t)HC0 * NFEAT * 2);    // 128 KB
  ushort_t* w1t = (ushort_t*)alloc((size_t)HC1 * HC0 * 2);      // 80 KB
  int* deg      = (int*)alloc((size_t)N_NODES * 4);
  int* fill     = (int*)alloc((size_t)N_NODES * 4);   // adjacent to deg
  int* rowstart = (int*)alloc((size_t)(N_NODES + 1) * 4);
  int* scol     = (int*)alloc((size_t)N_EDGESN * 4);
  ushort_t* h1b = h0b;   // layer-0 h dead after layer-0 agg
  float* al1 = al0;
  float* ar1 = ar0;

  const int* srcp = ei;
  const int* dstp = ei + N_EDGESN;

  const int ztot = (int)(fill - deg) + N_NODES;     // covers deg + fill
  zero_kernel<<<(ztot + 255) / 256, 256, 0, stream>>>(deg, ztot);
  hist_kernel<<<(N_EDGESN + 255) / 256, 256, 0, stream>>>(srcp, deg, N_EDGESN);
  scan_kernel<<<1, 1024, 0, stream>>>(deg, rowstart, N_NODES);
  scatter_kernel<<<(N_EDGESN + 255) / 256, 256, 0, stream>>>(srcp, dstp, rowstart,
                                                             fill, scol, N_EDGESN);
  wtrans_both<<<(NFEAT * HC0 + HC0 * HC1 + 255) / 256, 256, 0, stream>>>(
      w0, w1, w0t, w1t);

  // layer 0: 625 blocks x 3 strips, B in regs (128 VGPR), att fused
  gemm_mfma3<4, 4, true, 1, 256><<<625, 256, 0, stream>>>(
      x, w0t, h0b, 625, att0, al0, ar0);
  gat_agg6<C0V, true><<<(N_NODES + 3) / 4, 256, 0, stream>>>(
      h0b, al0, ar0, rowstart, scol, b0, o0b, N_NODES);
  // layer 1: 938 blocks (128 thr) x <=2 strips, B in regs (160 VGPR), att fused
  gemm_mfma3<5, 2, false, 2, 128><<<938, 128, 0, stream>>>(
      o0b, w1t, h1b, 938, att1, al1, ar1);
  gat_agg6<C1V, false><<<(N_NODES + 3) / 4, 256, 0, stream>>>(
      h1b, al1, ar1, rowstart, scol, b1, out, N_NODES);
}

// Round 12
// 194.211 us; speedup vs baseline: 2.5950x; 1.0138x over previous
//
#include <hip/hip_runtime.h>
#include <math.h>

#define N_NODES 30000
#define N_EDGESN 480000
#define NFEAT 256
#define HEADS 4
#define C0V 64
#define C1V 40
#define HC0 (HEADS*C0V)   // 256
#define HC1 (HEADS*C1V)   // 160
#define NEG_SLOPE 0.2f
#define EPSV 1e-16f
#define KDIM 256
#define KPAD 264

typedef unsigned short ushort_t;
typedef __attribute__((ext_vector_type(8))) short short8v;
typedef __attribute__((ext_vector_type(4))) float f32x4;

__device__ __forceinline__ float lrelu(float x) { return x >= 0.f ? x : x * NEG_SLOPE; }

__device__ __forceinline__ float b2f_lo(unsigned int u) {
  union { unsigned int u; float f; } v; v.u = u << 16; return v.f;
}
__device__ __forceinline__ float b2f_hi(unsigned int u) {
  union { unsigned int u; float f; } v; v.u = u & 0xffff0000u; return v.f;
}
__device__ __forceinline__ unsigned short f2b(float f) {
  union { float f; unsigned int u; } v; v.f = f;
  unsigned int u = v.u + 0x7FFFu + ((v.u >> 16) & 1u);   // round-nearest-even
  return (unsigned short)(u >> 16);
}

// ---- prep: weight transposes + zero deg/fill, one dispatch --------------------
__global__ __launch_bounds__(256) void prep_kernel(const float* __restrict__ W0,
    const float* __restrict__ W1, ushort_t* __restrict__ W0t,
    ushort_t* __restrict__ W1t, int* __restrict__ zp, int zn) {
  const int idx = blockIdx.x * 256 + threadIdx.x;
  constexpr int T0 = NFEAT * HC0;   // 65536
  constexpr int T1 = HC0 * HC1;     // 40960
  if (idx < T0) {
    const int k = idx / HC0, nf = idx - k * HC0;
    W0t[(size_t)nf * NFEAT + k] = f2b(W0[idx]);
  } else if (idx < T0 + T1) {
    const int i2 = idx - T0;
    const int k = i2 / HC1, nf = i2 - k * HC1;
    W1t[(size_t)nf * HC0 + k] = f2b(W1[i2]);
  }
  if (idx < zn) zp[idx] = 0;
}

// ---- MFMA GEMM v3: B in registers, multi-strip blocks, double-buffered A ------
template <int NFW, int CG, bool A_F32, int FUSE, int NT>
__global__ __launch_bounds__(NT) void gemm_mfma3(const void* __restrict__ Ap,
    const ushort_t* __restrict__ Wt, ushort_t* __restrict__ C, int nblk,
    const float* __restrict__ att, float* __restrict__ al, float* __restrict__ ar) {
  constexpr int S = N_NODES / 16;           // 1875 strips (M % 16 == 0)
  constexpr int N = CG * NFW * 16;
  constexpr int NCH = 16 * (KDIM / 8) / NT; // staging chunks per thread
  __shared__ ushort_t As[2][16][KPAD];
  const int tid = threadIdx.x;
  const int lane = tid & 63, cg = tid >> 6;
  const int r_a = lane & 15, kg = lane >> 4;

  // ---- B fragments: registers for entire kernel ----
  short8v B[8][NFW];
#pragma unroll
  for (int ks = 0; ks < 8; ++ks)
#pragma unroll
    for (int f = 0; f < NFW; ++f)
      B[ks][f] = *reinterpret_cast<const short8v*>(
          Wt + (size_t)((cg * NFW + f) * 16 + r_a) * KDIM + ks * 32 + kg * 8);

#define STAGE_LOAD(STRIP, STG)                                                   \
  _Pragma("unroll")                                                              \
  for (int q = 0; q < NCH; ++q) {                                                \
    const int c = tid + q * NT;                                                  \
    const int r = c >> 5, ko = (c & 31) * 8;                                     \
    if (A_F32) {                                                                 \
      const float* A = (const float*)Ap + (size_t)((STRIP) * 16 + r) * KDIM + ko;\
      const float4 lo = *reinterpret_cast<const float4*>(A);                     \
      const float4 hi = *reinterpret_cast<const float4*>(A + 4);                 \
      STG[q].x = (unsigned)f2b(lo.x) | ((unsigned)f2b(lo.y) << 16);              \
      STG[q].y = (unsigned)f2b(lo.z) | ((unsigned)f2b(lo.w) << 16);              \
      STG[q].z = (unsigned)f2b(hi.x) | ((unsigned)f2b(hi.y) << 16);              \
      STG[q].w = (unsigned)f2b(hi.z) | ((unsigned)f2b(hi.w) << 16);              \
    } else {                                                                     \
      STG[q] = *reinterpret_cast<const uint4*>(                                  \
          (const ushort_t*)Ap + (size_t)((STRIP) * 16 + r) * KDIM + ko);         \
    }                                                                            \
  }
#define STAGE_WRITE(BUF, STG)                                                    \
  _Pragma("unroll")                                                              \
  for (int q = 0; q < NCH; ++q) {                                                \
    const int c = tid + q * NT;                                                  \
    const int r = c >> 5, ko = (c & 31) * 8;                                     \
    *reinterpret_cast<uint4*>(&As[BUF][r][ko]) = STG[q];                         \
  }

  int strip = blockIdx.x;
  {
    uint4 stg[NCH];
    STAGE_LOAD(strip, stg)
    STAGE_WRITE(0, stg)
  }
  __syncthreads();

  int buf = 0;
  while (true) {
    const int next = strip + nblk;
    const bool has_next = next < S;
    uint4 stg[NCH];
    if (has_next) { STAGE_LOAD(next, stg) }   // loads in flight during compute

    f32x4 acc[NFW];
#pragma unroll
    for (int f = 0; f < NFW; ++f) acc[f] = (f32x4){0.f, 0.f, 0.f, 0.f};
#pragma unroll
    for (int ks = 0; ks < 8; ++ks) {
      const short8v a =
          *reinterpret_cast<const short8v*>(&As[buf][r_a][ks * 32 + kg * 8]);
#pragma unroll
      for (int f = 0; f < NFW; ++f)
        acc[f] = __builtin_amdgcn_mfma_f32_16x16x32_bf16(a, B[ks][f], acc[f], 0, 0, 0);
    }
    const int row0 = strip * 16;
#pragma unroll
    for (int f = 0; f < NFW; ++f) {
#pragma unroll
      for (int r = 0; r < 4; ++r) {
        C[(size_t)(row0 + kg * 4 + r) * N + (cg * NFW + f) * 16 + r_a] =
            f2b(acc[f][r]);
      }
    }
    if (FUSE == 1) {
      float hpl[4] = {0.f, 0.f, 0.f, 0.f}, hpr[4] = {0.f, 0.f, 0.f, 0.f};
#pragma unroll
      for (int f = 0; f < NFW; ++f) {
        const int cc = f * 16 + r_a;
        const float wlv = att[cg * 128 + cc];
        const float wrv = att[cg * 128 + 64 + cc];
#pragma unroll
        for (int r = 0; r < 4; ++r) {
          hpl[r] = fmaf(acc[f][r], wlv, hpl[r]);
          hpr[r] = fmaf(acc[f][r], wrv, hpr[r]);
        }
      }
#pragma unroll
      for (int o = 1; o < 16; o <<= 1) {
#pragma unroll
        for (int r = 0; r < 4; ++r) {
          hpl[r] += __shfl_xor(hpl[r], o);
          hpr[r] += __shfl_xor(hpr[r], o);
        }
      }
      if (r_a == 0) {
#pragma unroll
        for (int r = 0; r < 4; ++r) {
          const int row = row0 + kg * 4 + r;
          al[(size_t)row * 4 + cg] = hpl[r];
          ar[(size_t)row * 4 + cg] = hpr[r];
        }
      }
    } else if (FUSE == 2) {
      float hpa[4] = {0,0,0,0}, hpb[4] = {0,0,0,0};
      float hra[4] = {0,0,0,0}, hrb[4] = {0,0,0,0};
#pragma unroll
      for (int f = 0; f < NFW; ++f) {
        const int col = cg * 80 + f * 16 + r_a;
        const int hd = col / 40;
        const int cc = col - hd * 40;
        const float wlv = att[hd * 80 + cc];
        const float wrv = att[hd * 80 + 40 + cc];
        const bool isB = (hd & 1);
#pragma unroll
        for (int r = 0; r < 4; ++r) {
          const float v = acc[f][r];
          if (isB) { hpb[r] = fmaf(v, wlv, hpb[r]); hrb[r] = fmaf(v, wrv, hrb[r]); }
          else     { hpa[r] = fmaf(v, wlv, hpa[r]); hra[r] = fmaf(v, wrv, hra[r]); }
        }
      }
#pragma unroll
      for (int o = 1; o < 16; o <<= 1) {
#pragma unroll
        for (int r = 0; r < 4; ++r) {
          hpa[r] += __shfl_xor(hpa[r], o); hpb[r] += __shfl_xor(hpb[r], o);
          hra[r] += __shfl_xor(hra[r], o); hrb[r] += __shfl_xor(hrb[r], o);
        }
      }
      if (r_a == 0) {
#pragma unroll
        for (int r = 0; r < 4; ++r) {
          const int row = row0 + kg * 4 + r;
          al[(size_t)row * 4 + cg * 2 + 0] = hpa[r];
          al[(size_t)row * 4 + cg * 2 + 1] = hpb[r];
          ar[(size_t)row * 4 + cg * 2 + 0] = hra[r];
          ar[(size_t)row * 4 + cg * 2 + 1] = hrb[r];
        }
      }
    }

    if (!has_next) break;
    STAGE_WRITE(buf ^ 1, stg)
    __syncthreads();
    strip = next; buf ^= 1;
  }
#undef STAGE_LOAD
#undef STAGE_WRITE
}

// ---- CSR build ----------------------------------------------------------------
__global__ void hist_kernel(const int* __restrict__ src, int* __restrict__ deg, int E) {
  const int e = blockIdx.x * blockDim.x + threadIdx.x;
  if (e < E) atomicAdd(&deg[src[e]], 1);
}

__global__ __launch_bounds__(1024) void scan_kernel(const int* __restrict__ deg,
    int* __restrict__ rowstart, int n) {
  __shared__ int carry;
  __shared__ int wsum[16];
  const int tid = threadIdx.x;
  const int lane = tid & 63, w = tid >> 6;
  if (tid == 0) { carry = 0; rowstart[0] = 0; }
  __syncthreads();
  for (int base = 0; base < n; base += 1024) {
    const int idx = base + tid;
    int x = (idx < n) ? deg[idx] : 0;
#pragma unroll
    for (int o = 1; o < 64; o <<= 1) { int y = __shfl_up(x, o); if (lane >= o) x += y; }
    if (lane == 63) wsum[w] = x;
    __syncthreads();
    if (w == 0) {
      int s = (lane < 16) ? wsum[lane] : 0;
#pragma unroll
      for (int o = 1; o < 16; o <<= 1) { int y = __shfl_up(s, o); if (lane >= o) s += y; }
      if (lane < 16) wsum[lane] = s;
    }
    __syncthreads();
    const int add = (w > 0 ? wsum[w - 1] : 0) + carry;
    if (idx < n) rowstart[idx + 1] = x + add;
    __syncthreads();
    if (tid == 0) carry += wsum[15];
    __syncthreads();
  }
}

__global__ void scatter_kernel(const int* __restrict__ src, const int* __restrict__ dst,
    const int* __restrict__ rowstart, int* __restrict__ fill, int* __restrict__ scol,
    int E) {
  const int e = blockIdx.x * blockDim.x + threadIdx.x;
  if (e < E) {
    const int r = src[e];
    const int pos = rowstart[r] + atomicAdd(&fill[r], 1);
    scol[pos] = dst[e];
  }
}

// ---- agg v6c: single pass, normalize after aggregation, padded scol -----------
// scol is allocated with >=16 pad entries so index prefetches past s1 are safe
// to LOAD (never dereferenced into h) -> no min() clamps in the hot loop.
template <int C, bool CONCAT_RELU>
__global__ __launch_bounds__(256) void gat_agg6(const ushort_t* __restrict__ h,
    const float* __restrict__ al, const float* __restrict__ ar,
    const int* __restrict__ rowstart, const int* __restrict__ scol,
    const float* __restrict__ bias, void* __restrict__ outv, int n) {
  constexpr int ROW = HEADS * C;     // 256 / 160
  constexpr int LPG = ROW / 8;       // lanes per group: 32 / 20
  constexpr int NG  = 64 / LPG;      // groups: 2 / 3
  __shared__ float smA[CONCAT_RELU ? 1 : 4][CONCAT_RELU ? 1 : NG]
                      [CONCAT_RELU ? 1 : ROW];
  __shared__ float smT[CONCAT_RELU ? 1 : 4][CONCAT_RELU ? 1 : NG * LPG];
  const int wid = threadIdx.x >> 6, lane = threadIdx.x & 63;
  const int i = blockIdx.x * 4 + wid;
  if (i >= n) return;                // never taken (30000 % 4 == 0)
  const int s0 = rowstart[i], s1 = rowstart[i + 1];

  const float4 al4 = *reinterpret_cast<const float4*>(al + (size_t)i * 4);
  const float4 ari = *reinterpret_cast<const float4*>(ar + (size_t)i * 4);
  const float es0 = __expf(lrelu(al4.x + ari.x));
  const float es1 = __expf(lrelu(al4.y + ari.y));
  const float es2 = __expf(lrelu(al4.z + ari.z));
  const float es3 = __expf(lrelu(al4.w + ari.w));

  const int g  = lane / LPG;
  const int cl = lane - g * LPG;
  const bool act = g < NG;
  const int hd = (cl * 8) / C;
  const float al_h = hd < 2 ? (hd == 0 ? al4.x : al4.y) : (hd == 2 ? al4.z : al4.w);
  const float es_h = hd < 2 ? (hd == 0 ? es0 : es1) : (hd == 2 ? es2 : es3);

  float t = 0.f;
  float acc[8];
#pragma unroll
  for (int k = 0; k < 8; ++k) acc[k] = 0.f;

  if (g == 0) {   // self-loop contribution (unnormalized)
    const uint4 hv = *reinterpret_cast<const uint4*>(h + (size_t)i * ROW + cl * 8);
    acc[0] = es_h * b2f_lo(hv.x); acc[1] = es_h * b2f_hi(hv.x);
    acc[2] = es_h * b2f_lo(hv.y); acc[3] = es_h * b2f_hi(hv.y);
    acc[4] = es_h * b2f_lo(hv.z); acc[5] = es_h * b2f_hi(hv.z);
    acc[6] = es_h * b2f_lo(hv.w); acc[7] = es_h * b2f_hi(hv.w);
  }

#define FMA8(W, HV) \
  acc[0] = fmaf(W, b2f_lo(HV.x), acc[0]); acc[1] = fmaf(W, b2f_hi(HV.x), acc[1]); \
  acc[2] = fmaf(W, b2f_lo(HV.y), acc[2]); acc[3] = fmaf(W, b2f_hi(HV.y), acc[3]); \
  acc[4] = fmaf(W, b2f_lo(HV.z), acc[4]); acc[5] = fmaf(W, b2f_hi(HV.z), acc[5]); \
  acc[6] = fmaf(W, b2f_lo(HV.w), acc[6]); acc[7] = fmaf(W, b2f_hi(HV.w), acc[7])

  if (act) {
    int e = s0 + g;
    int ja = scol[e];              // padded scol: safe even if e >= s1
    int jb = scol[e + NG];
    for (; e + NG < s1; e += 2 * NG) {
      const int jc = scol[e + 2 * NG];
      const int jd = scol[e + 3 * NG];
      const float ara = ar[(size_t)ja * 4 + hd];
      const float arb = ar[(size_t)jb * 4 + hd];
      const uint4 ha = *reinterpret_cast<const uint4*>(h + (size_t)ja * ROW + cl * 8);
      const uint4 hb = *reinterpret_cast<const uint4*>(h + (size_t)jb * ROW + cl * 8);
      const float wa = __expf(lrelu(al_h + ara));
      const float wb = __expf(lrelu(al_h + arb));
      t += wa + wb;
      FMA8(wa, ha); FMA8(wb, hb);
      ja = jc; jb = jd;
    }
    if (e < s1) {
      const float ara = ar[(size_t)ja * 4 + hd];
      const uint4 ha = *reinterpret_cast<const uint4*>(h + (size_t)ja * ROW + cl * 8);
      const float wa = __expf(lrelu(al_h + ara));
      t += wa;
      FMA8(wa, ha);
    }
  }
#undef FMA8

  if (CONCAT_RELU) {
    t += __shfl_xor(t, 32);            // combine the two groups ONLY
    const float inv = 1.f / (t + es_h + EPSV);
#pragma unroll
    for (int k = 0; k < 8; ++k) acc[k] *= inv;
#pragma unroll
    for (int k = 0; k < 8; ++k) acc[k] += __shfl_xor(acc[k], 32);
    if (g == 0) {
      const float4 blo = *reinterpret_cast<const float4*>(bias + cl * 8);
      const float4 bhi = *reinterpret_cast<const float4*>(bias + cl * 8 + 4);
      uint4 st;
      st.x = (unsigned)f2b(fmaxf(acc[0] + blo.x, 0.f)) |
             ((unsigned)f2b(fmaxf(acc[1] + blo.y, 0.f)) << 16);
      st.y = (unsigned)f2b(fmaxf(acc[2] + blo.z, 0.f)) |
             ((unsigned)f2b(fmaxf(acc[3] + blo.w, 0.f)) << 16);
      st.z = (unsigned)f2b(fmaxf(acc[4] + bhi.x, 0.f)) |
             ((unsigned)f2b(fmaxf(acc[5] + bhi.y, 0.f)) << 16);
      st.w = (unsigned)f2b(fmaxf(acc[6] + bhi.z, 0.f)) |
             ((unsigned)f2b(fmaxf(acc[7] + bhi.w, 0.f)) << 16);
      *reinterpret_cast<uint4*>((ushort_t*)outv + (size_t)i * ROW + cl * 8) = st;
    }
  } else {
    if (act) {
#pragma unroll
      for (int k = 0; k < 8; ++k) smA[wid][g][cl * 8 + k] = acc[k];
      smT[wid][g * LPG + cl] = t;
    }
    __syncthreads();
    if (lane < C) {
      const float es[4] = {es0, es1, es2, es3};
      float s = 0.f;
#pragma unroll
      for (int hh = 0; hh < HEADS; ++hh) {
        float den = es[hh];
#pragma unroll
        for (int gg = 0; gg < NG; ++gg)
          den += smT[wid][gg * LPG + hh * 5];   // ONE representative per group
        float chan = 0.f;
#pragma unroll
        for (int gg = 0; gg < NG; ++gg) chan += smA[wid][gg][hh * C + lane];
        s += chan / (den + EPSV);
      }
      ((float*)outv)[(size_t)i * C + lane] = s * 0.25f + bias[lane];
    }
  }
}

// ---- launch -------------------------------------------------------------------
extern "C" void kernel_launch(void* const* d_in, const int* in_sizes, int n_in,
                              void* d_out, int out_size, void* d_ws, size_t ws_size,
                              hipStream_t stream) {
  const float* x    = (const float*)d_in[0];
  const int*   ei   = (const int*)d_in[1];
  const float* w0   = (const float*)d_in[2];
  const float* att0 = (const float*)d_in[3];
  const float* b0   = (const float*)d_in[4];
  const float* w1   = (const float*)d_in[5];
  const float* att1 = (const float*)d_in[6];
  const float* b1   = (const float*)d_in[7];
  float* out = (float*)d_out;

  char* ws = (char*)d_ws;
  size_t off = 0;
  auto alloc = [&](size_t bytes) -> void* {
    void* p = ws + off;
    off += (bytes + 255) & ~(size_t)255;
    return p;
  };
  ushort_t* h0b = (ushort_t*)alloc((size_t)N_NODES * HC0 * 2);  // 15.4 MB
  ushort_t* o0b = (ushort_t*)alloc((size_t)N_NODES * HC0 * 2);  // 15.4 MB
  float* al0 = (float*)alloc((size_t)N_NODES * HEADS * 4);
  float* ar0 = (float*)alloc((size_t)N_NODES * HEADS * 4);
  ushort_t* w0t = (ushort_t*)alloc((size_t)HC0 * NFEAT * 2);    // 128 KB
  ushort_t* w1t = (ushort_t*)alloc((size_t)HC1 * HC0 * 2);      // 80 KB
  int* deg      = (int*)alloc((size_t)N_NODES * 4);
  int* fill     = (int*)alloc((size_t)N_NODES * 4);   // adjacent to deg
  int* rowstart = (int*)alloc((size_t)(N_NODES + 1) * 4);
  int* scol     = (int*)alloc((size_t)(N_EDGESN + 16) * 4);  // +16 pad: no clamps
  ushort_t* h1b = h0b;   // layer-0 h dead after layer-0 agg
  float* al1 = al0;
  float* ar1 = ar0;

  const int* srcp = ei;
  const int* dstp = ei + N_EDGESN;

  const int ztot = (int)(fill - deg) + N_NODES;     // covers deg + fill
  constexpr int PREPN = NFEAT * HC0 + HC0 * HC1;    // 106496 >= ztot
  prep_kernel<<<(PREPN + 255) / 256, 256, 0, stream>>>(w0, w1, w0t, w1t, deg, ztot);
  hist_kernel<<<(N_EDGESN + 255) / 256, 256, 0, stream>>>(srcp, deg, N_EDGESN);
  scan_kernel<<<1, 1024, 0, stream>>>(deg, rowstart, N_NODES);
  scatter_kernel<<<(N_EDGESN + 255) / 256, 256, 0, stream>>>(srcp, dstp, rowstart,
                                                             fill, scol, N_EDGESN);

  // layer 0: 625 blocks x 3 strips, B in regs (128 VGPR), att fused
  gemm_mfma3<4, 4, true, 1, 256><<<625, 256, 0, stream>>>(
      x, w0t, h0b, 625, att0, al0, ar0);
  gat_agg6<C0V, true><<<(N_NODES + 3) / 4, 256, 0, stream>>>(
      h0b, al0, ar0, rowstart, scol, b0, o0b, N_NODES);
  // layer 1: 938 blocks (128 thr) x <=2 strips, B in regs, att fused
  gemm_mfma3<5, 2, false, 2, 128><<<938, 128, 0, stream>>>(
      o0b, w1t, h1b, 938, att1, al1, ar1);
  gat_agg6<C1V, false><<<(N_NODES + 3) / 4, 256, 0, stream>>>(
      h1b, al1, ar1, rowstart, scol, b1, out, N_NODES);
}